// Round 6
// baseline (1759.807 us; speedup 1.0000x reference)
//
#include <hip/hip_runtime.h>

typedef unsigned short u16;
typedef unsigned int u32;
typedef __attribute__((ext_vector_type(8))) short bf16x8;
typedef __attribute__((ext_vector_type(4))) float f32x4;
typedef __attribute__((ext_vector_type(16))) float f32x16;

#define BN_EPS 1e-5f
#define BN_S 16

__device__ __forceinline__ float bf2f(u16 u) {
  union { unsigned u; float f; } x; x.u = ((unsigned)u) << 16; return x.f;
}
__device__ __forceinline__ u16 f2bf(float f) {
  union { float f; unsigned u; } x; x.f = f;
  unsigned r = x.u + 0x7FFFu + ((x.u >> 16) & 1u);
  return (u16)(r >> 16);
}

// ---------------- conv1: direct, NHWC output [64*38*38][32] fp32 ----------------
__global__ void conv1_nhwc(const float* __restrict__ img, const float* __restrict__ w,
                           const float* __restrict__ b, float* __restrict__ C1) {
  int idx = blockIdx.x * blockDim.x + threadIdx.x;
  if (idx >= 92416 * 32) return;
  int co = idx & 31; int row = idx >> 5;
  int wo = row % 38; int t = row / 38;
  int ho = t % 38; int n = t / 38;
  int hi0 = ho * 2 - 1, wi0 = wo * 2 - 1;
  float acc = b[co];
  const float* wp = w + co * 27;
#pragma unroll
  for (int ci = 0; ci < 3; ci++) {
    const float* ip = img + ((size_t)(n * 3 + ci) * 75) * 75;
    const float* wc = wp + ci * 9;
#pragma unroll
    for (int kh = 0; kh < 3; kh++) {
      int hi = hi0 + kh;
      if (hi < 0 || hi >= 75) continue;
#pragma unroll
      for (int kw = 0; kw < 3; kw++) {
        int wi = wi0 + kw;
        if (wi < 0 || wi >= 75) continue;
        acc += ip[hi * 75 + wi] * wc[kh * 3 + kw];
      }
    }
  }
  C1[idx] = acc;
}

// ---------------- BN column-stats (deterministic 2-stage) ----------------
__global__ void bn_partial(const float* __restrict__ C, int ldc, int M,
                           float* __restrict__ part) {
  int c = blockIdx.x; int s = blockIdx.y; int t = threadIdx.x;
  int rowsPer = (M + BN_S - 1) / BN_S;
  int r0 = s * rowsPer; int r1 = r0 + rowsPer; if (r1 > M) r1 = M;
  float s1 = 0.f, s2 = 0.f;
  for (int r = r0 + t; r < r1; r += 256) {
    float v = C[(size_t)r * ldc + c]; s1 += v; s2 += v * v;
  }
  __shared__ float l1[256], l2[256];
  l1[t] = s1; l2[t] = s2; __syncthreads();
  for (int off = 128; off > 0; off >>= 1) {
    if (t < off) { l1[t] += l1[t + off]; l2[t] += l2[t + off]; }
    __syncthreads();
  }
  if (t == 0) { part[s * 512 + c] = l1[0]; part[s * 512 + 256 + c] = l2[0]; }
}

__global__ void bn_final(const float* __restrict__ part, const float* __restrict__ gamma,
                         const float* __restrict__ beta, float* __restrict__ ss,
                         int C, int M) {
  int c = threadIdx.x;
  if (c >= C) { if (c < 256) { ss[c] = 0.f; ss[256 + c] = 0.f; } return; }
  float s1 = 0.f, s2 = 0.f;
#pragma unroll
  for (int s = 0; s < BN_S; s++) { s1 += part[s * 512 + c]; s2 += part[s * 512 + 256 + c]; }
  float mu = s1 / M;
  float var = s2 / M - mu * mu;
  float sc = gamma[c] * rsqrtf(var + BN_EPS);
  ss[c] = sc; ss[256 + c] = beta[c] - mu * sc;
}

// ---------------- fused BN+ReLU + im2col -> bf16 X[row][tap*Ci+ci] ----------------
__global__ void bnrelu_im2col(const float* __restrict__ Cprev, int ldprev, int Hp, int Wp,
                              const float* __restrict__ ss, u16* __restrict__ X,
                              int Ho, int Wo, int Ci, int Mp) {
  int civ4 = Ci >> 2;
  int idx = blockIdx.x * blockDim.x + threadIdx.x;
  int total = Mp * 9 * civ4;
  if (idx >= total) return;
  int cv = idx % civ4; int t2 = idx / civ4;
  int tap = t2 % 9; int row = t2 / 9;
  int K = 9 * Ci;
  u16* dst = X + (size_t)row * K + tap * Ci + cv * 4;
  int HW = Ho * Wo;
  int Mvalid = 64 * HW;
  ushort4 o4; o4.x = 0; o4.y = 0; o4.z = 0; o4.w = 0;
  if (row < Mvalid) {
    int wo = row % Wo; int t = row / Wo;
    int ho = t % Ho; int n = t / Ho;
    int kh = tap / 3, kw = tap % 3;
    int hi = ho * 2 - 1 + kh, wi = wo * 2 - 1 + kw;
    if (hi >= 0 && hi < Hp && wi >= 0 && wi < Wp) {
      const float* src = Cprev + ((size_t)((n * Hp + hi) * Wp + wi)) * ldprev + cv * 4;
      float4 v = *(const float4*)src;
      int c0 = cv * 4;
      float a;
      a = v.x * ss[c0 + 0] + ss[256 + c0 + 0]; o4.x = f2bf(a > 0.f ? a : 0.f);
      a = v.y * ss[c0 + 1] + ss[256 + c0 + 1]; o4.y = f2bf(a > 0.f ? a : 0.f);
      a = v.z * ss[c0 + 2] + ss[256 + c0 + 2]; o4.z = f2bf(a > 0.f ? a : 0.f);
      a = v.w * ss[c0 + 3] + ss[256 + c0 + 3]; o4.w = f2bf(a > 0.f ? a : 0.f);
    }
  }
  *(ushort4*)dst = o4;
}

// ---------------- conv weight pack ----------------
__global__ void pack_convw(const float* __restrict__ w, u16* __restrict__ Wp,
                           int Co, int Ci, int Cop) {
  int K = 9 * Ci;
  int idx = blockIdx.x * blockDim.x + threadIdx.x;
  if (idx >= Cop * K) return;
  int k = idx % K; int co = idx / K;
  int tap = k / Ci; int ci = k % Ci;
  float v = (co < Co) ? w[((size_t)co * Ci + ci) * 9 + tap] : 0.f;
  Wp[idx] = f2bf(v);
}

__global__ void pad_bias(const float* __restrict__ b, float* __restrict__ bc, int Co, int Cop) {
  int i = blockIdx.x * blockDim.x + threadIdx.x;
  if (i < Cop) bc[i] = (i < Co) ? b[i] : 0.f;
}

// ---------------- obj pack from C4 with BN+ReLU ----------------
__global__ void obj_from_c4(const float* __restrict__ C4, const float* __restrict__ ss,
                            u16* __restrict__ obj) {
  int idx = blockIdx.x * blockDim.x + threadIdx.x;
  if (idx >= 1664 * 256) return;
  int c = idx & 255; int row = idx >> 8;
  float v = 0.f;
  if (row < 1600) {
    float x = C4[(size_t)row * 256 + c];
    x = x * ss[c] + ss[256 + c];
    v = x > 0.f ? x : 0.f;
  }
  obj[idx] = f2bf(v);
}

// ---------------- MLP weight packs ----------------
__global__ void pack_w1(const float* __restrict__ gw1, u16* __restrict__ W1a, u16* __restrict__ W1b) {
  int idx = blockIdx.x * blockDim.x + threadIdx.x;
  if (idx >= 2048 * 256) return;
  int k = idx & 255, n = idx >> 8;
  float a = 0.f, b = 0.f;
  if (n < 2000) { a = gw1[(size_t)n * 523 + k]; b = gw1[(size_t)n * 523 + 256 + k]; }
  W1a[idx] = f2bf(a); W1b[idx] = f2bf(b);
}

__global__ void pack_wbig(const float* __restrict__ gw, u16* __restrict__ Wp) {
  int idx = blockIdx.x * blockDim.x + threadIdx.x;
  if (idx >= 2048 * 2048) return;
  int k = idx & 2047, n = idx >> 11;
  float v = (n < 2000 && k < 2000) ? gw[(size_t)n * 2000 + k] : 0.f;
  Wp[idx] = f2bf(v);
}

__global__ void pack_bias3(const float* __restrict__ b2, const float* __restrict__ b3,
                           const float* __restrict__ b4, float* __restrict__ bp) {
  int i = blockIdx.x * blockDim.x + threadIdx.x;
  if (i >= 2048) return;
  bp[i]        = (i < 2000) ? b2[i] : 0.f;
  bp[2048 + i] = (i < 2000) ? b3[i] : 0.f;
  bp[4096 + i] = (i < 2000) ? b4[i] : 0.f;
}

// ---------------- Q[b][o] = gb1[o] + qst[b] . gw1[o][512:523] ----------------
__global__ void q_build(const float* __restrict__ qst, const float* __restrict__ gw1,
                        const float* __restrict__ gb1, float* __restrict__ Q) {
  int idx = blockIdx.x * blockDim.x + threadIdx.x;
  if (idx >= 64 * 2048) return;
  int o = idx & 2047, b = idx >> 11;
  float v = 0.f;
  if (o < 2000) {
    v = gb1[o];
    const float* w = gw1 + (size_t)o * 523 + 512;
    const float* q = qst + b * 11;
#pragma unroll
    for (int k = 0; k < 11; k++) v += q[k] * w[k];
  }
  Q[idx] = v;
}

// ---------------- global->LDS async ----------------
typedef const __attribute__((address_space(1))) u32* gas1;
typedef __attribute__((address_space(3))) u32* las3;
__device__ __forceinline__ void gld16(const void* g, void* l) {
  __builtin_amdgcn_global_load_lds((gas1)g, (las3)l, 16, 0, 0);
}

// ---------------- 128^2 bf16 MFMA GEMM (small/medium shapes) ----------------
// EPI 0: fp32 raw; EPI 2: fp32 acc+bias; EPI 3: bf16 raw
template <int EPI>
__global__ __launch_bounds__(256) void gemm_bt(
    const u16* __restrict__ A, int lda,
    const u16* __restrict__ W, int ldb,
    float* __restrict__ Cf, u16* __restrict__ Cb, int ldc,
    const float* __restrict__ bias, int KT, int NTN) {
  __shared__ __align__(16) char lds[32768];
  int bid = blockIdx.x;
  int wg;
  if ((gridDim.x & 7) == 0) {
    int cpx = gridDim.x >> 3;
    wg = (bid & 7) * cpx + (bid >> 3);
  } else {
    wg = bid;
  }
  int mt = wg / NTN, nt = wg % NTN;
  int tid = threadIdx.x;
  int wave = tid >> 6, lane = tid & 63;
  int r = lane & 15, g = lane >> 4;
  int wr = wave >> 1, wc = wave & 1;

  const u16* Asrc = A + (size_t)(mt * 128 + wave * 32 + r) * lda + g * 8;
  const u16* Wsrc = W + (size_t)(nt * 128 + wave * 32 + r) * ldb + g * 8;

  f32x4 acc[4][4];
#pragma unroll
  for (int i = 0; i < 4; i++)
#pragma unroll
    for (int j = 0; j < 4; j++) acc[i][j] = (f32x4){0.f, 0.f, 0.f, 0.f};

  {
    char* Al = lds; char* Wl = lds + 8192;
    gld16(Asrc, Al + wave * 2048);
    gld16(Asrc + (size_t)16 * lda, Al + wave * 2048 + 1024);
    gld16(Wsrc, Wl + wave * 2048);
    gld16(Wsrc + (size_t)16 * ldb, Wl + wave * 2048 + 1024);
  }
  __syncthreads();

  int buf = 0;
  for (int kt = 0; kt < KT; kt++) {
    if (kt + 1 < KT) {
      int k0 = (kt + 1) * 32;
      char* Al = lds + (buf ^ 1) * 16384; char* Wl = Al + 8192;
      gld16(Asrc + k0, Al + wave * 2048);
      gld16(Asrc + k0 + (size_t)16 * lda, Al + wave * 2048 + 1024);
      gld16(Wsrc + k0, Wl + wave * 2048);
      gld16(Wsrc + k0 + (size_t)16 * ldb, Wl + wave * 2048 + 1024);
    }
    char* Al = lds + buf * 16384; char* Wl = Al + 8192;
    bf16x8 a[4], w[4];
#pragma unroll
    for (int i = 0; i < 4; i++) a[i] = *(const bf16x8*)(Al + (wr * 4 + i) * 1024 + lane * 16);
#pragma unroll
    for (int j = 0; j < 4; j++) w[j] = *(const bf16x8*)(Wl + (wc * 4 + j) * 1024 + lane * 16);
#pragma unroll
    for (int i = 0; i < 4; i++)
#pragma unroll
      for (int j = 0; j < 4; j++)
        acc[i][j] = __builtin_amdgcn_mfma_f32_16x16x32_bf16(a[i], w[j], acc[i][j], 0, 0, 0);
    __syncthreads();
    buf ^= 1;
  }

  int rowb = mt * 128 + wr * 64 + (lane >> 4) * 4;
  int colb = nt * 128 + wc * 64 + (lane & 15);
#pragma unroll
  for (int i = 0; i < 4; i++) {
#pragma unroll
    for (int j = 0; j < 4; j++) {
      int col = colb + j * 16;
      float bv = (EPI == 2) ? bias[col] : 0.f;
#pragma unroll
      for (int q = 0; q < 4; q++) {
        int row = rowb + i * 16 + q;
        float v = acc[i][j][q];
        if (EPI == 2) {
          Cf[(size_t)row * ldc + col] = v + bv;
        } else if (EPI == 3) {
          Cb[(size_t)row * ldc + col] = f2bf(v);
        } else {
          Cf[(size_t)row * ldc + col] = v;
        }
      }
    }
  }
}

// ---------------- 256^2 bf16 GEMM, 32x32x16 MFMA, 4-deep pipeline ----------------
// C = relu(A@W^T + bias) -> bf16. lda=ldb=ldc=2048. BK=32.
// 8 waves (2M x 4N), per-wave out 128x64 (4m x 2n of 32x32). One barrier/tile,
// counted vmcnt(4/0), reads for t+1 issued under ph1(t), minimal sched pins.
#define MF32(d, av, bv) d = __builtin_amdgcn_mfma_f32_32x32x16_bf16(av, bv, d, 0, 0, 0)

#define GITER(T, BC, BN)                                                            \
  {                                                                                 \
    const char* base_ = lds + ((T) & 3) * 32768;                                    \
    aH00 = *(const bf16x8*)(base_ + ((wr4 + 2) * 2 + 0) * 1024 + lane16);           \
    aH01 = *(const bf16x8*)(base_ + ((wr4 + 2) * 2 + 1) * 1024 + lane16);           \
    aH10 = *(const bf16x8*)(base_ + ((wr4 + 3) * 2 + 0) * 1024 + lane16);           \
    aH11 = *(const bf16x8*)(base_ + ((wr4 + 3) * 2 + 1) * 1024 + lane16);           \
    __builtin_amdgcn_s_setprio(1);                                                  \
    MF32(acc00, aL00, BC##00); MF32(acc00, aL01, BC##01);                           \
    MF32(acc01, aL00, BC##10); MF32(acc01, aL01, BC##11);                           \
    MF32(acc10, aL10, BC##00); MF32(acc10, aL11, BC##01);                           \
    MF32(acc11, aL10, BC##10); MF32(acc11, aL11, BC##11);                           \
    __builtin_amdgcn_s_setprio(0);                                                  \
    {                                                                               \
      int rem_ = NT - 1 - (T);                                                      \
      if (rem_ >= 2)      { asm volatile("s_waitcnt vmcnt(4)" ::: "memory"); }      \
      else if (rem_ == 1) { asm volatile("s_waitcnt vmcnt(0)" ::: "memory"); }      \
    }                                                                               \
    __builtin_amdgcn_s_barrier();                                                   \
    __builtin_amdgcn_sched_barrier(0);                                              \
    if ((T) + 1 < NT) {                                                             \
      const char* nb_ = lds + (((T) + 1) & 3) * 32768;                              \
      aL00 = *(const bf16x8*)(nb_ + ((wr4 + 0) * 2 + 0) * 1024 + lane16);           \
      aL01 = *(const bf16x8*)(nb_ + ((wr4 + 0) * 2 + 1) * 1024 + lane16);           \
      aL10 = *(const bf16x8*)(nb_ + ((wr4 + 1) * 2 + 0) * 1024 + lane16);           \
      aL11 = *(const bf16x8*)(nb_ + ((wr4 + 1) * 2 + 1) * 1024 + lane16);           \
      BN##00 = *(const bf16x8*)(nb_ + 16384 + ((wc2 + 0) * 2 + 0) * 1024 + lane16); \
      BN##01 = *(const bf16x8*)(nb_ + 16384 + ((wc2 + 0) * 2 + 1) * 1024 + lane16); \
      BN##10 = *(const bf16x8*)(nb_ + 16384 + ((wc2 + 1) * 2 + 0) * 1024 + lane16); \
      BN##11 = *(const bf16x8*)(nb_ + 16384 + ((wc2 + 1) * 2 + 1) * 1024 + lane16); \
    }                                                                               \
    if ((T) + 3 < NT) {                                                             \
      char* sb_ = lds + (((T) + 3) & 3) * 32768;                                    \
      gld16(gA0, sb_ + subA);        gld16(gB0, sb_ + 16384 + subA);                \
      gld16(gA1, sb_ + subA + 1024); gld16(gB1, sb_ + 16384 + subA + 1024);         \
      gA0 += 32; gA1 += 32; gB0 += 32; gB1 += 32;                                   \
    }                                                                               \
    __builtin_amdgcn_s_setprio(1);                                                  \
    MF32(acc20, aH00, BC##00); MF32(acc20, aH01, BC##01);                           \
    MF32(acc21, aH00, BC##10); MF32(acc21, aH01, BC##11);                           \
    MF32(acc30, aH10, BC##00); MF32(acc30, aH11, BC##01);                           \
    MF32(acc31, aH10, BC##10); MF32(acc31, aH11, BC##11);                           \
    __builtin_amdgcn_s_setprio(0);                                                  \
  }

template <int NT>
__global__ __launch_bounds__(512, 2) void gemm256(
    const u16* __restrict__ A, const u16* __restrict__ W,
    u16* __restrict__ Cb, const float* __restrict__ bias) {
  __shared__ __align__(16) char lds[131072];
  int bid = blockIdx.x;
  int cpx = gridDim.x >> 3;                 // grid = mtiles*8, always %8==0
  int wg = (bid & 7) * cpx + (bid >> 3);
  int mt = wg >> 3, nt = wg & 7;
  int tid = threadIdx.x;
  int wave = tid >> 6, lane = tid & 63;
  int lane16 = lane * 16;
  int wr = wave >> 2, wc = wave & 3;
  int wr4 = wr * 4, wc2 = wc * 2;
  const int lda = 2048;

  // staging: wave w covers A mtile w (32 rows) and B ntile w, both ks halves.
  // lane l: row = base + (l&31), k = koff + ks*16 + (l>>5)*8  (16B = 8 bf16)
  const u16* gA0 = A + (size_t)(mt * 256 + wave * 32 + (lane & 31)) * lda + (lane >> 5) * 8;
  const u16* gA1 = gA0 + 16;
  const u16* gB0 = W + (size_t)(nt * 256 + wave * 32 + (lane & 31)) * lda + (lane >> 5) * 8;
  const u16* gB1 = gB0 + 16;
  int subA = (wave * 2) * 1024;

  f32x16 acc00 = {0,0,0,0,0,0,0,0,0,0,0,0,0,0,0,0};
  f32x16 acc01 = acc00, acc10 = acc00, acc11 = acc00;
  f32x16 acc20 = acc00, acc21 = acc00, acc30 = acc00, acc31 = acc00;

  // prologue: stage tiles 0,1,2
#pragma unroll
  for (int pt = 0; pt < 3; pt++) {
    char* sb = lds + pt * 32768;
    gld16(gA0, sb + subA);        gld16(gB0, sb + 16384 + subA);
    gld16(gA1, sb + subA + 1024); gld16(gB1, sb + 16384 + subA + 1024);
    gA0 += 32; gA1 += 32; gB0 += 32; gB1 += 32;
  }
  asm volatile("s_waitcnt vmcnt(8)" ::: "memory");   // tile 0 landed
  __builtin_amdgcn_s_barrier();
  __builtin_amdgcn_sched_barrier(0);

  bf16x8 aL00, aL01, aL10, aL11, aH00, aH01, aH10, aH11;
  bf16x8 bA00, bA01, bA10, bA11, bB00, bB01, bB10, bB11;

  {  // tile-0 aL + bA
    const char* b0_ = lds;
    aL00 = *(const bf16x8*)(b0_ + ((wr4 + 0) * 2 + 0) * 1024 + lane16);
    aL01 = *(const bf16x8*)(b0_ + ((wr4 + 0) * 2 + 1) * 1024 + lane16);
    aL10 = *(const bf16x8*)(b0_ + ((wr4 + 1) * 2 + 0) * 1024 + lane16);
    aL11 = *(const bf16x8*)(b0_ + ((wr4 + 1) * 2 + 1) * 1024 + lane16);
    bA00 = *(const bf16x8*)(b0_ + 16384 + ((wc2 + 0) * 2 + 0) * 1024 + lane16);
    bA01 = *(const bf16x8*)(b0_ + 16384 + ((wc2 + 0) * 2 + 1) * 1024 + lane16);
    bA10 = *(const bf16x8*)(b0_ + 16384 + ((wc2 + 1) * 2 + 0) * 1024 + lane16);
    bA11 = *(const bf16x8*)(b0_ + 16384 + ((wc2 + 1) * 2 + 1) * 1024 + lane16);
  }

#pragma unroll 1
  for (int t2 = 0; t2 < NT; t2 += 2) {
    GITER(t2,     bA, bB);
    GITER(t2 + 1, bB, bA);
  }

  // epilogue: 32x32 D layout: col = lane&31, row = (q&3) + 8*(q>>2) + 4*(lane>>5)
  int rowb = mt * 256 + wr * 128 + 4 * (lane >> 5);
  int colb = nt * 256 + wc * 64 + (lane & 31);
  f32x16 accs[8] = {acc00, acc01, acc10, acc11, acc20, acc21, acc30, acc31};
#pragma unroll
  for (int i = 0; i < 4; i++) {
#pragma unroll
    for (int j = 0; j < 2; j++) {
      f32x16 av = accs[i * 2 + j];
      int col = colb + j * 32;
      float bv = bias[col];
#pragma unroll
      for (int q = 0; q < 16; q++) {
        int row = rowb + i * 32 + (q & 3) + 8 * (q >> 2);
        float v = av[q] + bv;
        v = v > 0.f ? v : 0.f;
        Cb[(size_t)row * 2048 + col] = f2bf(v);
      }
    }
  }
}

// ---------------- h1 = relu(A_i + B_j + Q_b), bf16 in/out ----------------
__global__ void h1_build(const u16* __restrict__ Af, const u16* __restrict__ Bf,
                         const float* __restrict__ Q, u16* __restrict__ h1,
                         int c0, int nrows) {
  int row = blockIdx.x;
  int t = threadIdx.x;
  u16* dst = h1 + (size_t)row * 2048;
  if (row >= nrows) {
#pragma unroll
    for (int it = 0; it < 2; it++) {
      int o = it * 1024 + t * 4;
      ushort4 z; z.x = 0; z.y = 0; z.z = 0; z.w = 0;
      *(ushort4*)(dst + o) = z;
    }
    return;
  }
  int b_local = row / 625; int rem = row % 625;
  int i = rem / 25, j = rem % 25;
  int b = c0 + b_local;
  const u16* Ap = Af + (size_t)(b * 25 + i) * 2048;
  const u16* Bp = Bf + (size_t)(b * 25 + j) * 2048;
  const float* Qp = Q + (size_t)b * 2048;
#pragma unroll
  for (int it = 0; it < 2; it++) {
    int o = it * 1024 + t * 4;
    ushort4 a4 = *(const ushort4*)(Ap + o);
    ushort4 b4 = *(const ushort4*)(Bp + o);
    float4 qv = *(const float4*)(Qp + o);
    ushort4 outv;
    float v;
    v = bf2f(a4.x) + bf2f(b4.x) + qv.x; outv.x = f2bf(v > 0.f ? v : 0.f);
    v = bf2f(a4.y) + bf2f(b4.y) + qv.y; outv.y = f2bf(v > 0.f ? v : 0.f);
    v = bf2f(a4.z) + bf2f(b4.z) + qv.z; outv.z = f2bf(v > 0.f ? v : 0.f);
    v = bf2f(a4.w) + bf2f(b4.w) + qv.w; outv.w = f2bf(v > 0.f ? v : 0.f);
    *(ushort4*)(dst + o) = outv;
  }
}

// ---------------- pair-sum reduce, deterministic 2-stage ----------------
__global__ void reduce_part(const u16* __restrict__ h4, float* __restrict__ part, int CHI) {
  int bl = blockIdx.x; int s = blockIdx.y; int t = threadIdx.x;
  int k0 = s * 125, k1 = k0 + 125;
  const u16* base = h4 + ((size_t)bl * 625) * 2048 + t * 8;
  float acc0 = 0.f, acc1 = 0.f, acc2 = 0.f, acc3 = 0.f;
  float acc4 = 0.f, acc5 = 0.f, acc6 = 0.f, acc7 = 0.f;
  for (int k = k0; k < k1; k++) {
    uint4 u = *(const uint4*)(base + (size_t)k * 2048);
    acc0 += bf2f((u16)(u.x & 0xffff)); acc1 += bf2f((u16)(u.x >> 16));
    acc2 += bf2f((u16)(u.y & 0xffff)); acc3 += bf2f((u16)(u.y >> 16));
    acc4 += bf2f((u16)(u.z & 0xffff)); acc5 += bf2f((u16)(u.z >> 16));
    acc6 += bf2f((u16)(u.w & 0xffff)); acc7 += bf2f((u16)(u.w >> 16));
  }
  float* dst = part + (((size_t)s * CHI + bl) * 2048) + t * 8;
  dst[0] = acc0; dst[1] = acc1; dst[2] = acc2; dst[3] = acc3;
  dst[4] = acc4; dst[5] = acc5; dst[6] = acc6; dst[7] = acc7;
}

__global__ void reduce_fin(const float* __restrict__ part, float* __restrict__ xg,
                           int c0, int CHI) {
  int idx = blockIdx.x * blockDim.x + threadIdx.x;
  if (idx >= CHI * 2048) return;
  int bl = idx >> 11; int o = idx & 2047;
  float sv = 0.f;
#pragma unroll
  for (int st = 0; st < 5; st++) sv += part[((size_t)st * CHI + bl) * 2048 + o];
  xg[(size_t)(c0 + bl) * 2048 + o] = sv;
}

// ---------------- f MLP: warp per output, fp32 ----------------
__global__ void f_layer(const float* __restrict__ x, int ldx, int Kin,
                        const float* __restrict__ Wf, const float* __restrict__ bf_,
                        float* __restrict__ y, int ldy, int Nout, float scale, int relu) {
  int gwid = (blockIdx.x * blockDim.x + threadIdx.x) >> 6;
  int lane = threadIdx.x & 63;
  if (gwid >= 64 * Nout) return;
  int b = gwid / Nout, o = gwid % Nout;
  const float* xp = x + (size_t)b * ldx;
  const float* wp = Wf + (size_t)o * Kin;
  float s = 0.f;
  for (int k = lane; k < Kin; k += 64) s += xp[k] * wp[k];
  for (int off = 32; off > 0; off >>= 1) s += __shfl_down(s, off);
  if (lane == 0) {
    float v = s * scale + bf_[o];
    if (relu) v = v > 0.f ? v : 0.f;
    y[(size_t)b * ldy + o] = v;
  }
}

__global__ void lsm_kernel(const float* __restrict__ xf4, float* __restrict__ out) {
  int b = blockIdx.x * blockDim.x + threadIdx.x;
  if (b >= 64) return;
  const float* x = xf4 + b * 16;
  float m = x[0];
  for (int i = 1; i < 10; i++) m = fmaxf(m, x[i]);
  float s = 0.f;
  for (int i = 0; i < 10; i++) s += expf(x[i] - m);
  float ls = logf(s);
  for (int i = 0; i < 10; i++) out[b * 10 + i] = x[i] - m - ls;
}

// ---------------- host ----------------
extern "C" void kernel_launch(void* const* d_in, const int* in_sizes, int n_in,
                              void* d_out, int out_size, void* d_ws, size_t ws_size,
                              hipStream_t stream) {
  const float* img = (const float*)d_in[0];
  const float* qst = (const float*)d_in[1];
  const float* w1 = (const float*)d_in[2];  const float* b1 = (const float*)d_in[3];
  const float* w2 = (const float*)d_in[4];  const float* b2 = (const float*)d_in[5];
  const float* w3 = (const float*)d_in[6];  const float* b3 = (const float*)d_in[7];
  const float* w4 = (const float*)d_in[8];  const float* b4 = (const float*)d_in[9];
  const float* g1 = (const float*)d_in[10]; const float* be1 = (const float*)d_in[11];
  const float* g2 = (const float*)d_in[12]; const float* be2 = (const float*)d_in[13];
  const float* g3 = (const float*)d_in[14]; const float* be3 = (const float*)d_in[15];
  const float* g4 = (const float*)d_in[16]; const float* be4 = (const float*)d_in[17];
  const float* gw1 = (const float*)d_in[18]; const float* gb1 = (const float*)d_in[19];
  const float* gw2 = (const float*)d_in[20]; const float* gb2 = (const float*)d_in[21];
  const float* gw3 = (const float*)d_in[22]; const float* gb3 = (const float*)d_in[23];
  const float* gw4 = (const float*)d_in[24]; const float* gb4 = (const float*)d_in[25];
  const float* fw1 = (const float*)d_in[26]; const float* fb1 = (const float*)d_in[27];
  const float* fw2 = (const float*)d_in[28]; const float* fb2 = (const float*)d_in[29];
  const float* fw3 = (const float*)d_in[30]; const float* fb3 = (const float*)d_in[31];
  const float* fw4 = (const float*)d_in[32]; const float* fb4 = (const float*)d_in[33];
  float* out = (float*)d_out;

  // ---- persistent region (slim) ----
  char* P = (char*)d_ws;
  auto alloc = [&](size_t bytes) -> char* {
    char* r = P; P += (bytes + 255) & ~(size_t)255; return r;
  };
  u16* Wp2 = (u16*)alloc(2048ull * 2048 * 2);
  u16* Wp3 = (u16*)alloc(2048ull * 2048 * 2);
  u16* Wp4 = (u16*)alloc(2048ull * 2048 * 2);
  u16* Afu = (u16*)alloc(1664ull * 2048 * 2);   // bf16 layer-1 outputs
  u16* Bfu = (u16*)alloc(1664ull * 2048 * 2);
  float* Q = (float*)alloc(64ull * 2048 * 4);
  float* bp = (float*)alloc(3ull * 2048 * 4);
  float* xg = (float*)alloc(64ull * 2048 * 4);
  float* xf1 = (float*)alloc(64ull * 1024 * 4);
  float* xf2 = (float*)alloc(64ull * 512 * 4);
  float* xf3 = (float*)alloc(64ull * 128 * 4);
  float* xf4 = (float*)alloc(64ull * 16 * 4);

  // ---- scratch region (conv bufs, obj/W1 packs, and h bufs all alias) ----
  char* scratch = P;
  size_t scratch_avail = ws_size - (size_t)(scratch - (char*)d_ws);
  auto salloc = [&](char*& sp, size_t bytes) -> char* {
    char* r = sp; sp += (bytes + 255) & ~(size_t)255; return r;
  };
  // conv-phase layout; obj/W1a/W1b overlay C1 (C1 dead before they're written)
  char* sp = scratch;
  float* C1 = (float*)salloc(sp, 92416ull * 32 * 4);
  u16*   X2 = (u16*)salloc(sp, 23168ull * 288 * 2);
  float* C2 = (float*)salloc(sp, 23168ull * 128 * 4);
  u16*   X3 = (u16*)salloc(sp, 6400ull * 576 * 2);
  float* C3 = (float*)salloc(sp, 6400ull * 128 * 4);
  u16*   X4 = (u16*)salloc(sp, 1664ull * 1152 * 2);
  float* C4 = (float*)salloc(sp, 1664ull * 256 * 4);
  u16*  Wc2 = (u16*)salloc(sp, 128ull * 288 * 2);
  u16*  Wc3 = (u16*)salloc(sp, 128ull * 576 * 2);
  u16*  Wc4 = (u16*)salloc(sp, 256ull * 1152 * 2);
  float* bc2 = (float*)salloc(sp, 128 * 4);
  float* bc3 = (float*)salloc(sp, 128 * 4);
  float* bc4 = (float*)salloc(sp, 256 * 4);
  float* bnp = (float*)salloc(sp, BN_S * 512 * 4);
  float* ss  = (float*)salloc(sp, 512 * 4);
  // overlay region (inside C1's footprint, used only after conv stack)
  char* op = scratch;
  u16* obj = (u16*)salloc(op, 1664ull * 256 * 2);
  u16* W1a = (u16*)salloc(op, 2048ull * 256 * 2);
  u16* W1b = (u16*)salloc(op, 2048ull * 256 * 2);

  // h-phase buffers: pick largest CHI whose buffers fit scratch
  int cands[7] = {64, 32, 16, 8, 4, 2, 1};
  int CHI = 1;
  size_t Mp = 768;
  for (int ci = 0; ci < 7; ci++) {
    size_t mp = (((size_t)cands[ci] * 625 + 255) / 256) * 256;
    size_t hb = (mp * 2048 * 2 + 255) & ~(size_t)255;
    size_t rp = ((size_t)5 * cands[ci] * 2048 * 4 + 255) & ~(size_t)255;
    if (2 * hb + rp <= scratch_avail) {
      CHI = cands[ci]; Mp = mp; break;
    }
  }
  char* hp = scratch;
  u16* h0  = (u16*)salloc(hp, Mp * 2048 * 2);
  u16* h1b = (u16*)salloc(hp, Mp * 2048 * 2);
  float* rpart = (float*)salloc(hp, (size_t)5 * CHI * 2048 * 4);

  // ---- conv weight/bias packs ----
  pack_convw<<<(128 * 288 + 255) / 256, 256, 0, stream>>>(w2, Wc2, 64, 32, 128);
  pack_convw<<<(128 * 576 + 255) / 256, 256, 0, stream>>>(w3, Wc3, 128, 64, 128);
  pack_convw<<<(256 * 1152 + 255) / 256, 256, 0, stream>>>(w4, Wc4, 256, 128, 256);
  pad_bias<<<1, 256, 0, stream>>>(b2, bc2, 64, 128);
  pad_bias<<<1, 256, 0, stream>>>(b3, bc3, 128, 128);
  pad_bias<<<1, 256, 0, stream>>>(b4, bc4, 256, 256);

  // ---- conv stack ----
  conv1_nhwc<<<(92416 * 32 + 255) / 256, 256, 0, stream>>>(img, w1, b1, C1);
  bn_partial<<<dim3(32, BN_S), 256, 0, stream>>>(C1, 32, 92416, bnp);
  bn_final<<<1, 256, 0, stream>>>(bnp, g1, be1, ss, 32, 92416);
  bnrelu_im2col<<<(23168 * 9 * 8 + 255) / 256, 256, 0, stream>>>(C1, 32, 38, 38, ss, X2, 19, 19, 32, 23168);
  gemm_bt<2><<<181, 256, 0, stream>>>(X2, 288, Wc2, 288, C2, nullptr, 128, bc2, 9, 1);

  bn_partial<<<dim3(64, BN_S), 256, 0, stream>>>(C2, 128, 23104, bnp);
  bn_final<<<1, 256, 0, stream>>>(bnp, g2, be2, ss, 64, 23104);
  bnrelu_im2col<<<(6400 * 9 * 16 + 255) / 256, 256, 0, stream>>>(C2, 128, 19, 19, ss, X3, 10, 10, 64, 6400);
  gemm_bt<2><<<50, 256, 0, stream>>>(X3, 576, Wc3, 576, C3, nullptr, 128, bc3, 18, 1);

  bn_partial<<<dim3(128, BN_S), 256, 0, stream>>>(C3, 128, 6400, bnp);
  bn_final<<<1, 256, 0, stream>>>(bnp, g3, be3, ss, 128, 6400);
  bnrelu_im2col<<<(1664 * 9 * 32 + 255) / 256, 256, 0, stream>>>(C3, 128, 10, 10, ss, X4, 5, 5, 128, 1664);
  gemm_bt<2><<<26, 256, 0, stream>>>(X4, 1152, Wc4, 1152, C4, nullptr, 256, bc4, 36, 2);

  bn_partial<<<dim3(256, BN_S), 256, 0, stream>>>(C4, 256, 1600, bnp);
  bn_final<<<1, 256, 0, stream>>>(bnp, g4, be4, ss, 256, 1600);
  obj_from_c4<<<(1664 * 256 + 255) / 256, 256, 0, stream>>>(C4, ss, obj);

  // ---- MLP packs ----
  pack_w1<<<2048, 256, 0, stream>>>(gw1, W1a, W1b);
  pack_wbig<<<16384, 256, 0, stream>>>(gw2, Wp2);
  pack_wbig<<<16384, 256, 0, stream>>>(gw3, Wp3);
  pack_wbig<<<16384, 256, 0, stream>>>(gw4, Wp4);
  pack_bias3<<<8, 256, 0, stream>>>(gb2, gb3, gb4, bp);
  q_build<<<512, 256, 0, stream>>>(qst, gw1, gb1, Q);

  // ---- layer-1 decomposition GEMMs (bf16 raw out) ----
  gemm_bt<3><<<13 * 16, 256, 0, stream>>>(obj, 256, W1a, 256, nullptr, Afu, 2048, nullptr, 8, 16);
  gemm_bt<3><<<13 * 16, 256, 0, stream>>>(obj, 256, W1b, 256, nullptr, Bfu, 2048, nullptr, 8, 16);

  // ---- chunked g-MLP with 32x32 pipelined 256^2 GEMM ----
  int NC = 64 / CHI;
  int mtiles = (int)(Mp / 256);
  for (int c = 0; c < NC; c++) {
    int c0 = c * CHI;
    int nrows = CHI * 625;
    h1_build<<<(unsigned)Mp, 256, 0, stream>>>(Afu, Bfu, Q, h0, c0, nrows);
    gemm256<64><<<mtiles * 8, 512, 0, stream>>>(h0, Wp2, h1b, bp);
    gemm256<64><<<mtiles * 8, 512, 0, stream>>>(h1b, Wp3, h0, bp + 2048);
    gemm256<64><<<mtiles * 8, 512, 0, stream>>>(h0, Wp4, h1b, bp + 4096);
    reduce_part<<<dim3(CHI, 5), 256, 0, stream>>>(h1b, rpart, CHI);
    reduce_fin<<<(CHI * 2048 + 255) / 256, 256, 0, stream>>>(rpart, xg, c0, CHI);
  }

  // ---- f MLP ----
  {
    int nthreads;
    nthreads = 64 * 1000 * 64;
    f_layer<<<(nthreads + 255) / 256, 256, 0, stream>>>(xg, 2048, 2000, fw1, fb1, xf1, 1024, 1000, 1.f / 625.f, 1);
    nthreads = 64 * 500 * 64;
    f_layer<<<(nthreads + 255) / 256, 256, 0, stream>>>(xf1, 1024, 1000, fw2, fb2, xf2, 512, 500, 1.f, 1);
    nthreads = 64 * 100 * 64;
    f_layer<<<(nthreads + 255) / 256, 256, 0, stream>>>(xf2, 512, 500, fw3, fb3, xf3, 128, 100, 1.f, 1);
    nthreads = 64 * 10 * 64;
    f_layer<<<(nthreads + 255) / 256, 256, 0, stream>>>(xf3, 128, 100, fw4, fb4, xf4, 16, 10, 1.f, 0);
  }
  lsm_kernel<<<1, 64, 0, stream>>>(xf4, out);
}

// Round 7
// 1681.698 us; speedup vs baseline: 1.0464x; 1.0464x over previous
//
#include <hip/hip_runtime.h>

typedef unsigned short u16;
typedef unsigned int u32;
typedef __attribute__((ext_vector_type(8))) short bf16x8;
typedef __attribute__((ext_vector_type(4))) float f32x4;

#define BN_EPS 1e-5f
#define BN_S 16

__device__ __forceinline__ float bf2f(u16 u) {
  union { unsigned u; float f; } x; x.u = ((unsigned)u) << 16; return x.f;
}
__device__ __forceinline__ u16 f2bf(float f) {
  union { float f; unsigned u; } x; x.f = f;
  unsigned r = x.u + 0x7FFFu + ((x.u >> 16) & 1u);
  return (u16)(r >> 16);
}

// ---------------- conv1: direct, NHWC output [64*38*38][32] fp32 ----------------
__global__ void conv1_nhwc(const float* __restrict__ img, const float* __restrict__ w,
                           const float* __restrict__ b, float* __restrict__ C1) {
  int idx = blockIdx.x * blockDim.x + threadIdx.x;
  if (idx >= 92416 * 32) return;
  int co = idx & 31; int row = idx >> 5;
  int wo = row % 38; int t = row / 38;
  int ho = t % 38; int n = t / 38;
  int hi0 = ho * 2 - 1, wi0 = wo * 2 - 1;
  float acc = b[co];
  const float* wp = w + co * 27;
#pragma unroll
  for (int ci = 0; ci < 3; ci++) {
    const float* ip = img + ((size_t)(n * 3 + ci) * 75) * 75;
    const float* wc = wp + ci * 9;
#pragma unroll
    for (int kh = 0; kh < 3; kh++) {
      int hi = hi0 + kh;
      if (hi < 0 || hi >= 75) continue;
#pragma unroll
      for (int kw = 0; kw < 3; kw++) {
        int wi = wi0 + kw;
        if (wi < 0 || wi >= 75) continue;
        acc += ip[hi * 75 + wi] * wc[kh * 3 + kw];
      }
    }
  }
  C1[idx] = acc;
}

// ---------------- BN column-stats (deterministic 2-stage) ----------------
__global__ void bn_partial(const float* __restrict__ C, int ldc, int M,
                           float* __restrict__ part) {
  int c = blockIdx.x; int s = blockIdx.y; int t = threadIdx.x;
  int rowsPer = (M + BN_S - 1) / BN_S;
  int r0 = s * rowsPer; int r1 = r0 + rowsPer; if (r1 > M) r1 = M;
  float s1 = 0.f, s2 = 0.f;
  for (int r = r0 + t; r < r1; r += 256) {
    float v = C[(size_t)r * ldc + c]; s1 += v; s2 += v * v;
  }
  __shared__ float l1[256], l2[256];
  l1[t] = s1; l2[t] = s2; __syncthreads();
  for (int off = 128; off > 0; off >>= 1) {
    if (t < off) { l1[t] += l1[t + off]; l2[t] += l2[t + off]; }
    __syncthreads();
  }
  if (t == 0) { part[s * 512 + c] = l1[0]; part[s * 512 + 256 + c] = l2[0]; }
}

__global__ void bn_final(const float* __restrict__ part, const float* __restrict__ gamma,
                         const float* __restrict__ beta, float* __restrict__ ss,
                         int C, int M) {
  int c = threadIdx.x;
  if (c >= C) { if (c < 256) { ss[c] = 0.f; ss[256 + c] = 0.f; } return; }
  float s1 = 0.f, s2 = 0.f;
#pragma unroll
  for (int s = 0; s < BN_S; s++) { s1 += part[s * 512 + c]; s2 += part[s * 512 + 256 + c]; }
  float mu = s1 / M;
  float var = s2 / M - mu * mu;
  float sc = gamma[c] * rsqrtf(var + BN_EPS);
  ss[c] = sc; ss[256 + c] = beta[c] - mu * sc;
}

// ---------------- fused BN+ReLU + im2col -> bf16 X[row][tap*Ci+ci] ----------------
__global__ void bnrelu_im2col(const float* __restrict__ Cprev, int ldprev, int Hp, int Wp,
                              const float* __restrict__ ss, u16* __restrict__ X,
                              int Ho, int Wo, int Ci, int Mp) {
  int civ4 = Ci >> 2;
  int idx = blockIdx.x * blockDim.x + threadIdx.x;
  int total = Mp * 9 * civ4;
  if (idx >= total) return;
  int cv = idx % civ4; int t2 = idx / civ4;
  int tap = t2 % 9; int row = t2 / 9;
  int K = 9 * Ci;
  u16* dst = X + (size_t)row * K + tap * Ci + cv * 4;
  int HW = Ho * Wo;
  int Mvalid = 64 * HW;
  ushort4 o4; o4.x = 0; o4.y = 0; o4.z = 0; o4.w = 0;
  if (row < Mvalid) {
    int wo = row % Wo; int t = row / Wo;
    int ho = t % Ho; int n = t / Ho;
    int kh = tap / 3, kw = tap % 3;
    int hi = ho * 2 - 1 + kh, wi = wo * 2 - 1 + kw;
    if (hi >= 0 && hi < Hp && wi >= 0 && wi < Wp) {
      const float* src = Cprev + ((size_t)((n * Hp + hi) * Wp + wi)) * ldprev + cv * 4;
      float4 v = *(const float4*)src;
      int c0 = cv * 4;
      float a;
      a = v.x * ss[c0 + 0] + ss[256 + c0 + 0]; o4.x = f2bf(a > 0.f ? a : 0.f);
      a = v.y * ss[c0 + 1] + ss[256 + c0 + 1]; o4.y = f2bf(a > 0.f ? a : 0.f);
      a = v.z * ss[c0 + 2] + ss[256 + c0 + 2]; o4.z = f2bf(a > 0.f ? a : 0.f);
      a = v.w * ss[c0 + 3] + ss[256 + c0 + 3]; o4.w = f2bf(a > 0.f ? a : 0.f);
    }
  }
  *(ushort4*)dst = o4;
}

// ---------------- conv weight pack ----------------
__global__ void pack_convw(const float* __restrict__ w, u16* __restrict__ Wp,
                           int Co, int Ci, int Cop) {
  int K = 9 * Ci;
  int idx = blockIdx.x * blockDim.x + threadIdx.x;
  if (idx >= Cop * K) return;
  int k = idx % K; int co = idx / K;
  int tap = k / Ci; int ci = k % Ci;
  float v = (co < Co) ? w[((size_t)co * Ci + ci) * 9 + tap] : 0.f;
  Wp[idx] = f2bf(v);
}

__global__ void pad_bias(const float* __restrict__ b, float* __restrict__ bc, int Co, int Cop) {
  int i = blockIdx.x * blockDim.x + threadIdx.x;
  if (i < Cop) bc[i] = (i < Co) ? b[i] : 0.f;
}

// ---------------- obj pack from C4 with BN+ReLU ----------------
__global__ void obj_from_c4(const float* __restrict__ C4, const float* __restrict__ ss,
                            u16* __restrict__ obj) {
  int idx = blockIdx.x * blockDim.x + threadIdx.x;
  if (idx >= 1664 * 256) return;
  int c = idx & 255; int row = idx >> 8;
  float v = 0.f;
  if (row < 1600) {
    float x = C4[(size_t)row * 256 + c];
    x = x * ss[c] + ss[256 + c];
    v = x > 0.f ? x : 0.f;
  }
  obj[idx] = f2bf(v);
}

// ---------------- MLP weight packs ----------------
__global__ void pack_w1(const float* __restrict__ gw1, u16* __restrict__ W1a, u16* __restrict__ W1b) {
  int idx = blockIdx.x * blockDim.x + threadIdx.x;
  if (idx >= 2048 * 256) return;
  int k = idx & 255, n = idx >> 8;
  float a = 0.f, b = 0.f;
  if (n < 2000) { a = gw1[(size_t)n * 523 + k]; b = gw1[(size_t)n * 523 + 256 + k]; }
  W1a[idx] = f2bf(a); W1b[idx] = f2bf(b);
}

__global__ void pack_wbig(const float* __restrict__ gw, u16* __restrict__ Wp) {
  int idx = blockIdx.x * blockDim.x + threadIdx.x;
  if (idx >= 2048 * 2048) return;
  int k = idx & 2047, n = idx >> 11;
  float v = (n < 2000 && k < 2000) ? gw[(size_t)n * 2000 + k] : 0.f;
  Wp[idx] = f2bf(v);
}

__global__ void pack_bias3(const float* __restrict__ b2, const float* __restrict__ b3,
                           const float* __restrict__ b4, float* __restrict__ bp) {
  int i = blockIdx.x * blockDim.x + threadIdx.x;
  if (i >= 2048) return;
  bp[i]        = (i < 2000) ? b2[i] : 0.f;
  bp[2048 + i] = (i < 2000) ? b3[i] : 0.f;
  bp[4096 + i] = (i < 2000) ? b4[i] : 0.f;
}

// ---------------- Q[b][o] = gb1[o] + qst[b] . gw1[o][512:523] ----------------
__global__ void q_build(const float* __restrict__ qst, const float* __restrict__ gw1,
                        const float* __restrict__ gb1, float* __restrict__ Q) {
  int idx = blockIdx.x * blockDim.x + threadIdx.x;
  if (idx >= 64 * 2048) return;
  int o = idx & 2047, b = idx >> 11;
  float v = 0.f;
  if (o < 2000) {
    v = gb1[o];
    const float* w = gw1 + (size_t)o * 523 + 512;
    const float* q = qst + b * 11;
#pragma unroll
    for (int k = 0; k < 11; k++) v += q[k] * w[k];
  }
  Q[idx] = v;
}

// ---------------- global->LDS async ----------------
typedef const __attribute__((address_space(1))) u32* gas1;
typedef __attribute__((address_space(3))) u32* las3;
__device__ __forceinline__ void gld16(const void* g, void* l) {
  __builtin_amdgcn_global_load_lds((gas1)g, (las3)l, 16, 0, 0);
}

// ---------------- 128^2 bf16 MFMA GEMM (small/medium shapes) ----------------
// EPI 0: fp32 raw; EPI 2: fp32 acc+bias; EPI 3: bf16 raw
template <int EPI>
__global__ __launch_bounds__(256) void gemm_bt(
    const u16* __restrict__ A, int lda,
    const u16* __restrict__ W, int ldb,
    float* __restrict__ Cf, u16* __restrict__ Cb, int ldc,
    const float* __restrict__ bias, int KT, int NTN) {
  __shared__ __align__(16) char lds[32768];
  int bid = blockIdx.x;
  int wg;
  if ((gridDim.x & 7) == 0) {
    int cpx = gridDim.x >> 3;
    wg = (bid & 7) * cpx + (bid >> 3);
  } else {
    wg = bid;
  }
  int mt = wg / NTN, nt = wg % NTN;
  int tid = threadIdx.x;
  int wave = tid >> 6, lane = tid & 63;
  int r = lane & 15, g = lane >> 4;
  int wr = wave >> 1, wc = wave & 1;

  const u16* Asrc = A + (size_t)(mt * 128 + wave * 32 + r) * lda + g * 8;
  const u16* Wsrc = W + (size_t)(nt * 128 + wave * 32 + r) * ldb + g * 8;

  f32x4 acc[4][4];
#pragma unroll
  for (int i = 0; i < 4; i++)
#pragma unroll
    for (int j = 0; j < 4; j++) acc[i][j] = (f32x4){0.f, 0.f, 0.f, 0.f};

  {
    char* Al = lds; char* Wl = lds + 8192;
    gld16(Asrc, Al + wave * 2048);
    gld16(Asrc + (size_t)16 * lda, Al + wave * 2048 + 1024);
    gld16(Wsrc, Wl + wave * 2048);
    gld16(Wsrc + (size_t)16 * ldb, Wl + wave * 2048 + 1024);
  }
  __syncthreads();

  int buf = 0;
  for (int kt = 0; kt < KT; kt++) {
    if (kt + 1 < KT) {
      int k0 = (kt + 1) * 32;
      char* Al = lds + (buf ^ 1) * 16384; char* Wl = Al + 8192;
      gld16(Asrc + k0, Al + wave * 2048);
      gld16(Asrc + k0 + (size_t)16 * lda, Al + wave * 2048 + 1024);
      gld16(Wsrc + k0, Wl + wave * 2048);
      gld16(Wsrc + k0 + (size_t)16 * ldb, Wl + wave * 2048 + 1024);
    }
    char* Al = lds + buf * 16384; char* Wl = Al + 8192;
    bf16x8 a[4], w[4];
#pragma unroll
    for (int i = 0; i < 4; i++) a[i] = *(const bf16x8*)(Al + (wr * 4 + i) * 1024 + lane * 16);
#pragma unroll
    for (int j = 0; j < 4; j++) w[j] = *(const bf16x8*)(Wl + (wc * 4 + j) * 1024 + lane * 16);
#pragma unroll
    for (int i = 0; i < 4; i++)
#pragma unroll
      for (int j = 0; j < 4; j++)
        acc[i][j] = __builtin_amdgcn_mfma_f32_16x16x32_bf16(a[i], w[j], acc[i][j], 0, 0, 0);
    __syncthreads();
    buf ^= 1;
  }

  int rowb = mt * 128 + wr * 64 + (lane >> 4) * 4;
  int colb = nt * 128 + wc * 64 + (lane & 15);
#pragma unroll
  for (int i = 0; i < 4; i++) {
#pragma unroll
    for (int j = 0; j < 4; j++) {
      int col = colb + j * 16;
      float bv = (EPI == 2) ? bias[col] : 0.f;
#pragma unroll
      for (int q = 0; q < 4; q++) {
        int row = rowb + i * 16 + q;
        float v = acc[i][j][q];
        if (EPI == 2) {
          Cf[(size_t)row * ldc + col] = v + bv;
        } else if (EPI == 3) {
          Cb[(size_t)row * ldc + col] = f2bf(v);
        } else {
          Cf[(size_t)row * ldc + col] = v;
        }
      }
    }
  }
}

// ---------------- 256^2 bf16 GEMM — m201-style 8-phase schedule ----------------
// C = relu(A@W^T + bias) -> bf16. lda=ldb=ldc=2048. BK=64, 2-deep dbuf (2x64KB).
// 8 waves (2M x 4N); per-wave out 128x64 (8m x 4n frags). Per K-tile: 4 phases,
// each = {ds_read a-pair (+all b at Q0) | stage one half-tile | barrier |
//         setprio(1) 16 MFMA setprio(0) | [Q3: vmcnt(4)] | barrier}.
// Stage map: Ah0(t+1)@Q0(t), Ah1(t+1)@Q1(t), Bh0(t+2)@Q1(t), Bh1(t+2)@Q2(t).
#define MF16(d, av, bv) d = __builtin_amdgcn_mfma_f32_16x16x32_bf16(av, bv, d, 0, 0, 0)

template <int NT>
__global__ __launch_bounds__(512, 2) void gemm256(
    const u16* __restrict__ A, const u16* __restrict__ W,
    u16* __restrict__ Cb, const float* __restrict__ bias) {
  __shared__ __align__(16) char lds[131072];
  int bid = blockIdx.x;
  int cpx = gridDim.x >> 3;                 // grid = mtiles*8, always %8==0
  int wg = (bid & 7) * cpx + (bid >> 3);
  int mt = wg >> 3, nt = wg & 7;
  int tid = threadIdx.x;
  int wave = tid >> 6, lane = tid & 63;
  int lane16 = lane * 16;
  int wr = wave >> 2, wc = wave & 3;
  int wcl = wc & 1, wch = wc >> 1;

  // stage one A half-tile (128 rows x 64 k) of tile tt into slot (tt&1), half h.
  // frag-unit u = wave*2+j: i = u>>1 (16-row frag), ks = u&1 (k-half).
  auto stageA = [&](int tt, int h) {
#pragma unroll
    for (int j = 0; j < 2; j++) {
      int u = wave * 2 + j;
      const u16* src = A + (size_t)(mt * 256 + h * 128 + (u >> 1) * 16 + (lane & 15)) * 2048
                         + tt * 64 + (u & 1) * 32 + (lane >> 4) * 8;
      gld16(src, lds + (tt & 1) * 65536 + h * 16384 + u * 1024);
    }
  };
  auto stageB = [&](int tt, int h) {
#pragma unroll
    for (int j = 0; j < 2; j++) {
      int u = wave * 2 + j;
      const u16* src = W + (size_t)(nt * 256 + h * 128 + (u >> 1) * 16 + (lane & 15)) * 2048
                         + tt * 64 + (u & 1) * 32 + (lane >> 4) * 8;
      gld16(src, lds + (tt & 1) * 65536 + 32768 + h * 16384 + u * 1024);
    }
  };

  f32x4 acc[8][4];
#pragma unroll
  for (int i = 0; i < 8; i++)
#pragma unroll
    for (int j = 0; j < 4; j++) acc[i][j] = (f32x4){0.f, 0.f, 0.f, 0.f};

  // prologue: tile 0 fully (8 loads/thread) + tile 1 B-halves (4 loads/thread)
  stageA(0, 0); stageA(0, 1); stageB(0, 0); stageB(0, 1);
  stageB(1, 0); stageB(1, 1);
  asm volatile("s_waitcnt vmcnt(4)" ::: "memory");   // tile 0 landed; t1 B in flight
  __builtin_amdgcn_s_barrier();

  bf16x8 b00, b01, b10, b11, b20, b21, b30, b31;

#define PHASE(Q)                                                                 \
  {                                                                              \
    const char* Ab = lds + (t & 1) * 65536 + wr * 16384;                         \
    const char* Bb = lds + (t & 1) * 65536 + 32768 + wch * 16384;                \
    if (Q == 0) {                                                                \
      b00 = *(const bf16x8*)(Bb + ((wcl * 4 + 0) * 2 + 0) * 1024 + lane16);      \
      b01 = *(const bf16x8*)(Bb + ((wcl * 4 + 0) * 2 + 1) * 1024 + lane16);      \
      b10 = *(const bf16x8*)(Bb + ((wcl * 4 + 1) * 2 + 0) * 1024 + lane16);      \
      b11 = *(const bf16x8*)(Bb + ((wcl * 4 + 1) * 2 + 1) * 1024 + lane16);      \
      b20 = *(const bf16x8*)(Bb + ((wcl * 4 + 2) * 2 + 0) * 1024 + lane16);      \
      b21 = *(const bf16x8*)(Bb + ((wcl * 4 + 2) * 2 + 1) * 1024 + lane16);      \
      b30 = *(const bf16x8*)(Bb + ((wcl * 4 + 3) * 2 + 0) * 1024 + lane16);      \
      b31 = *(const bf16x8*)(Bb + ((wcl * 4 + 3) * 2 + 1) * 1024 + lane16);      \
    }                                                                            \
    bf16x8 a00 = *(const bf16x8*)(Ab + ((2 * Q + 0) * 2 + 0) * 1024 + lane16);   \
    bf16x8 a01 = *(const bf16x8*)(Ab + ((2 * Q + 0) * 2 + 1) * 1024 + lane16);   \
    bf16x8 a10 = *(const bf16x8*)(Ab + ((2 * Q + 1) * 2 + 0) * 1024 + lane16);   \
    bf16x8 a11 = *(const bf16x8*)(Ab + ((2 * Q + 1) * 2 + 1) * 1024 + lane16);   \
    if (Q == 0) { if (t + 1 < NT) stageA(t + 1, 0); }                            \
    if (Q == 1) { if (t + 1 < NT) stageA(t + 1, 1);                              \
                  if (t + 2 < NT) stageB(t + 2, 0); }                            \
    if (Q == 2) { if (t + 2 < NT) stageB(t + 2, 1); }                            \
    __builtin_amdgcn_s_barrier();                                                \
    __builtin_amdgcn_s_setprio(1);                                               \
    MF16(acc[2 * Q + 0][0], a00, b00); MF16(acc[2 * Q + 0][0], a01, b01);        \
    MF16(acc[2 * Q + 0][1], a00, b10); MF16(acc[2 * Q + 0][1], a01, b11);        \
    MF16(acc[2 * Q + 0][2], a00, b20); MF16(acc[2 * Q + 0][2], a01, b21);        \
    MF16(acc[2 * Q + 0][3], a00, b30); MF16(acc[2 * Q + 0][3], a01, b31);        \
    MF16(acc[2 * Q + 1][0], a10, b00); MF16(acc[2 * Q + 1][0], a11, b01);        \
    MF16(acc[2 * Q + 1][1], a10, b10); MF16(acc[2 * Q + 1][1], a11, b11);        \
    MF16(acc[2 * Q + 1][2], a10, b20); MF16(acc[2 * Q + 1][2], a11, b21);        \
    MF16(acc[2 * Q + 1][3], a10, b30); MF16(acc[2 * Q + 1][3], a11, b31);        \
    __builtin_amdgcn_s_setprio(0);                                               \
    if (Q == 3) { asm volatile("s_waitcnt vmcnt(4)" ::: "memory"); }             \
    __builtin_amdgcn_s_barrier();                                                \
  }

#pragma unroll 1
  for (int t = 0; t < NT; t++) {
    PHASE(0)
    PHASE(1)
    PHASE(2)
    PHASE(3)
  }
#undef PHASE

  // epilogue: frag D layout col=lane&15, row=(lane>>4)*4+q
  int rowb = mt * 256 + wr * 128 + (lane >> 4) * 4;
  int colb = nt * 256 + wc * 64 + (lane & 15);
#pragma unroll
  for (int i = 0; i < 8; i++) {
#pragma unroll
    for (int j = 0; j < 4; j++) {
      int col = colb + j * 16;
      float bv = bias[col];
#pragma unroll
      for (int q = 0; q < 4; q++) {
        int row = rowb + i * 16 + q;
        float v = acc[i][j][q] + bv;
        v = v > 0.f ? v : 0.f;
        Cb[(size_t)row * 2048 + col] = f2bf(v);
      }
    }
  }
}

// ---------------- h1 = relu(A_i + B_j + Q_b), bf16 in/out ----------------
__global__ void h1_build(const u16* __restrict__ Af, const u16* __restrict__ Bf,
                         const float* __restrict__ Q, u16* __restrict__ h1,
                         int c0, int nrows) {
  int row = blockIdx.x;
  int t = threadIdx.x;
  u16* dst = h1 + (size_t)row * 2048;
  if (row >= nrows) {
#pragma unroll
    for (int it = 0; it < 2; it++) {
      int o = it * 1024 + t * 4;
      ushort4 z; z.x = 0; z.y = 0; z.z = 0; z.w = 0;
      *(ushort4*)(dst + o) = z;
    }
    return;
  }
  int b_local = row / 625; int rem = row % 625;
  int i = rem / 25, j = rem % 25;
  int b = c0 + b_local;
  const u16* Ap = Af + (size_t)(b * 25 + i) * 2048;
  const u16* Bp = Bf + (size_t)(b * 25 + j) * 2048;
  const float* Qp = Q + (size_t)b * 2048;
#pragma unroll
  for (int it = 0; it < 2; it++) {
    int o = it * 1024 + t * 4;
    ushort4 a4 = *(const ushort4*)(Ap + o);
    ushort4 b4 = *(const ushort4*)(Bp + o);
    float4 qv = *(const float4*)(Qp + o);
    ushort4 outv;
    float v;
    v = bf2f(a4.x) + bf2f(b4.x) + qv.x; outv.x = f2bf(v > 0.f ? v : 0.f);
    v = bf2f(a4.y) + bf2f(b4.y) + qv.y; outv.y = f2bf(v > 0.f ? v : 0.f);
    v = bf2f(a4.z) + bf2f(b4.z) + qv.z; outv.z = f2bf(v > 0.f ? v : 0.f);
    v = bf2f(a4.w) + bf2f(b4.w) + qv.w; outv.w = f2bf(v > 0.f ? v : 0.f);
    *(ushort4*)(dst + o) = outv;
  }
}

// ---------------- pair-sum reduce, deterministic 2-stage ----------------
__global__ void reduce_part(const u16* __restrict__ h4, float* __restrict__ part, int CHI) {
  int bl = blockIdx.x; int s = blockIdx.y; int t = threadIdx.x;
  int k0 = s * 125, k1 = k0 + 125;
  const u16* base = h4 + ((size_t)bl * 625) * 2048 + t * 8;
  float acc0 = 0.f, acc1 = 0.f, acc2 = 0.f, acc3 = 0.f;
  float acc4 = 0.f, acc5 = 0.f, acc6 = 0.f, acc7 = 0.f;
  for (int k = k0; k < k1; k++) {
    uint4 u = *(const uint4*)(base + (size_t)k * 2048);
    acc0 += bf2f((u16)(u.x & 0xffff)); acc1 += bf2f((u16)(u.x >> 16));
    acc2 += bf2f((u16)(u.y & 0xffff)); acc3 += bf2f((u16)(u.y >> 16));
    acc4 += bf2f((u16)(u.z & 0xffff)); acc5 += bf2f((u16)(u.z >> 16));
    acc6 += bf2f((u16)(u.w & 0xffff)); acc7 += bf2f((u16)(u.w >> 16));
  }
  float* dst = part + (((size_t)s * CHI + bl) * 2048) + t * 8;
  dst[0] = acc0; dst[1] = acc1; dst[2] = acc2; dst[3] = acc3;
  dst[4] = acc4; dst[5] = acc5; dst[6] = acc6; dst[7] = acc7;
}

__global__ void reduce_fin(const float* __restrict__ part, float* __restrict__ xg,
                           int c0, int CHI) {
  int idx = blockIdx.x * blockDim.x + threadIdx.x;
  if (idx >= CHI * 2048) return;
  int bl = idx >> 11; int o = idx & 2047;
  float sv = 0.f;
#pragma unroll
  for (int st = 0; st < 5; st++) sv += part[((size_t)st * CHI + bl) * 2048 + o];
  xg[(size_t)(c0 + bl) * 2048 + o] = sv;
}

// ---------------- f MLP: warp per output, fp32 ----------------
__global__ void f_layer(const float* __restrict__ x, int ldx, int Kin,
                        const float* __restrict__ Wf, const float* __restrict__ bf_,
                        float* __restrict__ y, int ldy, int Nout, float scale, int relu) {
  int gwid = (blockIdx.x * blockDim.x + threadIdx.x) >> 6;
  int lane = threadIdx.x & 63;
  if (gwid >= 64 * Nout) return;
  int b = gwid / Nout, o = gwid % Nout;
  const float* xp = x + (size_t)b * ldx;
  const float* wp = Wf + (size_t)o * Kin;
  float s = 0.f;
  for (int k = lane; k < Kin; k += 64) s += xp[k] * wp[k];
  for (int off = 32; off > 0; off >>= 1) s += __shfl_down(s, off);
  if (lane == 0) {
    float v = s * scale + bf_[o];
    if (relu) v = v > 0.f ? v : 0.f;
    y[(size_t)b * ldy + o] = v;
  }
}

__global__ void lsm_kernel(const float* __restrict__ xf4, float* __restrict__ out) {
  int b = blockIdx.x * blockDim.x + threadIdx.x;
  if (b >= 64) return;
  const float* x = xf4 + b * 16;
  float m = x[0];
  for (int i = 1; i < 10; i++) m = fmaxf(m, x[i]);
  float s = 0.f;
  for (int i = 0; i < 10; i++) s += expf(x[i] - m);
  float ls = logf(s);
  for (int i = 0; i < 10; i++) out[b * 10 + i] = x[i] - m - ls;
}

// ---------------- host ----------------
extern "C" void kernel_launch(void* const* d_in, const int* in_sizes, int n_in,
                              void* d_out, int out_size, void* d_ws, size_t ws_size,
                              hipStream_t stream) {
  const float* img = (const float*)d_in[0];
  const float* qst = (const float*)d_in[1];
  const float* w1 = (const float*)d_in[2];  const float* b1 = (const float*)d_in[3];
  const float* w2 = (const float*)d_in[4];  const float* b2 = (const float*)d_in[5];
  const float* w3 = (const float*)d_in[6];  const float* b3 = (const float*)d_in[7];
  const float* w4 = (const float*)d_in[8];  const float* b4 = (const float*)d_in[9];
  const float* g1 = (const float*)d_in[10]; const float* be1 = (const float*)d_in[11];
  const float* g2 = (const float*)d_in[12]; const float* be2 = (const float*)d_in[13];
  const float* g3 = (const float*)d_in[14]; const float* be3 = (const float*)d_in[15];
  const float* g4 = (const float*)d_in[16]; const float* be4 = (const float*)d_in[17];
  const float* gw1 = (const float*)d_in[18]; const float* gb1 = (const float*)d_in[19];
  const float* gw2 = (const float*)d_in[20]; const float* gb2 = (const float*)d_in[21];
  const float* gw3 = (const float*)d_in[22]; const float* gb3 = (const float*)d_in[23];
  const float* gw4 = (const float*)d_in[24]; const float* gb4 = (const float*)d_in[25];
  const float* fw1 = (const float*)d_in[26]; const float* fb1 = (const float*)d_in[27];
  const float* fw2 = (const float*)d_in[28]; const float* fb2 = (const float*)d_in[29];
  const float* fw3 = (const float*)d_in[30]; const float* fb3 = (const float*)d_in[31];
  const float* fw4 = (const float*)d_in[32]; const float* fb4 = (const float*)d_in[33];
  float* out = (float*)d_out;

  // ---- persistent region (slim) ----
  char* P = (char*)d_ws;
  auto alloc = [&](size_t bytes) -> char* {
    char* r = P; P += (bytes + 255) & ~(size_t)255; return r;
  };
  u16* Wp2 = (u16*)alloc(2048ull * 2048 * 2);
  u16* Wp3 = (u16*)alloc(2048ull * 2048 * 2);
  u16* Wp4 = (u16*)alloc(2048ull * 2048 * 2);
  u16* Afu = (u16*)alloc(1664ull * 2048 * 2);   // bf16 layer-1 outputs
  u16* Bfu = (u16*)alloc(1664ull * 2048 * 2);
  float* Q = (float*)alloc(64ull * 2048 * 4);
  float* bp = (float*)alloc(3ull * 2048 * 4);
  float* xg = (float*)alloc(64ull * 2048 * 4);
  float* xf1 = (float*)alloc(64ull * 1024 * 4);
  float* xf2 = (float*)alloc(64ull * 512 * 4);
  float* xf3 = (float*)alloc(64ull * 128 * 4);
  float* xf4 = (float*)alloc(64ull * 16 * 4);

  // ---- scratch region (conv bufs, obj/W1 packs, and h bufs all alias) ----
  char* scratch = P;
  size_t scratch_avail = ws_size - (size_t)(scratch - (char*)d_ws);
  auto salloc = [&](char*& sp, size_t bytes) -> char* {
    char* r = sp; sp += (bytes + 255) & ~(size_t)255; return r;
  };
  char* sp = scratch;
  float* C1 = (float*)salloc(sp, 92416ull * 32 * 4);
  u16*   X2 = (u16*)salloc(sp, 23168ull * 288 * 2);
  float* C2 = (float*)salloc(sp, 23168ull * 128 * 4);
  u16*   X3 = (u16*)salloc(sp, 6400ull * 576 * 2);
  float* C3 = (float*)salloc(sp, 6400ull * 128 * 4);
  u16*   X4 = (u16*)salloc(sp, 1664ull * 1152 * 2);
  float* C4 = (float*)salloc(sp, 1664ull * 256 * 4);
  u16*  Wc2 = (u16*)salloc(sp, 128ull * 288 * 2);
  u16*  Wc3 = (u16*)salloc(sp, 128ull * 576 * 2);
  u16*  Wc4 = (u16*)salloc(sp, 256ull * 1152 * 2);
  float* bc2 = (float*)salloc(sp, 128 * 4);
  float* bc3 = (float*)salloc(sp, 128 * 4);
  float* bc4 = (float*)salloc(sp, 256 * 4);
  float* bnp = (float*)salloc(sp, BN_S * 512 * 4);
  float* ss  = (float*)salloc(sp, 512 * 4);
  // overlay region (inside C1's footprint, used only after conv stack)
  char* op = scratch;
  u16* obj = (u16*)salloc(op, 1664ull * 256 * 2);
  u16* W1a = (u16*)salloc(op, 2048ull * 256 * 2);
  u16* W1b = (u16*)salloc(op, 2048ull * 256 * 2);

  // h-phase buffers: pick largest CHI whose buffers fit scratch
  int cands[7] = {64, 32, 16, 8, 4, 2, 1};
  int CHI = 1;
  size_t Mp = 768;
  for (int ci = 0; ci < 7; ci++) {
    size_t mp = (((size_t)cands[ci] * 625 + 255) / 256) * 256;
    size_t hb = (mp * 2048 * 2 + 255) & ~(size_t)255;
    size_t rp = ((size_t)5 * cands[ci] * 2048 * 4 + 255) & ~(size_t)255;
    if (2 * hb + rp <= scratch_avail) {
      CHI = cands[ci]; Mp = mp; break;
    }
  }
  char* hp = scratch;
  u16* h0  = (u16*)salloc(hp, Mp * 2048 * 2);
  u16* h1b = (u16*)salloc(hp, Mp * 2048 * 2);
  float* rpart = (float*)salloc(hp, (size_t)5 * CHI * 2048 * 4);

  // ---- conv weight/bias packs ----
  pack_convw<<<(128 * 288 + 255) / 256, 256, 0, stream>>>(w2, Wc2, 64, 32, 128);
  pack_convw<<<(128 * 576 + 255) / 256, 256, 0, stream>>>(w3, Wc3, 128, 64, 128);
  pack_convw<<<(256 * 1152 + 255) / 256, 256, 0, stream>>>(w4, Wc4, 256, 128, 256);
  pad_bias<<<1, 256, 0, stream>>>(b2, bc2, 64, 128);
  pad_bias<<<1, 256, 0, stream>>>(b3, bc3, 128, 128);
  pad_bias<<<1, 256, 0, stream>>>(b4, bc4, 256, 256);

  // ---- conv stack ----
  conv1_nhwc<<<(92416 * 32 + 255) / 256, 256, 0, stream>>>(img, w1, b1, C1);
  bn_partial<<<dim3(32, BN_S), 256, 0, stream>>>(C1, 32, 92416, bnp);
  bn_final<<<1, 256, 0, stream>>>(bnp, g1, be1, ss, 32, 92416);
  bnrelu_im2col<<<(23168 * 9 * 8 + 255) / 256, 256, 0, stream>>>(C1, 32, 38, 38, ss, X2, 19, 19, 32, 23168);
  gemm_bt<2><<<181, 256, 0, stream>>>(X2, 288, Wc2, 288, C2, nullptr, 128, bc2, 9, 1);

  bn_partial<<<dim3(64, BN_S), 256, 0, stream>>>(C2, 128, 23104, bnp);
  bn_final<<<1, 256, 0, stream>>>(bnp, g2, be2, ss, 64, 23104);
  bnrelu_im2col<<<(6400 * 9 * 16 + 255) / 256, 256, 0, stream>>>(C2, 128, 19, 19, ss, X3, 10, 10, 64, 6400);
  gemm_bt<2><<<50, 256, 0, stream>>>(X3, 576, Wc3, 576, C3, nullptr, 128, bc3, 18, 1);

  bn_partial<<<dim3(128, BN_S), 256, 0, stream>>>(C3, 128, 6400, bnp);
  bn_final<<<1, 256, 0, stream>>>(bnp, g3, be3, ss, 128, 6400);
  bnrelu_im2col<<<(1664 * 9 * 32 + 255) / 256, 256, 0, stream>>>(C3, 128, 10, 10, ss, X4, 5, 5, 128, 1664);
  gemm_bt<2><<<26, 256, 0, stream>>>(X4, 1152, Wc4, 1152, C4, nullptr, 256, bc4, 36, 2);

  bn_partial<<<dim3(256, BN_S), 256, 0, stream>>>(C4, 256, 1600, bnp);
  bn_final<<<1, 256, 0, stream>>>(bnp, g4, be4, ss, 256, 1600);
  obj_from_c4<<<(1664 * 256 + 255) / 256, 256, 0, stream>>>(C4, ss, obj);

  // ---- MLP packs ----
  pack_w1<<<2048, 256, 0, stream>>>(gw1, W1a, W1b);
  pack_wbig<<<16384, 256, 0, stream>>>(gw2, Wp2);
  pack_wbig<<<16384, 256, 0, stream>>>(gw3, Wp3);
  pack_wbig<<<16384, 256, 0, stream>>>(gw4, Wp4);
  pack_bias3<<<8, 256, 0, stream>>>(gb2, gb3, gb4, bp);
  q_build<<<512, 256, 0, stream>>>(qst, gw1, gb1, Q);

  // ---- layer-1 decomposition GEMMs (bf16 raw out) ----
  gemm_bt<3><<<13 * 16, 256, 0, stream>>>(obj, 256, W1a, 256, nullptr, Afu, 2048, nullptr, 8, 16);
  gemm_bt<3><<<13 * 16, 256, 0, stream>>>(obj, 256, W1b, 256, nullptr, Bfu, 2048, nullptr, 8, 16);

  // ---- chunked g-MLP with 8-phase 256^2 GEMM ----
  int NC = 64 / CHI;
  int mtiles = (int)(Mp / 256);
  for (int c = 0; c < NC; c++) {
    int c0 = c * CHI;
    int nrows = CHI * 625;
    h1_build<<<(unsigned)Mp, 256, 0, stream>>>(Afu, Bfu, Q, h0, c0, nrows);
    gemm256<32><<<mtiles * 8, 512, 0, stream>>>(h0, Wp2, h1b, bp);
    gemm256<32><<<mtiles * 8, 512, 0, stream>>>(h1b, Wp3, h0, bp + 2048);
    gemm256<32><<<mtiles * 8, 512, 0, stream>>>(h0, Wp4, h1b, bp + 4096);
    reduce_part<<<dim3(CHI, 5), 256, 0, stream>>>(h1b, rpart, CHI);
    reduce_fin<<<(CHI * 2048 + 255) / 256, 256, 0, stream>>>(rpart, xg, c0, CHI);
  }

  // ---- f MLP ----
  {
    int nthreads;
    nthreads = 64 * 1000 * 64;
    f_layer<<<(nthreads + 255) / 256, 256, 0, stream>>>(xg, 2048, 2000, fw1, fb1, xf1, 1024, 1000, 1.f / 625.f, 1);
    nthreads = 64 * 500 * 64;
    f_layer<<<(nthreads + 255) / 256, 256, 0, stream>>>(xf1, 1024, 1000, fw2, fb2, xf2, 512, 500, 1.f, 1);
    nthreads = 64 * 100 * 64;
    f_layer<<<(nthreads + 255) / 256, 256, 0, stream>>>(xf2, 512, 500, fw3, fb3, xf3, 128, 100, 1.f, 1);
    nthreads = 64 * 10 * 64;
    f_layer<<<(nthreads + 255) / 256, 256, 0, stream>>>(xf3, 128, 100, fw4, fb4, xf4, 16, 10, 1.f, 0);
  }
  lsm_kernel<<<1, 64, 0, stream>>>(xf4, out);
}

// Round 8
// 1642.906 us; speedup vs baseline: 1.0712x; 1.0236x over previous
//
#include <hip/hip_runtime.h>

typedef unsigned short u16;
typedef unsigned int u32;
typedef __attribute__((ext_vector_type(8))) short bf16x8;
typedef __attribute__((ext_vector_type(4))) float f32x4;

#define BN_EPS 1e-5f
#define BN_S 16

__device__ __forceinline__ float bf2f(u16 u) {
  union { unsigned u; float f; } x; x.u = ((unsigned)u) << 16; return x.f;
}
__device__ __forceinline__ u16 f2bf(float f) {
  union { float f; unsigned u; } x; x.f = f;
  unsigned r = x.u + 0x7FFFu + ((x.u >> 16) & 1u);
  return (u16)(r >> 16);
}

// ---------------- conv1: direct, NHWC output [64*38*38][32] fp32 ----------------
__global__ void conv1_nhwc(const float* __restrict__ img, const float* __restrict__ w,
                           const float* __restrict__ b, float* __restrict__ C1) {
  int idx = blockIdx.x * blockDim.x + threadIdx.x;
  if (idx >= 92416 * 32) return;
  int co = idx & 31; int row = idx >> 5;
  int wo = row % 38; int t = row / 38;
  int ho = t % 38; int n = t / 38;
  int hi0 = ho * 2 - 1, wi0 = wo * 2 - 1;
  float acc = b[co];
  const float* wp = w + co * 27;
#pragma unroll
  for (int ci = 0; ci < 3; ci++) {
    const float* ip = img + ((size_t)(n * 3 + ci) * 75) * 75;
    const float* wc = wp + ci * 9;
#pragma unroll
    for (int kh = 0; kh < 3; kh++) {
      int hi = hi0 + kh;
      if (hi < 0 || hi >= 75) continue;
#pragma unroll
      for (int kw = 0; kw < 3; kw++) {
        int wi = wi0 + kw;
        if (wi < 0 || wi >= 75) continue;
        acc += ip[hi * 75 + wi] * wc[kh * 3 + kw];
      }
    }
  }
  C1[idx] = acc;
}

// ---------------- BN column-stats (deterministic 2-stage) ----------------
__global__ void bn_partial(const float* __restrict__ C, int ldc, int M,
                           float* __restrict__ part) {
  int c = blockIdx.x; int s = blockIdx.y; int t = threadIdx.x;
  int rowsPer = (M + BN_S - 1) / BN_S;
  int r0 = s * rowsPer; int r1 = r0 + rowsPer; if (r1 > M) r1 = M;
  float s1 = 0.f, s2 = 0.f;
  for (int r = r0 + t; r < r1; r += 256) {
    float v = C[(size_t)r * ldc + c]; s1 += v; s2 += v * v;
  }
  __shared__ float l1[256], l2[256];
  l1[t] = s1; l2[t] = s2; __syncthreads();
  for (int off = 128; off > 0; off >>= 1) {
    if (t < off) { l1[t] += l1[t + off]; l2[t] += l2[t + off]; }
    __syncthreads();
  }
  if (t == 0) { part[s * 512 + c] = l1[0]; part[s * 512 + 256 + c] = l2[0]; }
}

__global__ void bn_final(const float* __restrict__ part, const float* __restrict__ gamma,
                         const float* __restrict__ beta, float* __restrict__ ss,
                         int C, int M) {
  int c = threadIdx.x;
  if (c >= C) { if (c < 256) { ss[c] = 0.f; ss[256 + c] = 0.f; } return; }
  float s1 = 0.f, s2 = 0.f;
#pragma unroll
  for (int s = 0; s < BN_S; s++) { s1 += part[s * 512 + c]; s2 += part[s * 512 + 256 + c]; }
  float mu = s1 / M;
  float var = s2 / M - mu * mu;
  float sc = gamma[c] * rsqrtf(var + BN_EPS);
  ss[c] = sc; ss[256 + c] = beta[c] - mu * sc;
}

// ---------------- fused BN+ReLU + im2col -> bf16 X[row][tap*Ci+ci] ----------------
__global__ void bnrelu_im2col(const float* __restrict__ Cprev, int ldprev, int Hp, int Wp,
                              const float* __restrict__ ss, u16* __restrict__ X,
                              int Ho, int Wo, int Ci, int Mp) {
  int civ4 = Ci >> 2;
  int idx = blockIdx.x * blockDim.x + threadIdx.x;
  int total = Mp * 9 * civ4;
  if (idx >= total) return;
  int cv = idx % civ4; int t2 = idx / civ4;
  int tap = t2 % 9; int row = t2 / 9;
  int K = 9 * Ci;
  u16* dst = X + (size_t)row * K + tap * Ci + cv * 4;
  int HW = Ho * Wo;
  int Mvalid = 64 * HW;
  ushort4 o4; o4.x = 0; o4.y = 0; o4.z = 0; o4.w = 0;
  if (row < Mvalid) {
    int wo = row % Wo; int t = row / Wo;
    int ho = t % Ho; int n = t / Ho;
    int kh = tap / 3, kw = tap % 3;
    int hi = ho * 2 - 1 + kh, wi = wo * 2 - 1 + kw;
    if (hi >= 0 && hi < Hp && wi >= 0 && wi < Wp) {
      const float* src = Cprev + ((size_t)((n * Hp + hi) * Wp + wi)) * ldprev + cv * 4;
      float4 v = *(const float4*)src;
      int c0 = cv * 4;
      float a;
      a = v.x * ss[c0 + 0] + ss[256 + c0 + 0]; o4.x = f2bf(a > 0.f ? a : 0.f);
      a = v.y * ss[c0 + 1] + ss[256 + c0 + 1]; o4.y = f2bf(a > 0.f ? a : 0.f);
      a = v.z * ss[c0 + 2] + ss[256 + c0 + 2]; o4.z = f2bf(a > 0.f ? a : 0.f);
      a = v.w * ss[c0 + 3] + ss[256 + c0 + 3]; o4.w = f2bf(a > 0.f ? a : 0.f);
    }
  }
  *(ushort4*)dst = o4;
}

// ---------------- conv weight pack ----------------
__global__ void pack_convw(const float* __restrict__ w, u16* __restrict__ Wp,
                           int Co, int Ci, int Cop) {
  int K = 9 * Ci;
  int idx = blockIdx.x * blockDim.x + threadIdx.x;
  if (idx >= Cop * K) return;
  int k = idx % K; int co = idx / K;
  int tap = k / Ci; int ci = k % Ci;
  float v = (co < Co) ? w[((size_t)co * Ci + ci) * 9 + tap] : 0.f;
  Wp[idx] = f2bf(v);
}

__global__ void pad_bias(const float* __restrict__ b, float* __restrict__ bc, int Co, int Cop) {
  int i = blockIdx.x * blockDim.x + threadIdx.x;
  if (i < Cop) bc[i] = (i < Co) ? b[i] : 0.f;
}

// ---------------- obj pack from C4 with BN+ReLU ----------------
__global__ void obj_from_c4(const float* __restrict__ C4, const float* __restrict__ ss,
                            u16* __restrict__ obj) {
  int idx = blockIdx.x * blockDim.x + threadIdx.x;
  if (idx >= 1664 * 256) return;
  int c = idx & 255; int row = idx >> 8;
  float v = 0.f;
  if (row < 1600) {
    float x = C4[(size_t)row * 256 + c];
    x = x * ss[c] + ss[256 + c];
    v = x > 0.f ? x : 0.f;
  }
  obj[idx] = f2bf(v);
}

// ---------------- MLP weight packs ----------------
__global__ void pack_w1(const float* __restrict__ gw1, u16* __restrict__ W1a, u16* __restrict__ W1b) {
  int idx = blockIdx.x * blockDim.x + threadIdx.x;
  if (idx >= 2048 * 256) return;
  int k = idx & 255, n = idx >> 8;
  float a = 0.f, b = 0.f;
  if (n < 2000) { a = gw1[(size_t)n * 523 + k]; b = gw1[(size_t)n * 523 + 256 + k]; }
  W1a[idx] = f2bf(a); W1b[idx] = f2bf(b);
}

__global__ void pack_wbig(const float* __restrict__ gw, u16* __restrict__ Wp) {
  int idx = blockIdx.x * blockDim.x + threadIdx.x;
  if (idx >= 2048 * 2048) return;
  int k = idx & 2047, n = idx >> 11;
  float v = (n < 2000 && k < 2000) ? gw[(size_t)n * 2000 + k] : 0.f;
  Wp[idx] = f2bf(v);
}

__global__ void pack_bias3(const float* __restrict__ b2, const float* __restrict__ b3,
                           const float* __restrict__ b4, float* __restrict__ bp) {
  int i = blockIdx.x * blockDim.x + threadIdx.x;
  if (i >= 2048) return;
  bp[i]        = (i < 2000) ? b2[i] : 0.f;
  bp[2048 + i] = (i < 2000) ? b3[i] : 0.f;
  bp[4096 + i] = (i < 2000) ? b4[i] : 0.f;
}

// ---------------- Q[b][o] = gb1[o] + qst[b] . gw1[o][512:523] ----------------
__global__ void q_build(const float* __restrict__ qst, const float* __restrict__ gw1,
                        const float* __restrict__ gb1, float* __restrict__ Q) {
  int idx = blockIdx.x * blockDim.x + threadIdx.x;
  if (idx >= 64 * 2048) return;
  int o = idx & 2047, b = idx >> 11;
  float v = 0.f;
  if (o < 2000) {
    v = gb1[o];
    const float* w = gw1 + (size_t)o * 523 + 512;
    const float* q = qst + b * 11;
#pragma unroll
    for (int k = 0; k < 11; k++) v += q[k] * w[k];
  }
  Q[idx] = v;
}

// ---------------- global->LDS async ----------------
typedef const __attribute__((address_space(1))) u32* gas1;
typedef __attribute__((address_space(3))) u32* las3;
__device__ __forceinline__ void gld16(const void* g, void* l) {
  __builtin_amdgcn_global_load_lds((gas1)g, (las3)l, 16, 0, 0);
}

// ---------------- 128^2 bf16 MFMA GEMM (small/medium shapes) ----------------
// EPI 0: fp32 raw; EPI 2: fp32 acc+bias; EPI 3: bf16 raw
template <int EPI>
__global__ __launch_bounds__(256) void gemm_bt(
    const u16* __restrict__ A, int lda,
    const u16* __restrict__ W, int ldb,
    float* __restrict__ Cf, u16* __restrict__ Cb, int ldc,
    const float* __restrict__ bias, int KT, int NTN) {
  __shared__ __align__(16) char lds[32768];
  int bid = blockIdx.x;
  int wg;
  if ((gridDim.x & 7) == 0) {
    int cpx = gridDim.x >> 3;
    wg = (bid & 7) * cpx + (bid >> 3);
  } else {
    wg = bid;
  }
  int mt = wg / NTN, nt = wg % NTN;
  int tid = threadIdx.x;
  int wave = tid >> 6, lane = tid & 63;
  int r = lane & 15, g = lane >> 4;
  int wr = wave >> 1, wc = wave & 1;

  const u16* Asrc = A + (size_t)(mt * 128 + wave * 32 + r) * lda + g * 8;
  const u16* Wsrc = W + (size_t)(nt * 128 + wave * 32 + r) * ldb + g * 8;

  f32x4 acc[4][4];
#pragma unroll
  for (int i = 0; i < 4; i++)
#pragma unroll
    for (int j = 0; j < 4; j++) acc[i][j] = (f32x4){0.f, 0.f, 0.f, 0.f};

  {
    char* Al = lds; char* Wl = lds + 8192;
    gld16(Asrc, Al + wave * 2048);
    gld16(Asrc + (size_t)16 * lda, Al + wave * 2048 + 1024);
    gld16(Wsrc, Wl + wave * 2048);
    gld16(Wsrc + (size_t)16 * ldb, Wl + wave * 2048 + 1024);
  }
  __syncthreads();

  int buf = 0;
  for (int kt = 0; kt < KT; kt++) {
    if (kt + 1 < KT) {
      int k0 = (kt + 1) * 32;
      char* Al = lds + (buf ^ 1) * 16384; char* Wl = Al + 8192;
      gld16(Asrc + k0, Al + wave * 2048);
      gld16(Asrc + k0 + (size_t)16 * lda, Al + wave * 2048 + 1024);
      gld16(Wsrc + k0, Wl + wave * 2048);
      gld16(Wsrc + k0 + (size_t)16 * ldb, Wl + wave * 2048 + 1024);
    }
    char* Al = lds + buf * 16384; char* Wl = Al + 8192;
    bf16x8 a[4], w[4];
#pragma unroll
    for (int i = 0; i < 4; i++) a[i] = *(const bf16x8*)(Al + (wr * 4 + i) * 1024 + lane * 16);
#pragma unroll
    for (int j = 0; j < 4; j++) w[j] = *(const bf16x8*)(Wl + (wc * 4 + j) * 1024 + lane * 16);
#pragma unroll
    for (int i = 0; i < 4; i++)
#pragma unroll
      for (int j = 0; j < 4; j++)
        acc[i][j] = __builtin_amdgcn_mfma_f32_16x16x32_bf16(a[i], w[j], acc[i][j], 0, 0, 0);
    __syncthreads();
    buf ^= 1;
  }

  int rowb = mt * 128 + wr * 64 + (lane >> 4) * 4;
  int colb = nt * 128 + wc * 64 + (lane & 15);
#pragma unroll
  for (int i = 0; i < 4; i++) {
#pragma unroll
    for (int j = 0; j < 4; j++) {
      int col = colb + j * 16;
      float bv = (EPI == 2) ? bias[col] : 0.f;
#pragma unroll
      for (int q = 0; q < 4; q++) {
        int row = rowb + i * 16 + q;
        float v = acc[i][j][q];
        if (EPI == 2) {
          Cf[(size_t)row * ldc + col] = v + bv;
        } else if (EPI == 3) {
          Cb[(size_t)row * ldc + col] = f2bf(v);
        } else {
          Cf[(size_t)row * ldc + col] = v;
        }
      }
    }
  }
}

// ---------------- 256^2 bf16 GEMM — 8-phase schedule, unroll-2 K-loop ----------------
// C = relu(A@W^T + bias) -> bf16. lda=ldb=ldc=2048. BK=64, 2-deep dbuf (2x64KB).
// Grid is ALWAYS mtiles*8 = multiple of 256 (exact CU rounds, no tail).
#define MF16(d, av, bv) d = __builtin_amdgcn_mfma_f32_16x16x32_bf16(av, bv, d, 0, 0, 0)

template <int NT>
__global__ __launch_bounds__(512, 2) void gemm256(
    const u16* __restrict__ A, const u16* __restrict__ W,
    u16* __restrict__ Cb, const float* __restrict__ bias) {
  __shared__ __align__(16) char lds[131072];
  int bid = blockIdx.x;
  int cpx = gridDim.x >> 3;
  int wg = (bid & 7) * cpx + (bid >> 3);
  int mt = wg >> 3, nt = wg & 7;
  int tid = threadIdx.x;
  int wave = tid >> 6, lane = tid & 63;
  int lane16 = lane * 16;
  int wr = wave >> 2, wc = wave & 3;
  int wcl = wc & 1, wch = wc >> 1;

  // stage one A/B half-tile (128 rows x 64 k) of tile tt into LDS slot, half h.
  auto stageA = [&](int tt, int slot, int h) {
#pragma unroll
    for (int j = 0; j < 2; j++) {
      int u = wave * 2 + j;
      const u16* src = A + (size_t)(mt * 256 + h * 128 + (u >> 1) * 16 + (lane & 15)) * 2048
                         + tt * 64 + (u & 1) * 32 + (lane >> 4) * 8;
      gld16(src, lds + slot * 65536 + h * 16384 + u * 1024);
    }
  };
  auto stageB = [&](int tt, int slot, int h) {
#pragma unroll
    for (int j = 0; j < 2; j++) {
      int u = wave * 2 + j;
      const u16* src = W + (size_t)(nt * 256 + h * 128 + (u >> 1) * 16 + (lane & 15)) * 2048
                         + tt * 64 + (u & 1) * 32 + (lane >> 4) * 8;
      gld16(src, lds + slot * 65536 + 32768 + h * 16384 + u * 1024);
    }
  };

  f32x4 acc[8][4];
#pragma unroll
  for (int i = 0; i < 8; i++)
#pragma unroll
    for (int j = 0; j < 4; j++) acc[i][j] = (f32x4){0.f, 0.f, 0.f, 0.f};

  // prologue: tile 0 fully + tile 1 B-halves
  stageA(0, 0, 0); stageA(0, 0, 1); stageB(0, 0, 0); stageB(0, 0, 1);
  stageB(1, 1, 0); stageB(1, 1, 1);
  asm volatile("s_waitcnt vmcnt(4)" ::: "memory");   // tile 0 landed; t1 B in flight
  __builtin_amdgcn_s_barrier();

  bf16x8 b00, b01, b10, b11, b20, b21, b30, b31;

#define PHASE(Q, T, BUF)                                                         \
  {                                                                              \
    const char* Ab = lds + (BUF) * 65536 + wr * 16384;                           \
    const char* Bb = lds + (BUF) * 65536 + 32768 + wch * 16384;                  \
    if (Q == 0) {                                                                \
      b00 = *(const bf16x8*)(Bb + ((wcl * 4 + 0) * 2 + 0) * 1024 + lane16);      \
      b01 = *(const bf16x8*)(Bb + ((wcl * 4 + 0) * 2 + 1) * 1024 + lane16);      \
      b10 = *(const bf16x8*)(Bb + ((wcl * 4 + 1) * 2 + 0) * 1024 + lane16);      \
      b11 = *(const bf16x8*)(Bb + ((wcl * 4 + 1) * 2 + 1) * 1024 + lane16);      \
      b20 = *(const bf16x8*)(Bb + ((wcl * 4 + 2) * 2 + 0) * 1024 + lane16);      \
      b21 = *(const bf16x8*)(Bb + ((wcl * 4 + 2) * 2 + 1) * 1024 + lane16);      \
      b30 = *(const bf16x8*)(Bb + ((wcl * 4 + 3) * 2 + 0) * 1024 + lane16);      \
      b31 = *(const bf16x8*)(Bb + ((wcl * 4 + 3) * 2 + 1) * 1024 + lane16);      \
    }                                                                            \
    bf16x8 a00 = *(const bf16x8*)(Ab + ((2 * Q + 0) * 2 + 0) * 1024 + lane16);   \
    bf16x8 a01 = *(const bf16x8*)(Ab + ((2 * Q + 0) * 2 + 1) * 1024 + lane16);   \
    bf16x8 a10 = *(const bf16x8*)(Ab + ((2 * Q + 1) * 2 + 0) * 1024 + lane16);   \
    bf16x8 a11 = *(const bf16x8*)(Ab + ((2 * Q + 1) * 2 + 1) * 1024 + lane16);   \
    if (Q == 0) { if ((T) + 1 < NT) stageA((T) + 1, (BUF) ^ 1, 0); }             \
    if (Q == 1) { if ((T) + 1 < NT) stageA((T) + 1, (BUF) ^ 1, 1);               \
                  if ((T) + 2 < NT) stageB((T) + 2, (BUF), 0); }                 \
    if (Q == 2) { if ((T) + 2 < NT) stageB((T) + 2, (BUF), 1); }                 \
    __builtin_amdgcn_s_barrier();                                                \
    __builtin_amdgcn_s_setprio(1);                                               \
    MF16(acc[2 * Q + 0][0], a00, b00); MF16(acc[2 * Q + 0][0], a01, b01);        \
    MF16(acc[2 * Q + 0][1], a00, b10); MF16(acc[2 * Q + 0][1], a01, b11);        \
    MF16(acc[2 * Q + 0][2], a00, b20); MF16(acc[2 * Q + 0][2], a01, b21);        \
    MF16(acc[2 * Q + 0][3], a00, b30); MF16(acc[2 * Q + 0][3], a01, b31);        \
    MF16(acc[2 * Q + 1][0], a10, b00); MF16(acc[2 * Q + 1][0], a11, b01);        \
    MF16(acc[2 * Q + 1][1], a10, b10); MF16(acc[2 * Q + 1][1], a11, b11);        \
    MF16(acc[2 * Q + 1][2], a10, b20); MF16(acc[2 * Q + 1][2], a11, b21);        \
    MF16(acc[2 * Q + 1][3], a10, b30); MF16(acc[2 * Q + 1][3], a11, b31);        \
    __builtin_amdgcn_s_setprio(0);                                               \
    if (Q == 3) { asm volatile("s_waitcnt vmcnt(4)" ::: "memory"); }             \
    __builtin_amdgcn_s_barrier();                                                \
  }

#pragma unroll 1
  for (int t2 = 0; t2 < NT; t2 += 2) {
    PHASE(0, t2, 0) PHASE(1, t2, 0) PHASE(2, t2, 0) PHASE(3, t2, 0)
    PHASE(0, t2 + 1, 1) PHASE(1, t2 + 1, 1) PHASE(2, t2 + 1, 1) PHASE(3, t2 + 1, 1)
  }
#undef PHASE

  // epilogue: frag D layout col=lane&15, row=(lane>>4)*4+q
  int rowb = mt * 256 + wr * 128 + (lane >> 4) * 4;
  int colb = nt * 256 + wc * 64 + (lane & 15);
#pragma unroll
  for (int i = 0; i < 8; i++) {
#pragma unroll
    for (int j = 0; j < 4; j++) {
      int col = colb + j * 16;
      float bv = bias[col];
#pragma unroll
      for (int q = 0; q < 4; q++) {
        int row = rowb + i * 16 + q;
        float v = acc[i][j][q] + bv;
        v = v > 0.f ? v : 0.f;
        Cb[(size_t)row * 2048 + col] = f2bf(v);
      }
    }
  }
}

// ---------------- h1 = relu(A_i + B_j + Q_b), rows = global pair index ----------------
__global__ void h1_build(const u16* __restrict__ Af, const u16* __restrict__ Bf,
                         const float* __restrict__ Q, u16* __restrict__ h1,
                         int r0, int nvalid) {
  int lrow = blockIdx.x;
  int t = threadIdx.x;
  u16* dst = h1 + (size_t)lrow * 2048;
  if (lrow >= nvalid) {
#pragma unroll
    for (int it = 0; it < 2; it++) {
      int o = it * 1024 + t * 4;
      ushort4 z; z.x = 0; z.y = 0; z.z = 0; z.w = 0;
      *(ushort4*)(dst + o) = z;
    }
    return;
  }
  int grow = r0 + lrow;
  int b = grow / 625; int rem = grow % 625;
  int i = rem / 25, j = rem % 25;
  const u16* Ap = Af + (size_t)(b * 25 + i) * 2048;
  const u16* Bp = Bf + (size_t)(b * 25 + j) * 2048;
  const float* Qp = Q + (size_t)b * 2048;
#pragma unroll
  for (int it = 0; it < 2; it++) {
    int o = it * 1024 + t * 4;
    ushort4 a4 = *(const ushort4*)(Ap + o);
    ushort4 b4 = *(const ushort4*)(Bp + o);
    float4 qv = *(const float4*)(Qp + o);
    ushort4 outv;
    float v;
    v = bf2f(a4.x) + bf2f(b4.x) + qv.x; outv.x = f2bf(v > 0.f ? v : 0.f);
    v = bf2f(a4.y) + bf2f(b4.y) + qv.y; outv.y = f2bf(v > 0.f ? v : 0.f);
    v = bf2f(a4.z) + bf2f(b4.z) + qv.z; outv.z = f2bf(v > 0.f ? v : 0.f);
    v = bf2f(a4.w) + bf2f(b4.w) + qv.w; outv.w = f2bf(v > 0.f ? v : 0.f);
    *(ushort4*)(dst + o) = outv;
  }
}

// ---------------- pair-sum reduce across chunk-straddling images ----------------
__global__ void zero_xg(float* __restrict__ xg) {
  int i = blockIdx.x * blockDim.x + threadIdx.x;
  if (i < 64 * 2048) xg[i] = 0.f;
}

// grid (nseg, 5): segment = one image's rows within this chunk; 5 stripes.
__global__ void reduce_part2(const u16* __restrict__ h4, float* __restrict__ part,
                             int r0, int nvalid, int bfirst) {
  int seg = blockIdx.x; int s = blockIdx.y; int t = threadIdx.x;
  int b = bfirst + seg;
  int lo = b * 625 - r0; if (lo < 0) lo = 0;
  int hi = (b + 1) * 625 - r0; if (hi > nvalid) hi = nvalid;
  int len = hi - lo;
  int k0 = lo + (len * s) / 5;
  int k1 = lo + (len * (s + 1)) / 5;
  const u16* base = h4 + t * 8;
  float a0 = 0.f, a1 = 0.f, a2 = 0.f, a3 = 0.f, a4 = 0.f, a5 = 0.f, a6 = 0.f, a7 = 0.f;
  for (int k = k0; k < k1; k++) {
    uint4 u = *(const uint4*)(base + (size_t)k * 2048);
    a0 += bf2f((u16)(u.x & 0xffff)); a1 += bf2f((u16)(u.x >> 16));
    a2 += bf2f((u16)(u.y & 0xffff)); a3 += bf2f((u16)(u.y >> 16));
    a4 += bf2f((u16)(u.z & 0xffff)); a5 += bf2f((u16)(u.z >> 16));
    a6 += bf2f((u16)(u.w & 0xffff)); a7 += bf2f((u16)(u.w >> 16));
  }
  float* dst = part + ((size_t)(seg * 5 + s) * 2048) + t * 8;
  dst[0] = a0; dst[1] = a1; dst[2] = a2; dst[3] = a3;
  dst[4] = a4; dst[5] = a5; dst[6] = a6; dst[7] = a7;
}

__global__ void reduce_fin2(const float* __restrict__ part, float* __restrict__ xg,
                            int bfirst, int nseg) {
  int idx = blockIdx.x * blockDim.x + threadIdx.x;
  if (idx >= nseg * 2048) return;
  int seg = idx >> 11; int o = idx & 2047;
  float sv = 0.f;
#pragma unroll
  for (int s = 0; s < 5; s++) sv += part[(size_t)(seg * 5 + s) * 2048 + o];
  xg[(size_t)(bfirst + seg) * 2048 + o] += sv;
}

// ---------------- f MLP: warp per output, fp32 ----------------
__global__ void f_layer(const float* __restrict__ x, int ldx, int Kin,
                        const float* __restrict__ Wf, const float* __restrict__ bf_,
                        float* __restrict__ y, int ldy, int Nout, float scale, int relu) {
  int gwid = (blockIdx.x * blockDim.x + threadIdx.x) >> 6;
  int lane = threadIdx.x & 63;
  if (gwid >= 64 * Nout) return;
  int b = gwid / Nout, o = gwid % Nout;
  const float* xp = x + (size_t)b * ldx;
  const float* wp = Wf + (size_t)o * Kin;
  float s = 0.f;
  for (int k = lane; k < Kin; k += 64) s += xp[k] * wp[k];
  for (int off = 32; off > 0; off >>= 1) s += __shfl_down(s, off);
  if (lane == 0) {
    float v = s * scale + bf_[o];
    if (relu) v = v > 0.f ? v : 0.f;
    y[(size_t)b * ldy + o] = v;
  }
}

__global__ void lsm_kernel(const float* __restrict__ xf4, float* __restrict__ out) {
  int b = blockIdx.x * blockDim.x + threadIdx.x;
  if (b >= 64) return;
  const float* x = xf4 + b * 16;
  float m = x[0];
  for (int i = 1; i < 10; i++) m = fmaxf(m, x[i]);
  float s = 0.f;
  for (int i = 0; i < 10; i++) s += expf(x[i] - m);
  float ls = logf(s);
  for (int i = 0; i < 10; i++) out[b * 10 + i] = x[i] - m - ls;
}

// ---------------- host ----------------
extern "C" void kernel_launch(void* const* d_in, const int* in_sizes, int n_in,
                              void* d_out, int out_size, void* d_ws, size_t ws_size,
                              hipStream_t stream) {
  const float* img = (const float*)d_in[0];
  const float* qst = (const float*)d_in[1];
  const float* w1 = (const float*)d_in[2];  const float* b1 = (const float*)d_in[3];
  const float* w2 = (const float*)d_in[4];  const float* b2 = (const float*)d_in[5];
  const float* w3 = (const float*)d_in[6];  const float* b3 = (const float*)d_in[7];
  const float* w4 = (const float*)d_in[8];  const float* b4 = (const float*)d_in[9];
  const float* g1 = (const float*)d_in[10]; const float* be1 = (const float*)d_in[11];
  const float* g2 = (const float*)d_in[12]; const float* be2 = (const float*)d_in[13];
  const float* g3 = (const float*)d_in[14]; const float* be3 = (const float*)d_in[15];
  const float* g4 = (const float*)d_in[16]; const float* be4 = (const float*)d_in[17];
  const float* gw1 = (const float*)d_in[18]; const float* gb1 = (const float*)d_in[19];
  const float* gw2 = (const float*)d_in[20]; const float* gb2 = (const float*)d_in[21];
  const float* gw3 = (const float*)d_in[22]; const float* gb3 = (const float*)d_in[23];
  const float* gw4 = (const float*)d_in[24]; const float* gb4 = (const float*)d_in[25];
  const float* fw1 = (const float*)d_in[26]; const float* fb1 = (const float*)d_in[27];
  const float* fw2 = (const float*)d_in[28]; const float* fb2 = (const float*)d_in[29];
  const float* fw3 = (const float*)d_in[30]; const float* fb3 = (const float*)d_in[31];
  const float* fw4 = (const float*)d_in[32]; const float* fb4 = (const float*)d_in[33];
  float* out = (float*)d_out;

  char* P = (char*)d_ws;
  auto alloc = [&](size_t bytes) -> char* {
    char* r = P; P += (bytes + 255) & ~(size_t)255; return r;
  };
  // persistent
  u16* Wp2 = (u16*)alloc(2048ull * 2048 * 2);
  u16* Wp3 = (u16*)alloc(2048ull * 2048 * 2);
  u16* Wp4 = (u16*)alloc(2048ull * 2048 * 2);
  u16* Afu = (u16*)alloc(1664ull * 2048 * 2);
  u16* Bfu = (u16*)alloc(1664ull * 2048 * 2);
  float* Q = (float*)alloc(64ull * 2048 * 4);
  float* bp = (float*)alloc(3ull * 2048 * 4);
  float* xg = (float*)alloc(64ull * 2048 * 4);
  float* xf1 = (float*)alloc(64ull * 1024 * 4);
  float* xf2 = (float*)alloc(64ull * 512 * 4);
  float* xf3 = (float*)alloc(64ull * 128 * 4);
  float* xf4 = (float*)alloc(64ull * 16 * 4);
  u16* obj = (u16*)alloc(1664ull * 256 * 2);
  u16* W1a = (u16*)alloc(2048ull * 256 * 2);
  u16* W1b = (u16*)alloc(2048ull * 256 * 2);
  // h-phase (8192-row chunks)
  u16* h0  = (u16*)alloc(8192ull * 2048 * 2);
  u16* h1b = (u16*)alloc(8192ull * 2048 * 2);
  float* rpart = (float*)alloc(14ull * 5 * 2048 * 4);
  // conv-phase (dead after obj; kept separate — fits comfortably)
  float* C1 = (float*)alloc(92416ull * 32 * 4);
  u16*   X2 = (u16*)alloc(23168ull * 288 * 2);
  float* C2 = (float*)alloc(23168ull * 128 * 4);
  u16*   X3 = (u16*)alloc(6400ull * 576 * 2);
  float* C3 = (float*)alloc(6400ull * 128 * 4);
  u16*   X4 = (u16*)alloc(1664ull * 1152 * 2);
  float* C4 = (float*)alloc(1664ull * 256 * 4);
  u16*  Wc2 = (u16*)alloc(128ull * 288 * 2);
  u16*  Wc3 = (u16*)alloc(128ull * 576 * 2);
  u16*  Wc4 = (u16*)alloc(256ull * 1152 * 2);
  float* bc2 = (float*)alloc(128 * 4);
  float* bc3 = (float*)alloc(128 * 4);
  float* bc4 = (float*)alloc(256 * 4);
  float* bnp = (float*)alloc(BN_S * 512 * 4);
  float* ss  = (float*)alloc(512 * 4);

  // ---- conv weight/bias packs ----
  pack_convw<<<(128 * 288 + 255) / 256, 256, 0, stream>>>(w2, Wc2, 64, 32, 128);
  pack_convw<<<(128 * 576 + 255) / 256, 256, 0, stream>>>(w3, Wc3, 128, 64, 128);
  pack_convw<<<(256 * 1152 + 255) / 256, 256, 0, stream>>>(w4, Wc4, 256, 128, 256);
  pad_bias<<<1, 256, 0, stream>>>(b2, bc2, 64, 128);
  pad_bias<<<1, 256, 0, stream>>>(b3, bc3, 128, 128);
  pad_bias<<<1, 256, 0, stream>>>(b4, bc4, 256, 256);

  // ---- conv stack ----
  conv1_nhwc<<<(92416 * 32 + 255) / 256, 256, 0, stream>>>(img, w1, b1, C1);
  bn_partial<<<dim3(32, BN_S), 256, 0, stream>>>(C1, 32, 92416, bnp);
  bn_final<<<1, 256, 0, stream>>>(bnp, g1, be1, ss, 32, 92416);
  bnrelu_im2col<<<(23168 * 9 * 8 + 255) / 256, 256, 0, stream>>>(C1, 32, 38, 38, ss, X2, 19, 19, 32, 23168);
  gemm_bt<2><<<181, 256, 0, stream>>>(X2, 288, Wc2, 288, C2, nullptr, 128, bc2, 9, 1);

  bn_partial<<<dim3(64, BN_S), 256, 0, stream>>>(C2, 128, 23104, bnp);
  bn_final<<<1, 256, 0, stream>>>(bnp, g2, be2, ss, 64, 23104);
  bnrelu_im2col<<<(6400 * 9 * 16 + 255) / 256, 256, 0, stream>>>(C2, 128, 19, 19, ss, X3, 10, 10, 64, 6400);
  gemm_bt<2><<<50, 256, 0, stream>>>(X3, 576, Wc3, 576, C3, nullptr, 128, bc3, 18, 1);

  bn_partial<<<dim3(128, BN_S), 256, 0, stream>>>(C3, 128, 6400, bnp);
  bn_final<<<1, 256, 0, stream>>>(bnp, g3, be3, ss, 128, 6400);
  bnrelu_im2col<<<(1664 * 9 * 32 + 255) / 256, 256, 0, stream>>>(C3, 128, 10, 10, ss, X4, 5, 5, 128, 1664);
  gemm_bt<2><<<26, 256, 0, stream>>>(X4, 1152, Wc4, 1152, C4, nullptr, 256, bc4, 36, 2);

  bn_partial<<<dim3(256, BN_S), 256, 0, stream>>>(C4, 256, 1600, bnp);
  bn_final<<<1, 256, 0, stream>>>(bnp, g4, be4, ss, 256, 1600);
  obj_from_c4<<<(1664 * 256 + 255) / 256, 256, 0, stream>>>(C4, ss, obj);

  // ---- MLP packs ----
  pack_w1<<<2048, 256, 0, stream>>>(gw1, W1a, W1b);
  pack_wbig<<<16384, 256, 0, stream>>>(gw2, Wp2);
  pack_wbig<<<16384, 256, 0, stream>>>(gw3, Wp3);
  pack_wbig<<<16384, 256, 0, stream>>>(gw4, Wp4);
  pack_bias3<<<8, 256, 0, stream>>>(gb2, gb3, gb4, bp);
  q_build<<<512, 256, 0, stream>>>(qst, gw1, gb1, Q);

  // ---- layer-1 decomposition GEMMs (bf16 raw out) ----
  gemm_bt<3><<<13 * 16, 256, 0, stream>>>(obj, 256, W1a, 256, nullptr, Afu, 2048, nullptr, 8, 16);
  gemm_bt<3><<<13 * 16, 256, 0, stream>>>(obj, 256, W1b, 256, nullptr, Bfu, 2048, nullptr, 8, 16);

  // ---- g-MLP in 8192-row chunks (grid exactly 256 blocks per GEMM) ----
  zero_xg<<<512, 256, 0, stream>>>(xg);
  const int TOTROWS = 64 * 625;  // 40000
  for (int c = 0; c < 5; c++) {
    int r0 = c * 8192;
    int nvalid = TOTROWS - r0; if (nvalid > 8192) nvalid = 8192;
    h1_build<<<8192, 256, 0, stream>>>(Afu, Bfu, Q, h0, r0, nvalid);
    gemm256<32><<<256, 512, 0, stream>>>(h0, Wp2, h1b, bp);
    gemm256<32><<<256, 512, 0, stream>>>(h1b, Wp3, h0, bp + 2048);
    gemm256<32><<<256, 512, 0, stream>>>(h0, Wp4, h1b, bp + 4096);
    int bfirst = r0 / 625;
    int blast = (r0 + nvalid - 1) / 625;
    int nseg = blast - bfirst + 1;
    reduce_part2<<<dim3(nseg, 5), 256, 0, stream>>>(h1b, rpart, r0, nvalid, bfirst);
    reduce_fin2<<<(nseg * 2048 + 255) / 256, 256, 0, stream>>>(rpart, xg, bfirst, nseg);
  }

  // ---- f MLP ----
  {
    int nthreads;
    nthreads = 64 * 1000 * 64;
    f_layer<<<(nthreads + 255) / 256, 256, 0, stream>>>(xg, 2048, 2000, fw1, fb1, xf1, 1024, 1000, 1.f / 625.f, 1);
    nthreads = 64 * 500 * 64;
    f_layer<<<(nthreads + 255) / 256, 256, 0, stream>>>(xf1, 1024, 1000, fw2, fb2, xf2, 512, 500, 1.f, 1);
    nthreads = 64 * 100 * 64;
    f_layer<<<(nthreads + 255) / 256, 256, 0, stream>>>(xf2, 512, 500, fw3, fb3, xf3, 128, 100, 1.f, 1);
    nthreads = 64 * 10 * 64;
    f_layer<<<(nthreads + 255) / 256, 256, 0, stream>>>(xf3, 128, 100, fw4, fb4, xf4, 16, 10, 1.f, 0);
  }
  lsm_kernel<<<1, 64, 0, stream>>>(xf4, out);
}

// Round 9
// 1573.912 us; speedup vs baseline: 1.1181x; 1.0438x over previous
//
#include <hip/hip_runtime.h>

typedef unsigned short u16;
typedef unsigned int u32;
typedef __attribute__((ext_vector_type(8))) short bf16x8;
typedef __attribute__((ext_vector_type(4))) float f32x4;

#define BN_EPS 1e-5f
#define BN_S 16

__device__ __forceinline__ float bf2f(u16 u) {
  union { unsigned u; float f; } x; x.u = ((unsigned)u) << 16; return x.f;
}
__device__ __forceinline__ u16 f2bf(float f) {
  union { float f; unsigned u; } x; x.f = f;
  unsigned r = x.u + 0x7FFFu + ((x.u >> 16) & 1u);
  return (u16)(r >> 16);
}

// ---------------- conv1: LDS-staged, one block per (n, ho) ----------------
// out NHWC [64*38*38][32] fp32. Input rows + weights staged in LDS, zero borders,
// branch-free MAC loop. lane=co -> input reads broadcast, weight reads stride-27
// (odd -> conflict-free), stores fully coalesced.
__global__ __launch_bounds__(256) void conv1_lds(const float* __restrict__ img,
                                                 const float* __restrict__ w,
                                                 const float* __restrict__ b,
                                                 float* __restrict__ C1) {
  int blk = blockIdx.x;             // n*38 + ho
  int n = blk / 38, ho = blk % 38;
  __shared__ float in_s[9 * 80];    // [ci*3+kh][wi+1 (0..76)], borders zero
  __shared__ float w_s[32 * 27];
  __shared__ float b_s[32];
  int t = threadIdx.x;
  for (int i = t; i < 720; i += 256) in_s[i] = 0.f;
  __syncthreads();
  for (int i = t; i < 675; i += 256) {
    int wi = i % 75; int q = i / 75; int kh = q % 3; int ci = q / 3;
    int hi = ho * 2 - 1 + kh;
    if (hi >= 0 && hi < 75)
      in_s[(ci * 3 + kh) * 80 + wi + 1] = img[((size_t)(n * 3 + ci) * 75 + hi) * 75 + wi];
  }
  for (int i = t; i < 864; i += 256) w_s[i] = w[i];
  if (t < 32) b_s[t] = b[t];
  __syncthreads();
  for (int idx = t; idx < 1216; idx += 256) {
    int wo = idx >> 5, co = idx & 31;
    float acc = b_s[co];
    const float* wp = w_s + co * 27;
#pragma unroll
    for (int ci = 0; ci < 3; ci++) {
#pragma unroll
      for (int kh = 0; kh < 3; kh++) {
        const float* ip = in_s + (ci * 3 + kh) * 80 + 2 * wo;
        const float* wq = wp + ci * 9 + kh * 3;
        acc += ip[0] * wq[0] + ip[1] * wq[1] + ip[2] * wq[2];
      }
    }
    C1[((size_t)blk * 38 + wo) * 32 + co] = acc;
  }
}

// ---------------- BN column-stats (deterministic 2-stage) ----------------
__global__ void bn_partial(const float* __restrict__ C, int ldc, int M,
                           float* __restrict__ part) {
  int c = blockIdx.x; int s = blockIdx.y; int t = threadIdx.x;
  int rowsPer = (M + BN_S - 1) / BN_S;
  int r0 = s * rowsPer; int r1 = r0 + rowsPer; if (r1 > M) r1 = M;
  float s1 = 0.f, s2 = 0.f;
  for (int r = r0 + t; r < r1; r += 256) {
    float v = C[(size_t)r * ldc + c]; s1 += v; s2 += v * v;
  }
  __shared__ float l1[256], l2[256];
  l1[t] = s1; l2[t] = s2; __syncthreads();
  for (int off = 128; off > 0; off >>= 1) {
    if (t < off) { l1[t] += l1[t + off]; l2[t] += l2[t + off]; }
    __syncthreads();
  }
  if (t == 0) { part[s * 512 + c] = l1[0]; part[s * 512 + 256 + c] = l2[0]; }
}

__global__ void bn_final(const float* __restrict__ part, const float* __restrict__ gamma,
                         const float* __restrict__ beta, float* __restrict__ ss,
                         int C, int M) {
  int c = threadIdx.x;
  if (c >= C) { if (c < 256) { ss[c] = 0.f; ss[256 + c] = 0.f; } return; }
  float s1 = 0.f, s2 = 0.f;
#pragma unroll
  for (int s = 0; s < BN_S; s++) { s1 += part[s * 512 + c]; s2 += part[s * 512 + 256 + c]; }
  float mu = s1 / M;
  float var = s2 / M - mu * mu;
  float sc = gamma[c] * rsqrtf(var + BN_EPS);
  ss[c] = sc; ss[256 + c] = beta[c] - mu * sc;
}

// ---------------- fused BN+ReLU + im2col -> bf16 X[row][tap*Ci+ci] ----------------
__global__ void bnrelu_im2col(const float* __restrict__ Cprev, int ldprev, int Hp, int Wp,
                              const float* __restrict__ ss, u16* __restrict__ X,
                              int Ho, int Wo, int Ci, int Mp) {
  int civ4 = Ci >> 2;
  int idx = blockIdx.x * blockDim.x + threadIdx.x;
  int total = Mp * 9 * civ4;
  if (idx >= total) return;
  int cv = idx % civ4; int t2 = idx / civ4;
  int tap = t2 % 9; int row = t2 / 9;
  int K = 9 * Ci;
  u16* dst = X + (size_t)row * K + tap * Ci + cv * 4;
  int HW = Ho * Wo;
  int Mvalid = 64 * HW;
  ushort4 o4; o4.x = 0; o4.y = 0; o4.z = 0; o4.w = 0;
  if (row < Mvalid) {
    int wo = row % Wo; int t = row / Wo;
    int ho = t % Ho; int n = t / Ho;
    int kh = tap / 3, kw = tap % 3;
    int hi = ho * 2 - 1 + kh, wi = wo * 2 - 1 + kw;
    if (hi >= 0 && hi < Hp && wi >= 0 && wi < Wp) {
      const float* src = Cprev + ((size_t)((n * Hp + hi) * Wp + wi)) * ldprev + cv * 4;
      float4 v = *(const float4*)src;
      int c0 = cv * 4;
      float a;
      a = v.x * ss[c0 + 0] + ss[256 + c0 + 0]; o4.x = f2bf(a > 0.f ? a : 0.f);
      a = v.y * ss[c0 + 1] + ss[256 + c0 + 1]; o4.y = f2bf(a > 0.f ? a : 0.f);
      a = v.z * ss[c0 + 2] + ss[256 + c0 + 2]; o4.z = f2bf(a > 0.f ? a : 0.f);
      a = v.w * ss[c0 + 3] + ss[256 + c0 + 3]; o4.w = f2bf(a > 0.f ? a : 0.f);
    }
  }
  *(ushort4*)dst = o4;
}

// ---------------- conv weight pack ----------------
__global__ void pack_convw(const float* __restrict__ w, u16* __restrict__ Wp,
                           int Co, int Ci, int Cop) {
  int K = 9 * Ci;
  int idx = blockIdx.x * blockDim.x + threadIdx.x;
  if (idx >= Cop * K) return;
  int k = idx % K; int co = idx / K;
  int tap = k / Ci; int ci = k % Ci;
  float v = (co < Co) ? w[((size_t)co * Ci + ci) * 9 + tap] : 0.f;
  Wp[idx] = f2bf(v);
}

__global__ void pad_bias(const float* __restrict__ b, float* __restrict__ bc, int Co, int Cop) {
  int i = blockIdx.x * blockDim.x + threadIdx.x;
  if (i < Cop) bc[i] = (i < Co) ? b[i] : 0.f;
}

// ---------------- obj pack from C4 with BN+ReLU ----------------
__global__ void obj_from_c4(const float* __restrict__ C4, const float* __restrict__ ss,
                            u16* __restrict__ obj) {
  int idx = blockIdx.x * blockDim.x + threadIdx.x;
  if (idx >= 1664 * 256) return;
  int c = idx & 255; int row = idx >> 8;
  float v = 0.f;
  if (row < 1600) {
    float x = C4[(size_t)row * 256 + c];
    x = x * ss[c] + ss[256 + c];
    v = x > 0.f ? x : 0.f;
  }
  obj[idx] = f2bf(v);
}

// ---------------- MLP weight packs ----------------
__global__ void pack_w1(const float* __restrict__ gw1, u16* __restrict__ W1a, u16* __restrict__ W1b) {
  int idx = blockIdx.x * blockDim.x + threadIdx.x;
  if (idx >= 2048 * 256) return;
  int k = idx & 255, n = idx >> 8;
  float a = 0.f, b = 0.f;
  if (n < 2000) { a = gw1[(size_t)n * 523 + k]; b = gw1[(size_t)n * 523 + 256 + k]; }
  W1a[idx] = f2bf(a); W1b[idx] = f2bf(b);
}

// generic pad pack: W [N][K] fp32 -> Wp [Np][Kp] bf16 (zero pad)
__global__ void pack_wpad(const float* __restrict__ w, u16* __restrict__ Wp,
                          int N, int K, int Np, int Kp) {
  int idx = blockIdx.x * blockDim.x + threadIdx.x;
  if (idx >= Np * Kp) return;
  int k = idx % Kp, n = idx / Kp;
  float v = (n < N && k < K) ? w[(size_t)n * K + k] : 0.f;
  Wp[idx] = f2bf(v);
}

__global__ void pack_bias3(const float* __restrict__ b2, const float* __restrict__ b3,
                           const float* __restrict__ b4, float* __restrict__ bp) {
  int i = blockIdx.x * blockDim.x + threadIdx.x;
  if (i >= 2048) return;
  bp[i]        = (i < 2000) ? b2[i] : 0.f;
  bp[2048 + i] = (i < 2000) ? b3[i] : 0.f;
  bp[4096 + i] = (i < 2000) ? b4[i] : 0.f;
}

// ---------------- Q[b][o] = gb1[o] + qst[b] . gw1[o][512:523] ----------------
__global__ void q_build(const float* __restrict__ qst, const float* __restrict__ gw1,
                        const float* __restrict__ gb1, float* __restrict__ Q) {
  int idx = blockIdx.x * blockDim.x + threadIdx.x;
  if (idx >= 64 * 2048) return;
  int o = idx & 2047, b = idx >> 11;
  float v = 0.f;
  if (o < 2000) {
    v = gb1[o];
    const float* w = gw1 + (size_t)o * 523 + 512;
    const float* q = qst + b * 11;
#pragma unroll
    for (int k = 0; k < 11; k++) v += q[k] * w[k];
  }
  Q[idx] = v;
}

// ---------------- xg -> bf16 [128][2048] with 1/625 scale ----------------
__global__ void pack_xgb(const float* __restrict__ xg, u16* __restrict__ xgb) {
  int idx = blockIdx.x * blockDim.x + threadIdx.x;
  if (idx >= 128 * 2048) return;
  int row = idx >> 11;
  float v = (row < 64) ? xg[idx] * (1.f / 625.f) : 0.f;
  xgb[idx] = f2bf(v);
}

// ---------------- global->LDS async ----------------
typedef const __attribute__((address_space(1))) u32* gas1;
typedef __attribute__((address_space(3))) u32* las3;
__device__ __forceinline__ void gld16(const void* g, void* l) {
  __builtin_amdgcn_global_load_lds((gas1)g, (las3)l, 16, 0, 0);
}

// ---------------- 128^2 bf16 MFMA GEMM (small/medium shapes) ----------------
// EPI 0: fp32 raw; EPI 2: fp32 acc+bias; EPI 3: bf16 raw; EPI 5: bf16 relu(acc+bias)
template <int EPI>
__global__ __launch_bounds__(256) void gemm_bt(
    const u16* __restrict__ A, int lda,
    const u16* __restrict__ W, int ldb,
    float* __restrict__ Cf, u16* __restrict__ Cb, int ldc,
    const float* __restrict__ bias, int KT, int NTN) {
  __shared__ __align__(16) char lds[32768];
  int bid = blockIdx.x;
  int wg;
  if ((gridDim.x & 7) == 0) {
    int cpx = gridDim.x >> 3;
    wg = (bid & 7) * cpx + (bid >> 3);
  } else {
    wg = bid;
  }
  int mt = wg / NTN, nt = wg % NTN;
  int tid = threadIdx.x;
  int wave = tid >> 6, lane = tid & 63;
  int r = lane & 15, g = lane >> 4;
  int wr = wave >> 1, wc = wave & 1;

  const u16* Asrc = A + (size_t)(mt * 128 + wave * 32 + r) * lda + g * 8;
  const u16* Wsrc = W + (size_t)(nt * 128 + wave * 32 + r) * ldb + g * 8;

  f32x4 acc[4][4];
#pragma unroll
  for (int i = 0; i < 4; i++)
#pragma unroll
    for (int j = 0; j < 4; j++) acc[i][j] = (f32x4){0.f, 0.f, 0.f, 0.f};

  {
    char* Al = lds; char* Wl = lds + 8192;
    gld16(Asrc, Al + wave * 2048);
    gld16(Asrc + (size_t)16 * lda, Al + wave * 2048 + 1024);
    gld16(Wsrc, Wl + wave * 2048);
    gld16(Wsrc + (size_t)16 * ldb, Wl + wave * 2048 + 1024);
  }
  __syncthreads();

  int buf = 0;
  for (int kt = 0; kt < KT; kt++) {
    if (kt + 1 < KT) {
      int k0 = (kt + 1) * 32;
      char* Al = lds + (buf ^ 1) * 16384; char* Wl = Al + 8192;
      gld16(Asrc + k0, Al + wave * 2048);
      gld16(Asrc + k0 + (size_t)16 * lda, Al + wave * 2048 + 1024);
      gld16(Wsrc + k0, Wl + wave * 2048);
      gld16(Wsrc + k0 + (size_t)16 * ldb, Wl + wave * 2048 + 1024);
    }
    char* Al = lds + buf * 16384; char* Wl = Al + 8192;
    bf16x8 a[4], w[4];
#pragma unroll
    for (int i = 0; i < 4; i++) a[i] = *(const bf16x8*)(Al + (wr * 4 + i) * 1024 + lane * 16);
#pragma unroll
    for (int j = 0; j < 4; j++) w[j] = *(const bf16x8*)(Wl + (wc * 4 + j) * 1024 + lane * 16);
#pragma unroll
    for (int i = 0; i < 4; i++)
#pragma unroll
      for (int j = 0; j < 4; j++)
        acc[i][j] = __builtin_amdgcn_mfma_f32_16x16x32_bf16(a[i], w[j], acc[i][j], 0, 0, 0);
    __syncthreads();
    buf ^= 1;
  }

  int rowb = mt * 128 + wr * 64 + (lane >> 4) * 4;
  int colb = nt * 128 + wc * 64 + (lane & 15);
#pragma unroll
  for (int i = 0; i < 4; i++) {
#pragma unroll
    for (int j = 0; j < 4; j++) {
      int col = colb + j * 16;
      float bv = (EPI == 2 || EPI == 5) ? bias[col] : 0.f;
#pragma unroll
      for (int q = 0; q < 4; q++) {
        int row = rowb + i * 16 + q;
        float v = acc[i][j][q];
        if (EPI == 2) {
          Cf[(size_t)row * ldc + col] = v + bv;
        } else if (EPI == 3) {
          Cb[(size_t)row * ldc + col] = f2bf(v);
        } else if (EPI == 5) {
          float z = v + bv; z = z > 0.f ? z : 0.f;
          Cb[(size_t)row * ldc + col] = f2bf(z);
        } else {
          Cf[(size_t)row * ldc + col] = v;
        }
      }
    }
  }
}

// ---------------- 256^2 bf16 GEMM — 8-phase schedule, unroll-2 K-loop ----------------
#define MF16(d, av, bv) d = __builtin_amdgcn_mfma_f32_16x16x32_bf16(av, bv, d, 0, 0, 0)

template <int NT>
__global__ __launch_bounds__(512, 2) void gemm256(
    const u16* __restrict__ A, const u16* __restrict__ W,
    u16* __restrict__ Cb, const float* __restrict__ bias) {
  __shared__ __align__(16) char lds[131072];
  int bid = blockIdx.x;
  int cpx = gridDim.x >> 3;
  int wg = (bid & 7) * cpx + (bid >> 3);
  int mt = wg >> 3, nt = wg & 7;
  int tid = threadIdx.x;
  int wave = tid >> 6, lane = tid & 63;
  int lane16 = lane * 16;
  int wr = wave >> 2, wc = wave & 3;
  int wcl = wc & 1, wch = wc >> 1;

  auto stageA = [&](int tt, int slot, int h) {
#pragma unroll
    for (int j = 0; j < 2; j++) {
      int u = wave * 2 + j;
      const u16* src = A + (size_t)(mt * 256 + h * 128 + (u >> 1) * 16 + (lane & 15)) * 2048
                         + tt * 64 + (u & 1) * 32 + (lane >> 4) * 8;
      gld16(src, lds + slot * 65536 + h * 16384 + u * 1024);
    }
  };
  auto stageB = [&](int tt, int slot, int h) {
#pragma unroll
    for (int j = 0; j < 2; j++) {
      int u = wave * 2 + j;
      const u16* src = W + (size_t)(nt * 256 + h * 128 + (u >> 1) * 16 + (lane & 15)) * 2048
                         + tt * 64 + (u & 1) * 32 + (lane >> 4) * 8;
      gld16(src, lds + slot * 65536 + 32768 + h * 16384 + u * 1024);
    }
  };

  f32x4 acc[8][4];
#pragma unroll
  for (int i = 0; i < 8; i++)
#pragma unroll
    for (int j = 0; j < 4; j++) acc[i][j] = (f32x4){0.f, 0.f, 0.f, 0.f};

  stageA(0, 0, 0); stageA(0, 0, 1); stageB(0, 0, 0); stageB(0, 0, 1);
  stageB(1, 1, 0); stageB(1, 1, 1);
  asm volatile("s_waitcnt vmcnt(4)" ::: "memory");
  __builtin_amdgcn_s_barrier();

  bf16x8 b00, b01, b10, b11, b20, b21, b30, b31;

#define PHASE(Q, T, BUF)                                                         \
  {                                                                              \
    const char* Ab = lds + (BUF) * 65536 + wr * 16384;                           \
    const char* Bb = lds + (BUF) * 65536 + 32768 + wch * 16384;                  \
    if (Q == 0) {                                                                \
      b00 = *(const bf16x8*)(Bb + ((wcl * 4 + 0) * 2 + 0) * 1024 + lane16);      \
      b01 = *(const bf16x8*)(Bb + ((wcl * 4 + 0) * 2 + 1) * 1024 + lane16);      \
      b10 = *(const bf16x8*)(Bb + ((wcl * 4 + 1) * 2 + 0) * 1024 + lane16);      \
      b11 = *(const bf16x8*)(Bb + ((wcl * 4 + 1) * 2 + 1) * 1024 + lane16);      \
      b20 = *(const bf16x8*)(Bb + ((wcl * 4 + 2) * 2 + 0) * 1024 + lane16);      \
      b21 = *(const bf16x8*)(Bb + ((wcl * 4 + 2) * 2 + 1) * 1024 + lane16);      \
      b30 = *(const bf16x8*)(Bb + ((wcl * 4 + 3) * 2 + 0) * 1024 + lane16);      \
      b31 = *(const bf16x8*)(Bb + ((wcl * 4 + 3) * 2 + 1) * 1024 + lane16);      \
    }                                                                            \
    bf16x8 a00 = *(const bf16x8*)(Ab + ((2 * Q + 0) * 2 + 0) * 1024 + lane16);   \
    bf16x8 a01 = *(const bf16x8*)(Ab + ((2 * Q + 0) * 2 + 1) * 1024 + lane16);   \
    bf16x8 a10 = *(const bf16x8*)(Ab + ((2 * Q + 1) * 2 + 0) * 1024 + lane16);   \
    bf16x8 a11 = *(const bf16x8*)(Ab + ((2 * Q + 1) * 2 + 1) * 1024 + lane16);   \
    if (Q == 0) { if ((T) + 1 < NT) stageA((T) + 1, (BUF) ^ 1, 0); }             \
    if (Q == 1) { if ((T) + 1 < NT) stageA((T) + 1, (BUF) ^ 1, 1);               \
                  if ((T) + 2 < NT) stageB((T) + 2, (BUF), 0); }                 \
    if (Q == 2) { if ((T) + 2 < NT) stageB((T) + 2, (BUF), 1); }                 \
    __builtin_amdgcn_s_barrier();                                                \
    __builtin_amdgcn_s_setprio(1);                                               \
    MF16(acc[2 * Q + 0][0], a00, b00); MF16(acc[2 * Q + 0][0], a01, b01);        \
    MF16(acc[2 * Q + 0][1], a00, b10); MF16(acc[2 * Q + 0][1], a01, b11);        \
    MF16(acc[2 * Q + 0][2], a00, b20); MF16(acc[2 * Q + 0][2], a01, b21);        \
    MF16(acc[2 * Q + 0][3], a00, b30); MF16(acc[2 * Q + 0][3], a01, b31);        \
    MF16(acc[2 * Q + 1][0], a10, b00); MF16(acc[2 * Q + 1][0], a11, b01);        \
    MF16(acc[2 * Q + 1][1], a10, b10); MF16(acc[2 * Q + 1][1], a11, b11);        \
    MF16(acc[2 * Q + 1][2], a10, b20); MF16(acc[2 * Q + 1][2], a11, b21);        \
    MF16(acc[2 * Q + 1][3], a10, b30); MF16(acc[2 * Q + 1][3], a11, b31);        \
    __builtin_amdgcn_s_setprio(0);                                               \
    if (Q == 3) { asm volatile("s_waitcnt vmcnt(4)" ::: "memory"); }             \
    __builtin_amdgcn_s_barrier();                                                \
  }

#pragma unroll 1
  for (int t2 = 0; t2 < NT; t2 += 2) {
    PHASE(0, t2, 0) PHASE(1, t2, 0) PHASE(2, t2, 0) PHASE(3, t2, 0)
    PHASE(0, t2 + 1, 1) PHASE(1, t2 + 1, 1) PHASE(2, t2 + 1, 1) PHASE(3, t2 + 1, 1)
  }
#undef PHASE

  int rowb = mt * 256 + wr * 128 + (lane >> 4) * 4;
  int colb = nt * 256 + wc * 64 + (lane & 15);
#pragma unroll
  for (int i = 0; i < 8; i++) {
#pragma unroll
    for (int j = 0; j < 4; j++) {
      int col = colb + j * 16;
      float bv = bias[col];
#pragma unroll
      for (int q = 0; q < 4; q++) {
        int row = rowb + i * 16 + q;
        float v = acc[i][j][q] + bv;
        v = v > 0.f ? v : 0.f;
        Cb[(size_t)row * 2048 + col] = f2bf(v);
      }
    }
  }
}

// ---------------- h1 = relu(A_i + B_j + Q_b), rows = global pair index ----------------
__global__ void h1_build(const u16* __restrict__ Af, const u16* __restrict__ Bf,
                         const float* __restrict__ Q, u16* __restrict__ h1,
                         int r0, int nvalid) {
  int lrow = blockIdx.x;
  int t = threadIdx.x;
  u16* dst = h1 + (size_t)lrow * 2048;
  if (lrow >= nvalid) {
#pragma unroll
    for (int it = 0; it < 2; it++) {
      int o = it * 1024 + t * 4;
      ushort4 z; z.x = 0; z.y = 0; z.z = 0; z.w = 0;
      *(ushort4*)(dst + o) = z;
    }
    return;
  }
  int grow = r0 + lrow;
  int b = grow / 625; int rem = grow % 625;
  int i = rem / 25, j = rem % 25;
  const u16* Ap = Af + (size_t)(b * 25 + i) * 2048;
  const u16* Bp = Bf + (size_t)(b * 25 + j) * 2048;
  const float* Qp = Q + (size_t)b * 2048;
#pragma unroll
  for (int it = 0; it < 2; it++) {
    int o = it * 1024 + t * 4;
    ushort4 a4 = *(const ushort4*)(Ap + o);
    ushort4 b4 = *(const ushort4*)(Bp + o);
    float4 qv = *(const float4*)(Qp + o);
    ushort4 outv;
    float v;
    v = bf2f(a4.x) + bf2f(b4.x) + qv.x; outv.x = f2bf(v > 0.f ? v : 0.f);
    v = bf2f(a4.y) + bf2f(b4.y) + qv.y; outv.y = f2bf(v > 0.f ? v : 0.f);
    v = bf2f(a4.z) + bf2f(b4.z) + qv.z; outv.z = f2bf(v > 0.f ? v : 0.f);
    v = bf2f(a4.w) + bf2f(b4.w) + qv.w; outv.w = f2bf(v > 0.f ? v : 0.f);
    *(ushort4*)(dst + o) = outv;
  }
}

// ---------------- pair-sum reduce across chunk-straddling images ----------------
__global__ void zero_xg(float* __restrict__ xg) {
  int i = blockIdx.x * blockDim.x + threadIdx.x;
  if (i < 64 * 2048) xg[i] = 0.f;
}

__global__ void reduce_part2(const u16* __restrict__ h4, float* __restrict__ part,
                             int r0, int nvalid, int bfirst) {
  int seg = blockIdx.x; int s = blockIdx.y; int t = threadIdx.x;
  int b = bfirst + seg;
  int lo = b * 625 - r0; if (lo < 0) lo = 0;
  int hi = (b + 1) * 625 - r0; if (hi > nvalid) hi = nvalid;
  int len = hi - lo;
  int k0 = lo + (len * s) / 5;
  int k1 = lo + (len * (s + 1)) / 5;
  const u16* base = h4 + t * 8;
  float a0 = 0.f, a1 = 0.f, a2 = 0.f, a3 = 0.f, a4 = 0.f, a5 = 0.f, a6 = 0.f, a7 = 0.f;
  for (int k = k0; k < k1; k++) {
    uint4 u = *(const uint4*)(base + (size_t)k * 2048);
    a0 += bf2f((u16)(u.x & 0xffff)); a1 += bf2f((u16)(u.x >> 16));
    a2 += bf2f((u16)(u.y & 0xffff)); a3 += bf2f((u16)(u.y >> 16));
    a4 += bf2f((u16)(u.z & 0xffff)); a5 += bf2f((u16)(u.z >> 16));
    a6 += bf2f((u16)(u.w & 0xffff)); a7 += bf2f((u16)(u.w >> 16));
  }
  float* dst = part + ((size_t)(seg * 5 + s) * 2048) + t * 8;
  dst[0] = a0; dst[1] = a1; dst[2] = a2; dst[3] = a3;
  dst[4] = a4; dst[5] = a5; dst[6] = a6; dst[7] = a7;
}

__global__ void reduce_fin2(const float* __restrict__ part, float* __restrict__ xg,
                            int bfirst, int nseg) {
  int idx = blockIdx.x * blockDim.x + threadIdx.x;
  if (idx >= nseg * 2048) return;
  int seg = idx >> 11; int o = idx & 2047;
  float sv = 0.f;
#pragma unroll
  for (int s = 0; s < 5; s++) sv += part[(size_t)(seg * 5 + s) * 2048 + o];
  xg[(size_t)(bfirst + seg) * 2048 + o] += sv;
}

// ---------------- f-MLP layer 4: warp per (b,o), bf16 input ----------------
__global__ void f_layer4(const u16* __restrict__ x, const float* __restrict__ Wf,
                         const float* __restrict__ bf_, float* __restrict__ y) {
  int gwid = (blockIdx.x * blockDim.x + threadIdx.x) >> 6;
  int lane = threadIdx.x & 63;
  if (gwid >= 64 * 10) return;
  int b = gwid / 10, o = gwid % 10;
  const u16* xp = x + (size_t)b * 128;
  const float* wp = Wf + (size_t)o * 100;
  float s = 0.f;
  for (int k = lane; k < 100; k += 64) s += bf2f(xp[k]) * wp[k];
  for (int off = 32; off > 0; off >>= 1) s += __shfl_down(s, off);
  if (lane == 0) y[b * 16 + o] = s + bf_[o];
}

__global__ void lsm_kernel(const float* __restrict__ xf4, float* __restrict__ out) {
  int b = blockIdx.x * blockDim.x + threadIdx.x;
  if (b >= 64) return;
  const float* x = xf4 + b * 16;
  float m = x[0];
  for (int i = 1; i < 10; i++) m = fmaxf(m, x[i]);
  float s = 0.f;
  for (int i = 0; i < 10; i++) s += expf(x[i] - m);
  float ls = logf(s);
  for (int i = 0; i < 10; i++) out[b * 10 + i] = x[i] - m - ls;
}

// ---------------- host ----------------
extern "C" void kernel_launch(void* const* d_in, const int* in_sizes, int n_in,
                              void* d_out, int out_size, void* d_ws, size_t ws_size,
                              hipStream_t stream) {
  const float* img = (const float*)d_in[0];
  const float* qst = (const float*)d_in[1];
  const float* w1 = (const float*)d_in[2];  const float* b1 = (const float*)d_in[3];
  const float* w2 = (const float*)d_in[4];  const float* b2 = (const float*)d_in[5];
  const float* w3 = (const float*)d_in[6];  const float* b3 = (const float*)d_in[7];
  const float* w4 = (const float*)d_in[8];  const float* b4 = (const float*)d_in[9];
  const float* g1 = (const float*)d_in[10]; const float* be1 = (const float*)d_in[11];
  const float* g2 = (const float*)d_in[12]; const float* be2 = (const float*)d_in[13];
  const float* g3 = (const float*)d_in[14]; const float* be3 = (const float*)d_in[15];
  const float* g4 = (const float*)d_in[16]; const float* be4 = (const float*)d_in[17];
  const float* gw1 = (const float*)d_in[18]; const float* gb1 = (const float*)d_in[19];
  const float* gw2 = (const float*)d_in[20]; const float* gb2 = (const float*)d_in[21];
  const float* gw3 = (const float*)d_in[22]; const float* gb3 = (const float*)d_in[23];
  const float* gw4 = (const float*)d_in[24]; const float* gb4 = (const float*)d_in[25];
  const float* fw1 = (const float*)d_in[26]; const float* fb1 = (const float*)d_in[27];
  const float* fw2 = (const float*)d_in[28]; const float* fb2 = (const float*)d_in[29];
  const float* fw3 = (const float*)d_in[30]; const float* fb3 = (const float*)d_in[31];
  const float* fw4 = (const float*)d_in[32]; const float* fb4 = (const float*)d_in[33];
  float* out = (float*)d_out;

  char* P = (char*)d_ws;
  auto alloc = [&](size_t bytes) -> char* {
    char* r = P; P += (bytes + 255) & ~(size_t)255; return r;
  };
  // persistent
  u16* Wp2 = (u16*)alloc(2048ull * 2048 * 2);
  u16* Wp3 = (u16*)alloc(2048ull * 2048 * 2);
  u16* Wp4 = (u16*)alloc(2048ull * 2048 * 2);
  u16* Afu = (u16*)alloc(1664ull * 2048 * 2);
  u16* Bfu = (u16*)alloc(1664ull * 2048 * 2);
  float* Q = (float*)alloc(64ull * 2048 * 4);
  float* bp = (float*)alloc(3ull * 2048 * 4);
  float* xg = (float*)alloc(64ull * 2048 * 4);
  u16* obj = (u16*)alloc(1664ull * 256 * 2);
  u16* W1a = (u16*)alloc(2048ull * 256 * 2);
  u16* W1b = (u16*)alloc(2048ull * 256 * 2);
  // f-MLP packs / buffers
  u16* Fp1 = (u16*)alloc(1024ull * 2048 * 2);
  u16* Fp2 = (u16*)alloc(512ull * 1024 * 2);
  u16* Fp3 = (u16*)alloc(128ull * 512 * 2);
  float* fbc1 = (float*)alloc(1024 * 4);
  float* fbc2 = (float*)alloc(512 * 4);
  float* fbc3 = (float*)alloc(128 * 4);
  u16* xgb  = (u16*)alloc(128ull * 2048 * 2);
  u16* xf1b = (u16*)alloc(128ull * 1024 * 2);
  u16* xf2b = (u16*)alloc(128ull * 512 * 2);
  u16* xf3b = (u16*)alloc(128ull * 128 * 2);
  float* xf4 = (float*)alloc(64ull * 16 * 4);
  // h-phase (8192-row chunks)
  u16* h0  = (u16*)alloc(8192ull * 2048 * 2);
  u16* h1b = (u16*)alloc(8192ull * 2048 * 2);
  float* rpart = (float*)alloc(14ull * 5 * 2048 * 4);
  // conv-phase
  float* C1 = (float*)alloc(92416ull * 32 * 4);
  u16*   X2 = (u16*)alloc(23168ull * 288 * 2);
  float* C2 = (float*)alloc(23168ull * 128 * 4);
  u16*   X3 = (u16*)alloc(6400ull * 576 * 2);
  float* C3 = (float*)alloc(6400ull * 128 * 4);
  u16*   X4 = (u16*)alloc(1664ull * 1152 * 2);
  float* C4 = (float*)alloc(1664ull * 256 * 4);
  u16*  Wc2 = (u16*)alloc(128ull * 288 * 2);
  u16*  Wc3 = (u16*)alloc(128ull * 576 * 2);
  u16*  Wc4 = (u16*)alloc(256ull * 1152 * 2);
  float* bc2 = (float*)alloc(128 * 4);
  float* bc3 = (float*)alloc(128 * 4);
  float* bc4 = (float*)alloc(256 * 4);
  float* bnp = (float*)alloc(BN_S * 512 * 4);
  float* ss  = (float*)alloc(512 * 4);

  // ---- conv weight/bias packs ----
  pack_convw<<<(128 * 288 + 255) / 256, 256, 0, stream>>>(w2, Wc2, 64, 32, 128);
  pack_convw<<<(128 * 576 + 255) / 256, 256, 0, stream>>>(w3, Wc3, 128, 64, 128);
  pack_convw<<<(256 * 1152 + 255) / 256, 256, 0, stream>>>(w4, Wc4, 256, 128, 256);
  pad_bias<<<1, 256, 0, stream>>>(b2, bc2, 64, 128);
  pad_bias<<<1, 256, 0, stream>>>(b3, bc3, 128, 128);
  pad_bias<<<1, 256, 0, stream>>>(b4, bc4, 256, 256);

  // ---- conv stack ----
  conv1_lds<<<64 * 38, 256, 0, stream>>>(img, w1, b1, C1);
  bn_partial<<<dim3(32, BN_S), 256, 0, stream>>>(C1, 32, 92416, bnp);
  bn_final<<<1, 256, 0, stream>>>(bnp, g1, be1, ss, 32, 92416);
  bnrelu_im2col<<<(23168 * 9 * 8 + 255) / 256, 256, 0, stream>>>(C1, 32, 38, 38, ss, X2, 19, 19, 32, 23168);
  gemm_bt<2><<<181, 256, 0, stream>>>(X2, 288, Wc2, 288, C2, nullptr, 128, bc2, 9, 1);

  bn_partial<<<dim3(64, BN_S), 256, 0, stream>>>(C2, 128, 23104, bnp);
  bn_final<<<1, 256, 0, stream>>>(bnp, g2, be2, ss, 64, 23104);
  bnrelu_im2col<<<(6400 * 9 * 16 + 255) / 256, 256, 0, stream>>>(C2, 128, 19, 19, ss, X3, 10, 10, 64, 6400);
  gemm_bt<2><<<50, 256, 0, stream>>>(X3, 576, Wc3, 576, C3, nullptr, 128, bc3, 18, 1);

  bn_partial<<<dim3(128, BN_S), 256, 0, stream>>>(C3, 128, 6400, bnp);
  bn_final<<<1, 256, 0, stream>>>(bnp, g3, be3, ss, 128, 6400);
  bnrelu_im2col<<<(1664 * 9 * 32 + 255) / 256, 256, 0, stream>>>(C3, 128, 10, 10, ss, X4, 5, 5, 128, 1664);
  gemm_bt<2><<<26, 256, 0, stream>>>(X4, 1152, Wc4, 1152, C4, nullptr, 256, bc4, 36, 2);

  bn_partial<<<dim3(256, BN_S), 256, 0, stream>>>(C4, 256, 1600, bnp);
  bn_final<<<1, 256, 0, stream>>>(bnp, g4, be4, ss, 256, 1600);
  obj_from_c4<<<(1664 * 256 + 255) / 256, 256, 0, stream>>>(C4, ss, obj);

  // ---- MLP packs ----
  pack_w1<<<2048, 256, 0, stream>>>(gw1, W1a, W1b);
  pack_wpad<<<(2048 * 2048 + 255) / 256, 256, 0, stream>>>(gw2, Wp2, 2000, 2000, 2048, 2048);
  pack_wpad<<<(2048 * 2048 + 255) / 256, 256, 0, stream>>>(gw3, Wp3, 2000, 2000, 2048, 2048);
  pack_wpad<<<(2048 * 2048 + 255) / 256, 256, 0, stream>>>(gw4, Wp4, 2000, 2000, 2048, 2048);
  pack_bias3<<<8, 256, 0, stream>>>(gb2, gb3, gb4, bp);
  q_build<<<512, 256, 0, stream>>>(qst, gw1, gb1, Q);
  // f-MLP packs
  pack_wpad<<<(1024 * 2048 + 255) / 256, 256, 0, stream>>>(fw1, Fp1, 1000, 2000, 1024, 2048);
  pack_wpad<<<(512 * 1024 + 255) / 256, 256, 0, stream>>>(fw2, Fp2, 500, 1000, 512, 1024);
  pack_wpad<<<(128 * 512 + 255) / 256, 256, 0, stream>>>(fw3, Fp3, 100, 500, 128, 512);
  pad_bias<<<4, 256, 0, stream>>>(fb1, fbc1, 1000, 1024);
  pad_bias<<<2, 256, 0, stream>>>(fb2, fbc2, 500, 512);
  pad_bias<<<1, 256, 0, stream>>>(fb3, fbc3, 100, 128);

  // ---- layer-1 decomposition GEMMs (bf16 raw out) ----
  gemm_bt<3><<<13 * 16, 256, 0, stream>>>(obj, 256, W1a, 256, nullptr, Afu, 2048, nullptr, 8, 16);
  gemm_bt<3><<<13 * 16, 256, 0, stream>>>(obj, 256, W1b, 256, nullptr, Bfu, 2048, nullptr, 8, 16);

  // ---- g-MLP in 8192-row chunks (grid exactly 256 blocks per GEMM) ----
  zero_xg<<<512, 256, 0, stream>>>(xg);
  const int TOTROWS = 64 * 625;  // 40000
  for (int c = 0; c < 5; c++) {
    int r0 = c * 8192;
    int nvalid = TOTROWS - r0; if (nvalid > 8192) nvalid = 8192;
    h1_build<<<8192, 256, 0, stream>>>(Afu, Bfu, Q, h0, r0, nvalid);
    gemm256<32><<<256, 512, 0, stream>>>(h0, Wp2, h1b, bp);
    gemm256<32><<<256, 512, 0, stream>>>(h1b, Wp3, h0, bp + 2048);
    gemm256<32><<<256, 512, 0, stream>>>(h0, Wp4, h1b, bp + 4096);
    int bfirst = r0 / 625;
    int blast = (r0 + nvalid - 1) / 625;
    int nseg = blast - bfirst + 1;
    reduce_part2<<<dim3(nseg, 5), 256, 0, stream>>>(h1b, rpart, r0, nvalid, bfirst);
    reduce_fin2<<<(nseg * 2048 + 255) / 256, 256, 0, stream>>>(rpart, xg, bfirst, nseg);
  }

  // ---- f MLP: layers 1-3 as MFMA GEMMs, layer 4 tiny ----
  pack_xgb<<<(128 * 2048 + 255) / 256, 256, 0, stream>>>(xg, xgb);
  gemm_bt<5><<<8, 256, 0, stream>>>(xgb, 2048, Fp1, 2048, nullptr, xf1b, 1024, fbc1, 64, 8);
  gemm_bt<5><<<4, 256, 0, stream>>>(xf1b, 1024, Fp2, 1024, nullptr, xf2b, 512, fbc2, 32, 4);
  gemm_bt<5><<<1, 256, 0, stream>>>(xf2b, 512, Fp3, 512, nullptr, xf3b, 128, fbc3, 16, 1);
  f_layer4<<<(64 * 10 * 64 + 255) / 256, 256, 0, stream>>>(xf3b, fw4, fb4, xf4);
  lsm_kernel<<<1, 64, 0, stream>>>(xf4, out);
}

// Round 10
// 1420.196 us; speedup vs baseline: 1.2391x; 1.1082x over previous
//
#include <hip/hip_runtime.h>

typedef unsigned short u16;
typedef unsigned int u32;
typedef __attribute__((ext_vector_type(8))) short bf16x8;
typedef __attribute__((ext_vector_type(4))) float f32x4;

#define BN_EPS 1e-5f
#define BN_S 16

__device__ __forceinline__ float bf2f(u16 u) {
  union { unsigned u; float f; } x; x.u = ((unsigned)u) << 16; return x.f;
}
__device__ __forceinline__ u16 f2bf(float f) {
  union { float f; unsigned u; } x; x.f = f;
  unsigned r = x.u + 0x7FFFu + ((x.u >> 16) & 1u);
  return (u16)(r >> 16);
}

// ---------------- conv1: LDS-staged, one block per (n, ho) ----------------
__global__ __launch_bounds__(256) void conv1_lds(const float* __restrict__ img,
                                                 const float* __restrict__ w,
                                                 const float* __restrict__ b,
                                                 float* __restrict__ C1) {
  int blk = blockIdx.x;             // n*38 + ho
  int n = blk / 38, ho = blk % 38;
  __shared__ float in_s[9 * 80];
  __shared__ float w_s[32 * 27];
  __shared__ float b_s[32];
  int t = threadIdx.x;
  for (int i = t; i < 720; i += 256) in_s[i] = 0.f;
  __syncthreads();
  for (int i = t; i < 675; i += 256) {
    int wi = i % 75; int q = i / 75; int kh = q % 3; int ci = q / 3;
    int hi = ho * 2 - 1 + kh;
    if (hi >= 0 && hi < 75)
      in_s[(ci * 3 + kh) * 80 + wi + 1] = img[((size_t)(n * 3 + ci) * 75 + hi) * 75 + wi];
  }
  for (int i = t; i < 864; i += 256) w_s[i] = w[i];
  if (t < 32) b_s[t] = b[t];
  __syncthreads();
  for (int idx = t; idx < 1216; idx += 256) {
    int wo = idx >> 5, co = idx & 31;
    float acc = b_s[co];
    const float* wp = w_s + co * 27;
#pragma unroll
    for (int ci = 0; ci < 3; ci++) {
#pragma unroll
      for (int kh = 0; kh < 3; kh++) {
        const float* ip = in_s + (ci * 3 + kh) * 80 + 2 * wo;
        const float* wq = wp + ci * 9 + kh * 3;
        acc += ip[0] * wq[0] + ip[1] * wq[1] + ip[2] * wq[2];
      }
    }
    C1[((size_t)blk * 38 + wo) * 32 + co] = acc;
  }
}

// ---------------- BN column-stats (deterministic 2-stage) ----------------
__global__ void bn_partial(const float* __restrict__ C, int ldc, int M,
                           float* __restrict__ part) {
  int c = blockIdx.x; int s = blockIdx.y; int t = threadIdx.x;
  int rowsPer = (M + BN_S - 1) / BN_S;
  int r0 = s * rowsPer; int r1 = r0 + rowsPer; if (r1 > M) r1 = M;
  float s1 = 0.f, s2 = 0.f;
  for (int r = r0 + t; r < r1; r += 256) {
    float v = C[(size_t)r * ldc + c]; s1 += v; s2 += v * v;
  }
  __shared__ float l1[256], l2[256];
  l1[t] = s1; l2[t] = s2; __syncthreads();
  for (int off = 128; off > 0; off >>= 1) {
    if (t < off) { l1[t] += l1[t + off]; l2[t] += l2[t + off]; }
    __syncthreads();
  }
  if (t == 0) { part[s * 512 + c] = l1[0]; part[s * 512 + 256 + c] = l2[0]; }
}

__global__ void bn_final(const float* __restrict__ part, const float* __restrict__ gamma,
                         const float* __restrict__ beta, float* __restrict__ ss,
                         int C, int M) {
  int c = threadIdx.x;
  if (c >= C) { if (c < 256) { ss[c] = 0.f; ss[256 + c] = 0.f; } return; }
  float s1 = 0.f, s2 = 0.f;
#pragma unroll
  for (int s = 0; s < BN_S; s++) { s1 += part[s * 512 + c]; s2 += part[s * 512 + 256 + c]; }
  float mu = s1 / M;
  float var = s2 / M - mu * mu;
  float sc = gamma[c] * rsqrtf(var + BN_EPS);
  ss[c] = sc; ss[256 + c] = beta[c] - mu * sc;
}

// ---------------- fused BN+ReLU + im2col -> bf16 X[row][tap*Ci+ci] ----------------
__global__ void bnrelu_im2col(const float* __restrict__ Cprev, int ldprev, int Hp, int Wp,
                              const float* __restrict__ ss, u16* __restrict__ X,
                              int Ho, int Wo, int Ci, int Mp) {
  int civ4 = Ci >> 2;
  int idx = blockIdx.x * blockDim.x + threadIdx.x;
  int total = Mp * 9 * civ4;
  if (idx >= total) return;
  int cv = idx % civ4; int t2 = idx / civ4;
  int tap = t2 % 9; int row = t2 / 9;
  int K = 9 * Ci;
  u16* dst = X + (size_t)row * K + tap * Ci + cv * 4;
  int HW = Ho * Wo;
  int Mvalid = 64 * HW;
  ushort4 o4; o4.x = 0; o4.y = 0; o4.z = 0; o4.w = 0;
  if (row < Mvalid) {
    int wo = row % Wo; int t = row / Wo;
    int ho = t % Ho; int n = t / Ho;
    int kh = tap / 3, kw = tap % 3;
    int hi = ho * 2 - 1 + kh, wi = wo * 2 - 1 + kw;
    if (hi >= 0 && hi < Hp && wi >= 0 && wi < Wp) {
      const float* src = Cprev + ((size_t)((n * Hp + hi) * Wp + wi)) * ldprev + cv * 4;
      float4 v = *(const float4*)src;
      int c0 = cv * 4;
      float a;
      a = v.x * ss[c0 + 0] + ss[256 + c0 + 0]; o4.x = f2bf(a > 0.f ? a : 0.f);
      a = v.y * ss[c0 + 1] + ss[256 + c0 + 1]; o4.y = f2bf(a > 0.f ? a : 0.f);
      a = v.z * ss[c0 + 2] + ss[256 + c0 + 2]; o4.z = f2bf(a > 0.f ? a : 0.f);
      a = v.w * ss[c0 + 3] + ss[256 + c0 + 3]; o4.w = f2bf(a > 0.f ? a : 0.f);
    }
  }
  *(ushort4*)dst = o4;
}

// ---------------- conv weight pack ----------------
__global__ void pack_convw(const float* __restrict__ w, u16* __restrict__ Wp,
                           int Co, int Ci, int Cop) {
  int K = 9 * Ci;
  int idx = blockIdx.x * blockDim.x + threadIdx.x;
  if (idx >= Cop * K) return;
  int k = idx % K; int co = idx / K;
  int tap = k / Ci; int ci = k % Ci;
  float v = (co < Co) ? w[((size_t)co * Ci + ci) * 9 + tap] : 0.f;
  Wp[idx] = f2bf(v);
}

__global__ void pad_bias(const float* __restrict__ b, float* __restrict__ bc, int Co, int Cop) {
  int i = blockIdx.x * blockDim.x + threadIdx.x;
  if (i < Cop) bc[i] = (i < Co) ? b[i] : 0.f;
}

// ---------------- obj pack from C4 with BN+ReLU ----------------
__global__ void obj_from_c4(const float* __restrict__ C4, const float* __restrict__ ss,
                            u16* __restrict__ obj) {
  int idx = blockIdx.x * blockDim.x + threadIdx.x;
  if (idx >= 1664 * 256) return;
  int c = idx & 255; int row = idx >> 8;
  float v = 0.f;
  if (row < 1600) {
    float x = C4[(size_t)row * 256 + c];
    x = x * ss[c] + ss[256 + c];
    v = x > 0.f ? x : 0.f;
  }
  obj[idx] = f2bf(v);
}

// ---------------- MLP weight packs ----------------
__global__ void pack_w1(const float* __restrict__ gw1, u16* __restrict__ W1a, u16* __restrict__ W1b) {
  int idx = blockIdx.x * blockDim.x + threadIdx.x;
  if (idx >= 2048 * 256) return;
  int k = idx & 255, n = idx >> 8;
  float a = 0.f, b = 0.f;
  if (n < 2000) { a = gw1[(size_t)n * 523 + k]; b = gw1[(size_t)n * 523 + 256 + k]; }
  W1a[idx] = f2bf(a); W1b[idx] = f2bf(b);
}

// generic pad pack: W [N][K] fp32 -> Wp [Np][Kp] bf16 (zero pad)
__global__ void pack_wpad(const float* __restrict__ w, u16* __restrict__ Wp,
                          int N, int K, int Np, int Kp) {
  int idx = blockIdx.x * blockDim.x + threadIdx.x;
  if (idx >= Np * Kp) return;
  int k = idx % Kp, n = idx / Kp;
  float v = (n < N && k < K) ? w[(size_t)n * K + k] : 0.f;
  Wp[idx] = f2bf(v);
}

__global__ void pack_bias3(const float* __restrict__ b2, const float* __restrict__ b3,
                           const float* __restrict__ b4, float* __restrict__ bp) {
  int i = blockIdx.x * blockDim.x + threadIdx.x;
  if (i >= 2048) return;
  bp[i]        = (i < 2000) ? b2[i] : 0.f;
  bp[2048 + i] = (i < 2000) ? b3[i] : 0.f;
  bp[4096 + i] = (i < 2000) ? b4[i] : 0.f;
}

// ---------------- Q[b][o] = gb1[o] + qst[b] . gw1[o][512:523] ----------------
__global__ void q_build(const float* __restrict__ qst, const float* __restrict__ gw1,
                        const float* __restrict__ gb1, float* __restrict__ Q) {
  int idx = blockIdx.x * blockDim.x + threadIdx.x;
  if (idx >= 64 * 2048) return;
  int o = idx & 2047, b = idx >> 11;
  float v = 0.f;
  if (o < 2000) {
    v = gb1[o];
    const float* w = gw1 + (size_t)o * 523 + 512;
    const float* q = qst + b * 11;
#pragma unroll
    for (int k = 0; k < 11; k++) v += q[k] * w[k];
  }
  Q[idx] = v;
}

// ---------------- xg -> bf16 [128][2048] with 1/625 scale ----------------
__global__ void pack_xgb(const float* __restrict__ xg, u16* __restrict__ xgb) {
  int idx = blockIdx.x * blockDim.x + threadIdx.x;
  if (idx >= 128 * 2048) return;
  int row = idx >> 11;
  float v = (row < 64) ? xg[idx] * (1.f / 625.f) : 0.f;
  xgb[idx] = f2bf(v);
}

// ---------------- global->LDS async ----------------
typedef const __attribute__((address_space(1))) u32* gas1;
typedef __attribute__((address_space(3))) u32* las3;
__device__ __forceinline__ void gld16(const void* g, void* l) {
  __builtin_amdgcn_global_load_lds((gas1)g, (las3)l, 16, 0, 0);
}

// ---------------- 128^2 bf16 MFMA GEMM (small/medium shapes) ----------------
// EPI 0: fp32 raw; EPI 2: fp32 acc+bias; EPI 3: bf16 raw; EPI 5: bf16 relu(acc+bias)
template <int EPI>
__global__ __launch_bounds__(256) void gemm_bt(
    const u16* __restrict__ A, int lda,
    const u16* __restrict__ W, int ldb,
    float* __restrict__ Cf, u16* __restrict__ Cb, int ldc,
    const float* __restrict__ bias, int KT, int NTN) {
  __shared__ __align__(16) char lds[32768];
  int bid = blockIdx.x;
  int wg;
  if ((gridDim.x & 7) == 0) {
    int cpx = gridDim.x >> 3;
    wg = (bid & 7) * cpx + (bid >> 3);
  } else {
    wg = bid;
  }
  int mt = wg / NTN, nt = wg % NTN;
  int tid = threadIdx.x;
  int wave = tid >> 6, lane = tid & 63;
  int r = lane & 15, g = lane >> 4;
  int wr = wave >> 1, wc = wave & 1;

  const u16* Asrc = A + (size_t)(mt * 128 + wave * 32 + r) * lda + g * 8;
  const u16* Wsrc = W + (size_t)(nt * 128 + wave * 32 + r) * ldb + g * 8;

  f32x4 acc[4][4];
#pragma unroll
  for (int i = 0; i < 4; i++)
#pragma unroll
    for (int j = 0; j < 4; j++) acc[i][j] = (f32x4){0.f, 0.f, 0.f, 0.f};

  {
    char* Al = lds; char* Wl = lds + 8192;
    gld16(Asrc, Al + wave * 2048);
    gld16(Asrc + (size_t)16 * lda, Al + wave * 2048 + 1024);
    gld16(Wsrc, Wl + wave * 2048);
    gld16(Wsrc + (size_t)16 * ldb, Wl + wave * 2048 + 1024);
  }
  __syncthreads();

  int buf = 0;
  for (int kt = 0; kt < KT; kt++) {
    if (kt + 1 < KT) {
      int k0 = (kt + 1) * 32;
      char* Al = lds + (buf ^ 1) * 16384; char* Wl = Al + 8192;
      gld16(Asrc + k0, Al + wave * 2048);
      gld16(Asrc + k0 + (size_t)16 * lda, Al + wave * 2048 + 1024);
      gld16(Wsrc + k0, Wl + wave * 2048);
      gld16(Wsrc + k0 + (size_t)16 * ldb, Wl + wave * 2048 + 1024);
    }
    char* Al = lds + buf * 16384; char* Wl = Al + 8192;
    bf16x8 a[4], w[4];
#pragma unroll
    for (int i = 0; i < 4; i++) a[i] = *(const bf16x8*)(Al + (wr * 4 + i) * 1024 + lane * 16);
#pragma unroll
    for (int j = 0; j < 4; j++) w[j] = *(const bf16x8*)(Wl + (wc * 4 + j) * 1024 + lane * 16);
#pragma unroll
    for (int i = 0; i < 4; i++)
#pragma unroll
      for (int j = 0; j < 4; j++)
        acc[i][j] = __builtin_amdgcn_mfma_f32_16x16x32_bf16(a[i], w[j], acc[i][j], 0, 0, 0);
    __syncthreads();
    buf ^= 1;
  }

  int rowb = mt * 128 + wr * 64 + (lane >> 4) * 4;
  int colb = nt * 128 + wc * 64 + (lane & 15);
#pragma unroll
  for (int i = 0; i < 4; i++) {
#pragma unroll
    for (int j = 0; j < 4; j++) {
      int col = colb + j * 16;
      float bv = (EPI == 2 || EPI == 5) ? bias[col] : 0.f;
#pragma unroll
      for (int q = 0; q < 4; q++) {
        int row = rowb + i * 16 + q;
        float v = acc[i][j][q];
        if (EPI == 2) {
          Cf[(size_t)row * ldc + col] = v + bv;
        } else if (EPI == 3) {
          Cb[(size_t)row * ldc + col] = f2bf(v);
        } else if (EPI == 5) {
          float z = v + bv; z = z > 0.f ? z : 0.f;
          Cb[(size_t)row * ldc + col] = f2bf(z);
        } else {
          Cf[(size_t)row * ldc + col] = v;
        }
      }
    }
  }
}

// ---------------- 256^2 bf16 GEMM — 8-phase, coalesced staging + XOR swizzle ----------------
// LDS per half-tile: linear row-major [128 rows][8 chunks x 16B], content swizzled:
// LDS[r][c] = G[r][c ^ (r&7)]. Stage: linear dest, inverse-swizzled coalesced source
// (8 x 128B full lines per instruction). Read: chunk = (ks*4 + (lane>>4)) ^ (lane&7)
// -> conflict-free (2-way aliasing only). Schedule identical to R9.
#define MF16(d, av, bv) d = __builtin_amdgcn_mfma_f32_16x16x32_bf16(av, bv, d, 0, 0, 0)

template <int NT>
__global__ __launch_bounds__(512, 2) void gemm256(
    const u16* __restrict__ A, const u16* __restrict__ W,
    u16* __restrict__ Cb, const float* __restrict__ bias) {
  __shared__ __align__(16) char lds[131072];
  int bid = blockIdx.x;
  int cpx = gridDim.x >> 3;
  int wg = (bid & 7) * cpx + (bid >> 3);
  int mt = wg >> 3, nt = wg & 7;
  int tid = threadIdx.x;
  int wave = tid >> 6, lane = tid & 63;
  int wr = wave >> 2, wc = wave & 3;
  int wcl = wc & 1, wch = wc >> 1;
  int l15 = lane & 15, l7 = lane & 7, lh = lane >> 4;

  // stage one half-tile (128 rows x 64 k = 16KB) of tile tt into LDS slot, half h.
  // sweep s: rows s*64 + wave*8 + (lane>>3); source chunk (lane&7)^(row&7), row&7 = lane>>3.
  int srcChunkOff = (((lane & 7) ^ (lane >> 3)) << 3);  // elements (x8 = 16B chunks)
  int srcRowInWave = (lane >> 3);
  auto stageA = [&](int tt, int slot, int h) {
#pragma unroll
    for (int s = 0; s < 2; s++) {
      const u16* src = A + (size_t)(mt * 256 + h * 128 + s * 64 + wave * 8 + srcRowInWave) * 2048
                         + tt * 64 + srcChunkOff;
      gld16(src, lds + slot * 65536 + h * 16384 + s * 8192 + wave * 1024);
    }
  };
  auto stageB = [&](int tt, int slot, int h) {
#pragma unroll
    for (int s = 0; s < 2; s++) {
      const u16* src = W + (size_t)(nt * 256 + h * 128 + s * 64 + wave * 8 + srcRowInWave) * 2048
                         + tt * 64 + srcChunkOff;
      gld16(src, lds + slot * 65536 + 32768 + h * 16384 + s * 8192 + wave * 1024);
    }
  };

  f32x4 acc[8][4];
#pragma unroll
  for (int i = 0; i < 8; i++)
#pragma unroll
    for (int j = 0; j < 4; j++) acc[i][j] = (f32x4){0.f, 0.f, 0.f, 0.f};

  stageA(0, 0, 0); stageA(0, 0, 1); stageB(0, 0, 0); stageB(0, 0, 1);
  stageB(1, 1, 0); stageB(1, 1, 1);
  asm volatile("s_waitcnt vmcnt(4)" ::: "memory");
  __builtin_amdgcn_s_barrier();

  bf16x8 b00, b01, b10, b11, b20, b21, b30, b31;

// swizzled read offsets within a 16KB half-region (row-local, chunk XOR)
#define AROFF(Q, i, ks) \
  ((((2 * (Q) + (i)) * 16 + l15) * 128) + (((((ks) * 4) + lh) ^ l7) << 4))
#define BROFF(j, ks) \
  ((((wcl * 4 + (j)) * 16 + l15) * 128) + (((((ks) * 4) + lh) ^ l7) << 4))

#define PHASE(Q, T, BUF)                                                         \
  {                                                                              \
    const char* Ab = lds + (BUF) * 65536 + wr * 16384;                           \
    const char* Bb = lds + (BUF) * 65536 + 32768 + wch * 16384;                  \
    if (Q == 0) {                                                                \
      b00 = *(const bf16x8*)(Bb + BROFF(0, 0));                                  \
      b01 = *(const bf16x8*)(Bb + BROFF(0, 1));                                  \
      b10 = *(const bf16x8*)(Bb + BROFF(1, 0));                                  \
      b11 = *(const bf16x8*)(Bb + BROFF(1, 1));                                  \
      b20 = *(const bf16x8*)(Bb + BROFF(2, 0));                                  \
      b21 = *(const bf16x8*)(Bb + BROFF(2, 1));                                  \
      b30 = *(const bf16x8*)(Bb + BROFF(3, 0));                                  \
      b31 = *(const bf16x8*)(Bb + BROFF(3, 1));                                  \
    }                                                                            \
    bf16x8 a00 = *(const bf16x8*)(Ab + AROFF(Q, 0, 0));                          \
    bf16x8 a01 = *(const bf16x8*)(Ab + AROFF(Q, 0, 1));                          \
    bf16x8 a10 = *(const bf16x8*)(Ab + AROFF(Q, 1, 0));                          \
    bf16x8 a11 = *(const bf16x8*)(Ab + AROFF(Q, 1, 1));                          \
    if (Q == 0) { if ((T) + 1 < NT) stageA((T) + 1, (BUF) ^ 1, 0); }             \
    if (Q == 1) { if ((T) + 1 < NT) stageA((T) + 1, (BUF) ^ 1, 1);               \
                  if ((T) + 2 < NT) stageB((T) + 2, (BUF), 0); }                 \
    if (Q == 2) { if ((T) + 2 < NT) stageB((T) + 2, (BUF), 1); }                 \
    __builtin_amdgcn_s_barrier();                                                \
    __builtin_amdgcn_s_setprio(1);                                               \
    MF16(acc[2 * Q + 0][0], a00, b00); MF16(acc[2 * Q + 0][0], a01, b01);        \
    MF16(acc[2 * Q + 0][1], a00, b10); MF16(acc[2 * Q + 0][1], a01, b11);        \
    MF16(acc[2 * Q + 0][2], a00, b20); MF16(acc[2 * Q + 0][2], a01, b21);        \
    MF16(acc[2 * Q + 0][3], a00, b30); MF16(acc[2 * Q + 0][3], a01, b31);        \
    MF16(acc[2 * Q + 1][0], a10, b00); MF16(acc[2 * Q + 1][0], a11, b01);        \
    MF16(acc[2 * Q + 1][1], a10, b10); MF16(acc[2 * Q + 1][1], a11, b11);        \
    MF16(acc[2 * Q + 1][2], a10, b20); MF16(acc[2 * Q + 1][2], a11, b21);        \
    MF16(acc[2 * Q + 1][3], a10, b30); MF16(acc[2 * Q + 1][3], a11, b31);        \
    __builtin_amdgcn_s_setprio(0);                                               \
    if (Q == 3) { asm volatile("s_waitcnt vmcnt(4)" ::: "memory"); }             \
    __builtin_amdgcn_s_barrier();                                                \
  }

#pragma unroll 1
  for (int t2 = 0; t2 < NT; t2 += 2) {
    PHASE(0, t2, 0) PHASE(1, t2, 0) PHASE(2, t2, 0) PHASE(3, t2, 0)
    PHASE(0, t2 + 1, 1) PHASE(1, t2 + 1, 1) PHASE(2, t2 + 1, 1) PHASE(3, t2 + 1, 1)
  }
#undef PHASE
#undef AROFF
#undef BROFF

  int rowb = mt * 256 + wr * 128 + (lane >> 4) * 4;
  int colb = nt * 256 + wc * 64 + (lane & 15);
#pragma unroll
  for (int i = 0; i < 8; i++) {
#pragma unroll
    for (int j = 0; j < 4; j++) {
      int col = colb + j * 16;
      float bv = bias[col];
#pragma unroll
      for (int q = 0; q < 4; q++) {
        int row = rowb + i * 16 + q;
        float v = acc[i][j][q] + bv;
        v = v > 0.f ? v : 0.f;
        Cb[(size_t)row * 2048 + col] = f2bf(v);
      }
    }
  }
}

// ---------------- h1 = relu(A_i + B_j + Q_b), rows = global pair index ----------------
__global__ void h1_build(const u16* __restrict__ Af, const u16* __restrict__ Bf,
                         const float* __restrict__ Q, u16* __restrict__ h1,
                         int r0, int nvalid) {
  int lrow = blockIdx.x;
  int t = threadIdx.x;
  u16* dst = h1 + (size_t)lrow * 2048;
  if (lrow >= nvalid) {
#pragma unroll
    for (int it = 0; it < 2; it++) {
      int o = it * 1024 + t * 4;
      ushort4 z; z.x = 0; z.y = 0; z.z = 0; z.w = 0;
      *(ushort4*)(dst + o) = z;
    }
    return;
  }
  int grow = r0 + lrow;
  int b = grow / 625; int rem = grow % 625;
  int i = rem / 25, j = rem % 25;
  const u16* Ap = Af + (size_t)(b * 25 + i) * 2048;
  const u16* Bp = Bf + (size_t)(b * 25 + j) * 2048;
  const float* Qp = Q + (size_t)b * 2048;
#pragma unroll
  for (int it = 0; it < 2; it++) {
    int o = it * 1024 + t * 4;
    ushort4 a4 = *(const ushort4*)(Ap + o);
    ushort4 b4 = *(const ushort4*)(Bp + o);
    float4 qv = *(const float4*)(Qp + o);
    ushort4 outv;
    float v;
    v = bf2f(a4.x) + bf2f(b4.x) + qv.x; outv.x = f2bf(v > 0.f ? v : 0.f);
    v = bf2f(a4.y) + bf2f(b4.y) + qv.y; outv.y = f2bf(v > 0.f ? v : 0.f);
    v = bf2f(a4.z) + bf2f(b4.z) + qv.z; outv.z = f2bf(v > 0.f ? v : 0.f);
    v = bf2f(a4.w) + bf2f(b4.w) + qv.w; outv.w = f2bf(v > 0.f ? v : 0.f);
    *(ushort4*)(dst + o) = outv;
  }
}

// ---------------- pair-sum reduce across chunk-straddling images ----------------
__global__ void zero_xg(float* __restrict__ xg) {
  int i = blockIdx.x * blockDim.x + threadIdx.x;
  if (i < 64 * 2048) xg[i] = 0.f;
}

__global__ void reduce_part2(const u16* __restrict__ h4, float* __restrict__ part,
                             int r0, int nvalid, int bfirst) {
  int seg = blockIdx.x; int s = blockIdx.y; int t = threadIdx.x;
  int b = bfirst + seg;
  int lo = b * 625 - r0; if (lo < 0) lo = 0;
  int hi = (b + 1) * 625 - r0; if (hi > nvalid) hi = nvalid;
  int len = hi - lo;
  int k0 = lo + (len * s) / 5;
  int k1 = lo + (len * (s + 1)) / 5;
  const u16* base = h4 + t * 8;
  float a0 = 0.f, a1 = 0.f, a2 = 0.f, a3 = 0.f, a4 = 0.f, a5 = 0.f, a6 = 0.f, a7 = 0.f;
  for (int k = k0; k < k1; k++) {
    uint4 u = *(const uint4*)(base + (size_t)k * 2048);
    a0 += bf2f((u16)(u.x & 0xffff)); a1 += bf2f((u16)(u.x >> 16));
    a2 += bf2f((u16)(u.y & 0xffff)); a3 += bf2f((u16)(u.y >> 16));
    a4 += bf2f((u16)(u.z & 0xffff)); a5 += bf2f((u16)(u.z >> 16));
    a6 += bf2f((u16)(u.w & 0xffff)); a7 += bf2f((u16)(u.w >> 16));
  }
  float* dst = part + ((size_t)(seg * 5 + s) * 2048) + t * 8;
  dst[0] = a0; dst[1] = a1; dst[2] = a2; dst[3] = a3;
  dst[4] = a4; dst[5] = a5; dst[6] = a6; dst[7] = a7;
}

__global__ void reduce_fin2(const float* __restrict__ part, float* __restrict__ xg,
                            int bfirst, int nseg) {
  int idx = blockIdx.x * blockDim.x + threadIdx.x;
  if (idx >= nseg * 2048) return;
  int seg = idx >> 11; int o = idx & 2047;
  float sv = 0.f;
#pragma unroll
  for (int s = 0; s < 5; s++) sv += part[(size_t)(seg * 5 + s) * 2048 + o];
  xg[(size_t)(bfirst + seg) * 2048 + o] += sv;
}

// ---------------- f-MLP layer 4: warp per (b,o), bf16 input ----------------
__global__ void f_layer4(const u16* __restrict__ x, const float* __restrict__ Wf,
                         const float* __restrict__ bf_, float* __restrict__ y) {
  int gwid = (blockIdx.x * blockDim.x + threadIdx.x) >> 6;
  int lane = threadIdx.x & 63;
  if (gwid >= 64 * 10) return;
  int b = gwid / 10, o = gwid % 10;
  const u16* xp = x + (size_t)b * 128;
  const float* wp = Wf + (size_t)o * 100;
  float s = 0.f;
  for (int k = lane; k < 100; k += 64) s += bf2f(xp[k]) * wp[k];
  for (int off = 32; off > 0; off >>= 1) s += __shfl_down(s, off);
  if (lane == 0) y[b * 16 + o] = s + bf_[o];
}

__global__ void lsm_kernel(const float* __restrict__ xf4, float* __restrict__ out) {
  int b = blockIdx.x * blockDim.x + threadIdx.x;
  if (b >= 64) return;
  const float* x = xf4 + b * 16;
  float m = x[0];
  for (int i = 1; i < 10; i++) m = fmaxf(m, x[i]);
  float s = 0.f;
  for (int i = 0; i < 10; i++) s += expf(x[i] - m);
  float ls = logf(s);
  for (int i = 0; i < 10; i++) out[b * 10 + i] = x[i] - m - ls;
}

// ---------------- host ----------------
extern "C" void kernel_launch(void* const* d_in, const int* in_sizes, int n_in,
                              void* d_out, int out_size, void* d_ws, size_t ws_size,
                              hipStream_t stream) {
  const float* img = (const float*)d_in[0];
  const float* qst = (const float*)d_in[1];
  const float* w1 = (const float*)d_in[2];  const float* b1 = (const float*)d_in[3];
  const float* w2 = (const float*)d_in[4];  const float* b2 = (const float*)d_in[5];
  const float* w3 = (const float*)d_in[6];  const float* b3 = (const float*)d_in[7];
  const float* w4 = (const float*)d_in[8];  const float* b4 = (const float*)d_in[9];
  const float* g1 = (const float*)d_in[10]; const float* be1 = (const float*)d_in[11];
  const float* g2 = (const float*)d_in[12]; const float* be2 = (const float*)d_in[13];
  const float* g3 = (const float*)d_in[14]; const float* be3 = (const float*)d_in[15];
  const float* g4 = (const float*)d_in[16]; const float* be4 = (const float*)d_in[17];
  const float* gw1 = (const float*)d_in[18]; const float* gb1 = (const float*)d_in[19];
  const float* gw2 = (const float*)d_in[20]; const float* gb2 = (const float*)d_in[21];
  const float* gw3 = (const float*)d_in[22]; const float* gb3 = (const float*)d_in[23];
  const float* gw4 = (const float*)d_in[24]; const float* gb4 = (const float*)d_in[25];
  const float* fw1 = (const float*)d_in[26]; const float* fb1 = (const float*)d_in[27];
  const float* fw2 = (const float*)d_in[28]; const float* fb2 = (const float*)d_in[29];
  const float* fw3 = (const float*)d_in[30]; const float* fb3 = (const float*)d_in[31];
  const float* fw4 = (const float*)d_in[32]; const float* fb4 = (const float*)d_in[33];
  float* out = (float*)d_out;

  char* P = (char*)d_ws;
  auto alloc = [&](size_t bytes) -> char* {
    char* r = P; P += (bytes + 255) & ~(size_t)255; return r;
  };
  // persistent
  u16* Wp2 = (u16*)alloc(2048ull * 2048 * 2);
  u16* Wp3 = (u16*)alloc(2048ull * 2048 * 2);
  u16* Wp4 = (u16*)alloc(2048ull * 2048 * 2);
  u16* Afu = (u16*)alloc(1664ull * 2048 * 2);
  u16* Bfu = (u16*)alloc(1664ull * 2048 * 2);
  float* Q = (float*)alloc(64ull * 2048 * 4);
  float* bp = (float*)alloc(3ull * 2048 * 4);
  float* xg = (float*)alloc(64ull * 2048 * 4);
  u16* obj = (u16*)alloc(1664ull * 256 * 2);
  u16* W1a = (u16*)alloc(2048ull * 256 * 2);
  u16* W1b = (u16*)alloc(2048ull * 256 * 2);
  // f-MLP packs / buffers
  u16* Fp1 = (u16*)alloc(1024ull * 2048 * 2);
  u16* Fp2 = (u16*)alloc(512ull * 1024 * 2);
  u16* Fp3 = (u16*)alloc(128ull * 512 * 2);
  float* fbc1 = (float*)alloc(1024 * 4);
  float* fbc2 = (float*)alloc(512 * 4);
  float* fbc3 = (float*)alloc(128 * 4);
  u16* xgb  = (u16*)alloc(128ull * 2048 * 2);
  u16* xf1b = (u16*)alloc(128ull * 1024 * 2);
  u16* xf2b = (u16*)alloc(128ull * 512 * 2);
  u16* xf3b = (u16*)alloc(128ull * 128 * 2);
  float* xf4 = (float*)alloc(64ull * 16 * 4);
  // h-phase (8192-row chunks)
  u16* h0  = (u16*)alloc(8192ull * 2048 * 2);
  u16* h1b = (u16*)alloc(8192ull * 2048 * 2);
  float* rpart = (float*)alloc(14ull * 5 * 2048 * 4);
  // conv-phase
  float* C1 = (float*)alloc(92416ull * 32 * 4);
  u16*   X2 = (u16*)alloc(23168ull * 288 * 2);
  float* C2 = (float*)alloc(23168ull * 128 * 4);
  u16*   X3 = (u16*)alloc(6400ull * 576 * 2);
  float* C3 = (float*)alloc(6400ull * 128 * 4);
  u16*   X4 = (u16*)alloc(1664ull * 1152 * 2);
  float* C4 = (float*)alloc(1664ull * 256 * 4);
  u16*  Wc2 = (u16*)alloc(128ull * 288 * 2);
  u16*  Wc3 = (u16*)alloc(128ull * 576 * 2);
  u16*  Wc4 = (u16*)alloc(256ull * 1152 * 2);
  float* bc2 = (float*)alloc(128 * 4);
  float* bc3 = (float*)alloc(128 * 4);
  float* bc4 = (float*)alloc(256 * 4);
  float* bnp = (float*)alloc(BN_S * 512 * 4);
  float* ss  = (float*)alloc(512 * 4);

  // ---- conv weight/bias packs ----
  pack_convw<<<(128 * 288 + 255) / 256, 256, 0, stream>>>(w2, Wc2, 64, 32, 128);
  pack_convw<<<(128 * 576 + 255) / 256, 256, 0, stream>>>(w3, Wc3, 128, 64, 128);
  pack_convw<<<(256 * 1152 + 255) / 256, 256, 0, stream>>>(w4, Wc4, 256, 128, 256);
  pad_bias<<<1, 256, 0, stream>>>(b2, bc2, 64, 128);
  pad_bias<<<1, 256, 0, stream>>>(b3, bc3, 128, 128);
  pad_bias<<<1, 256, 0, stream>>>(b4, bc4, 256, 256);

  // ---- conv stack ----
  conv1_lds<<<64 * 38, 256, 0, stream>>>(img, w1, b1, C1);
  bn_partial<<<dim3(32, BN_S), 256, 0, stream>>>(C1, 32, 92416, bnp);
  bn_final<<<1, 256, 0, stream>>>(bnp, g1, be1, ss, 32, 92416);
  bnrelu_im2col<<<(23168 * 9 * 8 + 255) / 256, 256, 0, stream>>>(C1, 32, 38, 38, ss, X2, 19, 19, 32, 23168);
  gemm_bt<2><<<181, 256, 0, stream>>>(X2, 288, Wc2, 288, C2, nullptr, 128, bc2, 9, 1);

  bn_partial<<<dim3(64, BN_S), 256, 0, stream>>>(C2, 128, 23104, bnp);
  bn_final<<<1, 256, 0, stream>>>(bnp, g2, be2, ss, 64, 23104);
  bnrelu_im2col<<<(6400 * 9 * 16 + 255) / 256, 256, 0, stream>>>(C2, 128, 19, 19, ss, X3, 10, 10, 64, 6400);
  gemm_bt<2><<<50, 256, 0, stream>>>(X3, 576, Wc3, 576, C3, nullptr, 128, bc3, 18, 1);

  bn_partial<<<dim3(128, BN_S), 256, 0, stream>>>(C3, 128, 6400, bnp);
  bn_final<<<1, 256, 0, stream>>>(bnp, g3, be3, ss, 128, 6400);
  bnrelu_im2col<<<(1664 * 9 * 32 + 255) / 256, 256, 0, stream>>>(C3, 128, 10, 10, ss, X4, 5, 5, 128, 1664);
  gemm_bt<2><<<26, 256, 0, stream>>>(X4, 1152, Wc4, 1152, C4, nullptr, 256, bc4, 36, 2);

  bn_partial<<<dim3(256, BN_S), 256, 0, stream>>>(C4, 256, 1600, bnp);
  bn_final<<<1, 256, 0, stream>>>(bnp, g4, be4, ss, 256, 1600);
  obj_from_c4<<<(1664 * 256 + 255) / 256, 256, 0, stream>>>(C4, ss, obj);

  // ---- MLP packs ----
  pack_w1<<<2048, 256, 0, stream>>>(gw1, W1a, W1b);
  pack_wpad<<<(2048 * 2048 + 255) / 256, 256, 0, stream>>>(gw2, Wp2, 2000, 2000, 2048, 2048);
  pack_wpad<<<(2048 * 2048 + 255) / 256, 256, 0, stream>>>(gw3, Wp3, 2000, 2000, 2048, 2048);
  pack_wpad<<<(2048 * 2048 + 255) / 256, 256, 0, stream>>>(gw4, Wp4, 2000, 2000, 2048, 2048);
  pack_bias3<<<8, 256, 0, stream>>>(gb2, gb3, gb4, bp);
  q_build<<<512, 256, 0, stream>>>(qst, gw1, gb1, Q);
  // f-MLP packs
  pack_wpad<<<(1024 * 2048 + 255) / 256, 256, 0, stream>>>(fw1, Fp1, 1000, 2000, 1024, 2048);
  pack_wpad<<<(512 * 1024 + 255) / 256, 256, 0, stream>>>(fw2, Fp2, 500, 1000, 512, 1024);
  pack_wpad<<<(128 * 512 + 255) / 256, 256, 0, stream>>>(fw3, Fp3, 100, 500, 128, 512);
  pad_bias<<<4, 256, 0, stream>>>(fb1, fbc1, 1000, 1024);
  pad_bias<<<2, 256, 0, stream>>>(fb2, fbc2, 500, 512);
  pad_bias<<<1, 256, 0, stream>>>(fb3, fbc3, 100, 128);

  // ---- layer-1 decomposition GEMMs (bf16 raw out) ----
  gemm_bt<3><<<13 * 16, 256, 0, stream>>>(obj, 256, W1a, 256, nullptr, Afu, 2048, nullptr, 8, 16);
  gemm_bt<3><<<13 * 16, 256, 0, stream>>>(obj, 256, W1b, 256, nullptr, Bfu, 2048, nullptr, 8, 16);

  // ---- g-MLP in 8192-row chunks (grid exactly 256 blocks per GEMM) ----
  zero_xg<<<512, 256, 0, stream>>>(xg);
  const int TOTROWS = 64 * 625;  // 40000
  for (int c = 0; c < 5; c++) {
    int r0 = c * 8192;
    int nvalid = TOTROWS - r0; if (nvalid > 8192) nvalid = 8192;
    h1_build<<<8192, 256, 0, stream>>>(Afu, Bfu, Q, h0, r0, nvalid);
    gemm256<32><<<256, 512, 0, stream>>>(h0, Wp2, h1b, bp);
    gemm256<32><<<256, 512, 0, stream>>>(h1b, Wp3, h0, bp + 2048);
    gemm256<32><<<256, 512, 0, stream>>>(h0, Wp4, h1b, bp + 4096);
    int bfirst = r0 / 625;
    int blast = (r0 + nvalid - 1) / 625;
    int nseg = blast - bfirst + 1;
    reduce_part2<<<dim3(nseg, 5), 256, 0, stream>>>(h1b, rpart, r0, nvalid, bfirst);
    reduce_fin2<<<(nseg * 2048 + 255) / 256, 256, 0, stream>>>(rpart, xg, bfirst, nseg);
  }

  // ---- f MLP: layers 1-3 as MFMA GEMMs, layer 4 tiny ----
  pack_xgb<<<(128 * 2048 + 255) / 256, 256, 0, stream>>>(xg, xgb);
  gemm_bt<5><<<8, 256, 0, stream>>>(xgb, 2048, Fp1, 2048, nullptr, xf1b, 1024, fbc1, 64, 8);
  gemm_bt<5><<<4, 256, 0, stream>>>(xf1b, 1024, Fp2, 1024, nullptr, xf2b, 512, fbc2, 32, 4);
  gemm_bt<5><<<1, 256, 0, stream>>>(xf2b, 512, Fp3, 512, nullptr, xf3b, 128, fbc3, 16, 1);
  f_layer4<<<(64 * 10 * 64 + 255) / 256, 256, 0, stream>>>(xf3b, fw4, fb4, xf4);
  lsm_kernel<<<1, 64, 0, stream>>>(xf4, out);
}

// Round 11
// 1200.354 us; speedup vs baseline: 1.4661x; 1.1831x over previous
//
#include <hip/hip_runtime.h>

typedef unsigned short u16;
typedef unsigned int u32;
typedef __attribute__((ext_vector_type(8))) short bf16x8;
typedef __attribute__((ext_vector_type(4))) float f32x4;

#define BN_EPS 1e-5f
#define BN_S 16

__device__ __forceinline__ float bf2f(u16 u) {
  union { unsigned u; float f; } x; x.u = ((unsigned)u) << 16; return x.f;
}
__device__ __forceinline__ u16 f2bf(float f) {
  union { float f; unsigned u; } x; x.f = f;
  unsigned r = x.u + 0x7FFFu + ((x.u >> 16) & 1u);
  return (u16)(r >> 16);
}

// ---------------- conv1: LDS-staged, one block per (n, ho) ----------------
__global__ __launch_bounds__(256) void conv1_lds(const float* __restrict__ img,
                                                 const float* __restrict__ w,
                                                 const float* __restrict__ b,
                                                 float* __restrict__ C1) {
  int blk = blockIdx.x;             // n*38 + ho
  int n = blk / 38, ho = blk % 38;
  __shared__ float in_s[9 * 80];
  __shared__ float w_s[32 * 27];
  __shared__ float b_s[32];
  int t = threadIdx.x;
  for (int i = t; i < 720; i += 256) in_s[i] = 0.f;
  __syncthreads();
  for (int i = t; i < 675; i += 256) {
    int wi = i % 75; int q = i / 75; int kh = q % 3; int ci = q / 3;
    int hi = ho * 2 - 1 + kh;
    if (hi >= 0 && hi < 75)
      in_s[(ci * 3 + kh) * 80 + wi + 1] = img[((size_t)(n * 3 + ci) * 75 + hi) * 75 + wi];
  }
  for (int i = t; i < 864; i += 256) w_s[i] = w[i];
  if (t < 32) b_s[t] = b[t];
  __syncthreads();
  for (int idx = t; idx < 1216; idx += 256) {
    int wo = idx >> 5, co = idx & 31;
    float acc = b_s[co];
    const float* wp = w_s + co * 27;
#pragma unroll
    for (int ci = 0; ci < 3; ci++) {
#pragma unroll
      for (int kh = 0; kh < 3; kh++) {
        const float* ip = in_s + (ci * 3 + kh) * 80 + 2 * wo;
        const float* wq = wp + ci * 9 + kh * 3;
        acc += ip[0] * wq[0] + ip[1] * wq[1] + ip[2] * wq[2];
      }
    }
    C1[((size_t)blk * 38 + wo) * 32 + co] = acc;
  }
}

// ---------------- BN column-stats (deterministic 2-stage) ----------------
__global__ void bn_partial(const float* __restrict__ C, int ldc, int M,
                           float* __restrict__ part) {
  int c = blockIdx.x; int s = blockIdx.y; int t = threadIdx.x;
  int rowsPer = (M + BN_S - 1) / BN_S;
  int r0 = s * rowsPer; int r1 = r0 + rowsPer; if (r1 > M) r1 = M;
  float s1 = 0.f, s2 = 0.f;
  for (int r = r0 + t; r < r1; r += 256) {
    float v = C[(size_t)r * ldc + c]; s1 += v; s2 += v * v;
  }
  __shared__ float l1[256], l2[256];
  l1[t] = s1; l2[t] = s2; __syncthreads();
  for (int off = 128; off > 0; off >>= 1) {
    if (t < off) { l1[t] += l1[t + off]; l2[t] += l2[t + off]; }
    __syncthreads();
  }
  if (t == 0) { part[s * 512 + c] = l1[0]; part[s * 512 + 256 + c] = l2[0]; }
}

__global__ void bn_final(const float* __restrict__ part, const float* __restrict__ gamma,
                         const float* __restrict__ beta, float* __restrict__ ss,
                         int C, int M) {
  int c = threadIdx.x;
  if (c >= C) { if (c < 256) { ss[c] = 0.f; ss[256 + c] = 0.f; } return; }
  float s1 = 0.f, s2 = 0.f;
#pragma unroll
  for (int s = 0; s < BN_S; s++) { s1 += part[s * 512 + c]; s2 += part[s * 512 + 256 + c]; }
  float mu = s1 / M;
  float var = s2 / M - mu * mu;
  float sc = gamma[c] * rsqrtf(var + BN_EPS);
  ss[c] = sc; ss[256 + c] = beta[c] - mu * sc;
}

// ---------------- fused BN+ReLU + im2col -> bf16 X[row][tap*Ci+ci] ----------------
__global__ void bnrelu_im2col(const float* __restrict__ Cprev, int ldprev, int Hp, int Wp,
                              const float* __restrict__ ss, u16* __restrict__ X,
                              int Ho, int Wo, int Ci, int Mp) {
  int civ4 = Ci >> 2;
  int idx = blockIdx.x * blockDim.x + threadIdx.x;
  int total = Mp * 9 * civ4;
  if (idx >= total) return;
  int cv = idx % civ4; int t2 = idx / civ4;
  int tap = t2 % 9; int row = t2 / 9;
  int K = 9 * Ci;
  u16* dst = X + (size_t)row * K + tap * Ci + cv * 4;
  int HW = Ho * Wo;
  int Mvalid = 64 * HW;
  ushort4 o4; o4.x = 0; o4.y = 0; o4.z = 0; o4.w = 0;
  if (row < Mvalid) {
    int wo = row % Wo; int t = row / Wo;
    int ho = t % Ho; int n = t / Ho;
    int kh = tap / 3, kw = tap % 3;
    int hi = ho * 2 - 1 + kh, wi = wo * 2 - 1 + kw;
    if (hi >= 0 && hi < Hp && wi >= 0 && wi < Wp) {
      const float* src = Cprev + ((size_t)((n * Hp + hi) * Wp + wi)) * ldprev + cv * 4;
      float4 v = *(const float4*)src;
      int c0 = cv * 4;
      float a;
      a = v.x * ss[c0 + 0] + ss[256 + c0 + 0]; o4.x = f2bf(a > 0.f ? a : 0.f);
      a = v.y * ss[c0 + 1] + ss[256 + c0 + 1]; o4.y = f2bf(a > 0.f ? a : 0.f);
      a = v.z * ss[c0 + 2] + ss[256 + c0 + 2]; o4.z = f2bf(a > 0.f ? a : 0.f);
      a = v.w * ss[c0 + 3] + ss[256 + c0 + 3]; o4.w = f2bf(a > 0.f ? a : 0.f);
    }
  }
  *(ushort4*)dst = o4;
}

// ---------------- conv weight pack ----------------
__global__ void pack_convw(const float* __restrict__ w, u16* __restrict__ Wp,
                           int Co, int Ci, int Cop) {
  int K = 9 * Ci;
  int idx = blockIdx.x * blockDim.x + threadIdx.x;
  if (idx >= Cop * K) return;
  int k = idx % K; int co = idx / K;
  int tap = k / Ci; int ci = k % Ci;
  float v = (co < Co) ? w[((size_t)co * Ci + ci) * 9 + tap] : 0.f;
  Wp[idx] = f2bf(v);
}

__global__ void pad_bias(const float* __restrict__ b, float* __restrict__ bc, int Co, int Cop) {
  int i = blockIdx.x * blockDim.x + threadIdx.x;
  if (i < Cop) bc[i] = (i < Co) ? b[i] : 0.f;
}

// ---------------- obj pack from C4 with BN+ReLU ----------------
__global__ void obj_from_c4(const float* __restrict__ C4, const float* __restrict__ ss,
                            u16* __restrict__ obj) {
  int idx = blockIdx.x * blockDim.x + threadIdx.x;
  if (idx >= 1664 * 256) return;
  int c = idx & 255; int row = idx >> 8;
  float v = 0.f;
  if (row < 1600) {
    float x = C4[(size_t)row * 256 + c];
    x = x * ss[c] + ss[256 + c];
    v = x > 0.f ? x : 0.f;
  }
  obj[idx] = f2bf(v);
}

// ---------------- MLP weight packs ----------------
__global__ void pack_w1(const float* __restrict__ gw1, u16* __restrict__ W1a, u16* __restrict__ W1b) {
  int idx = blockIdx.x * blockDim.x + threadIdx.x;
  if (idx >= 2048 * 256) return;
  int k = idx & 255, n = idx >> 8;
  float a = 0.f, b = 0.f;
  if (n < 2000) { a = gw1[(size_t)n * 523 + k]; b = gw1[(size_t)n * 523 + 256 + k]; }
  W1a[idx] = f2bf(a); W1b[idx] = f2bf(b);
}

__global__ void pack_wpad(const float* __restrict__ w, u16* __restrict__ Wp,
                          int N, int K, int Np, int Kp) {
  int idx = blockIdx.x * blockDim.x + threadIdx.x;
  if (idx >= Np * Kp) return;
  int k = idx % Kp, n = idx / Kp;
  float v = (n < N && k < K) ? w[(size_t)n * K + k] : 0.f;
  Wp[idx] = f2bf(v);
}

__global__ void pack_bias3(const float* __restrict__ b2, const float* __restrict__ b3,
                           const float* __restrict__ b4, float* __restrict__ bp) {
  int i = blockIdx.x * blockDim.x + threadIdx.x;
  if (i >= 2048) return;
  bp[i]        = (i < 2000) ? b2[i] : 0.f;
  bp[2048 + i] = (i < 2000) ? b3[i] : 0.f;
  bp[4096 + i] = (i < 2000) ? b4[i] : 0.f;
}

// ---------------- Q[b][o] = gb1[o] + qst[b] . gw1[o][512:523] ----------------
__global__ void q_build(const float* __restrict__ qst, const float* __restrict__ gw1,
                        const float* __restrict__ gb1, float* __restrict__ Q) {
  int idx = blockIdx.x * blockDim.x + threadIdx.x;
  if (idx >= 64 * 2048) return;
  int o = idx & 2047, b = idx >> 11;
  float v = 0.f;
  if (o < 2000) {
    v = gb1[o];
    const float* w = gw1 + (size_t)o * 523 + 512;
    const float* q = qst + b * 11;
#pragma unroll
    for (int k = 0; k < 11; k++) v += q[k] * w[k];
  }
  Q[idx] = v;
}

// ---------------- xg -> bf16 [128][2048] with 1/625 scale ----------------
__global__ void pack_xgb(const float* __restrict__ xg, u16* __restrict__ xgb) {
  int idx = blockIdx.x * blockDim.x + threadIdx.x;
  if (idx >= 128 * 2048) return;
  int row = idx >> 11;
  float v = (row < 64) ? xg[idx] * (1.f / 625.f) : 0.f;
  xgb[idx] = f2bf(v);
}

// ---------------- global->LDS async ----------------
typedef const __attribute__((address_space(1))) u32* gas1;
typedef __attribute__((address_space(3))) u32* las3;
__device__ __forceinline__ void gld16(const void* g, void* l) {
  __builtin_amdgcn_global_load_lds((gas1)g, (las3)l, 16, 0, 0);
}

// ---------------- 128^2 bf16 MFMA GEMM (small/medium shapes) ----------------
// EPI 0: fp32 raw; EPI 2: fp32 acc+bias; EPI 3: bf16 raw; EPI 5: bf16 relu(acc+bias)
template <int EPI>
__global__ __launch_bounds__(256) void gemm_bt(
    const u16* __restrict__ A, int lda,
    const u16* __restrict__ W, int ldb,
    float* __restrict__ Cf, u16* __restrict__ Cb, int ldc,
    const float* __restrict__ bias, int KT, int NTN) {
  __shared__ __align__(16) char lds[32768];
  int bid = blockIdx.x;
  int wg;
  if ((gridDim.x & 7) == 0) {
    int cpx = gridDim.x >> 3;
    wg = (bid & 7) * cpx + (bid >> 3);
  } else {
    wg = bid;
  }
  int mt = wg / NTN, nt = wg % NTN;
  int tid = threadIdx.x;
  int wave = tid >> 6, lane = tid & 63;
  int r = lane & 15, g = lane >> 4;
  int wr = wave >> 1, wc = wave & 1;

  const u16* Asrc = A + (size_t)(mt * 128 + wave * 32 + r) * lda + g * 8;
  const u16* Wsrc = W + (size_t)(nt * 128 + wave * 32 + r) * ldb + g * 8;

  f32x4 acc[4][4];
#pragma unroll
  for (int i = 0; i < 4; i++)
#pragma unroll
    for (int j = 0; j < 4; j++) acc[i][j] = (f32x4){0.f, 0.f, 0.f, 0.f};

  {
    char* Al = lds; char* Wl = lds + 8192;
    gld16(Asrc, Al + wave * 2048);
    gld16(Asrc + (size_t)16 * lda, Al + wave * 2048 + 1024);
    gld16(Wsrc, Wl + wave * 2048);
    gld16(Wsrc + (size_t)16 * ldb, Wl + wave * 2048 + 1024);
  }
  __syncthreads();

  int buf = 0;
  for (int kt = 0; kt < KT; kt++) {
    if (kt + 1 < KT) {
      int k0 = (kt + 1) * 32;
      char* Al = lds + (buf ^ 1) * 16384; char* Wl = Al + 8192;
      gld16(Asrc + k0, Al + wave * 2048);
      gld16(Asrc + k0 + (size_t)16 * lda, Al + wave * 2048 + 1024);
      gld16(Wsrc + k0, Wl + wave * 2048);
      gld16(Wsrc + k0 + (size_t)16 * ldb, Wl + wave * 2048 + 1024);
    }
    char* Al = lds + buf * 16384; char* Wl = Al + 8192;
    bf16x8 a[4], w[4];
#pragma unroll
    for (int i = 0; i < 4; i++) a[i] = *(const bf16x8*)(Al + (wr * 4 + i) * 1024 + lane * 16);
#pragma unroll
    for (int j = 0; j < 4; j++) w[j] = *(const bf16x8*)(Wl + (wc * 4 + j) * 1024 + lane * 16);
#pragma unroll
    for (int i = 0; i < 4; i++)
#pragma unroll
      for (int j = 0; j < 4; j++)
        acc[i][j] = __builtin_amdgcn_mfma_f32_16x16x32_bf16(a[i], w[j], acc[i][j], 0, 0, 0);
    __syncthreads();
    buf ^= 1;
  }

  int rowb = mt * 128 + wr * 64 + (lane >> 4) * 4;
  int colb = nt * 128 + wc * 64 + (lane & 15);
#pragma unroll
  for (int i = 0; i < 4; i++) {
#pragma unroll
    for (int j = 0; j < 4; j++) {
      int col = colb + j * 16;
      float bv = (EPI == 2 || EPI == 5) ? bias[col] : 0.f;
#pragma unroll
      for (int q = 0; q < 4; q++) {
        int row = rowb + i * 16 + q;
        float v = acc[i][j][q];
        if (EPI == 2) {
          Cf[(size_t)row * ldc + col] = v + bv;
        } else if (EPI == 3) {
          Cb[(size_t)row * ldc + col] = f2bf(v);
        } else if (EPI == 5) {
          float z = v + bv; z = z > 0.f ? z : 0.f;
          Cb[(size_t)row * ldc + col] = f2bf(z);
        } else {
          Cf[(size_t)row * ldc + col] = v;
        }
      }
    }
  }
}

// ---------------- 256^2 bf16 GEMM — 8-phase, coalesced staging + XOR swizzle ----------------
// SUM=0: C = relu(A@W^T+bias) -> bf16. SUM=1: no C write; per-block masked column-sum
// of relu(acc+bias), split at the (<=1) image boundary, -> rp4[mt][2][2048].
#define MF16(d, av, bv) d = __builtin_amdgcn_mfma_f32_16x16x32_bf16(av, bv, d, 0, 0, 0)

template <int NT, int SUM>
__global__ __launch_bounds__(512, 2) void gemm256(
    const u16* __restrict__ A, const u16* __restrict__ W,
    u16* __restrict__ Cb, const float* __restrict__ bias,
    float* __restrict__ rp4, int r0c, int nvalid) {
  __shared__ __align__(16) char lds[131072];
  int bid = blockIdx.x;
  int cpx = gridDim.x >> 3;
  int wg = (bid & 7) * cpx + (bid >> 3);
  int mt = wg >> 3, nt = wg & 7;
  int tid = threadIdx.x;
  int wave = tid >> 6, lane = tid & 63;
  int wr = wave >> 2, wc = wave & 3;
  int wcl = wc & 1, wch = wc >> 1;
  int l15 = lane & 15, l7 = lane & 7, lh = lane >> 4;

  int srcChunkOff = (((lane & 7) ^ (lane >> 3)) << 3);
  int srcRowInWave = (lane >> 3);
  auto stageA = [&](int tt, int slot, int h) {
#pragma unroll
    for (int s = 0; s < 2; s++) {
      const u16* src = A + (size_t)(mt * 256 + h * 128 + s * 64 + wave * 8 + srcRowInWave) * 2048
                         + tt * 64 + srcChunkOff;
      gld16(src, lds + slot * 65536 + h * 16384 + s * 8192 + wave * 1024);
    }
  };
  auto stageB = [&](int tt, int slot, int h) {
#pragma unroll
    for (int s = 0; s < 2; s++) {
      const u16* src = W + (size_t)(nt * 256 + h * 128 + s * 64 + wave * 8 + srcRowInWave) * 2048
                         + tt * 64 + srcChunkOff;
      gld16(src, lds + slot * 65536 + 32768 + h * 16384 + s * 8192 + wave * 1024);
    }
  };

  f32x4 acc[8][4];
#pragma unroll
  for (int i = 0; i < 8; i++)
#pragma unroll
    for (int j = 0; j < 4; j++) acc[i][j] = (f32x4){0.f, 0.f, 0.f, 0.f};

  stageA(0, 0, 0); stageA(0, 0, 1); stageB(0, 0, 0); stageB(0, 0, 1);
  stageB(1, 1, 0); stageB(1, 1, 1);
  asm volatile("s_waitcnt vmcnt(4)" ::: "memory");
  __builtin_amdgcn_s_barrier();

  bf16x8 b00, b01, b10, b11, b20, b21, b30, b31;

#define AROFF(Q, i, ks) \
  ((((2 * (Q) + (i)) * 16 + l15) * 128) + (((((ks) * 4) + lh) ^ l7) << 4))
#define BROFF(j, ks) \
  ((((wcl * 4 + (j)) * 16 + l15) * 128) + (((((ks) * 4) + lh) ^ l7) << 4))

#define PHASE(Q, T, BUF)                                                         \
  {                                                                              \
    const char* Ab = lds + (BUF) * 65536 + wr * 16384;                           \
    const char* Bb = lds + (BUF) * 65536 + 32768 + wch * 16384;                  \
    if (Q == 0) {                                                                \
      b00 = *(const bf16x8*)(Bb + BROFF(0, 0));                                  \
      b01 = *(const bf16x8*)(Bb + BROFF(0, 1));                                  \
      b10 = *(const bf16x8*)(Bb + BROFF(1, 0));                                  \
      b11 = *(const bf16x8*)(Bb + BROFF(1, 1));                                  \
      b20 = *(const bf16x8*)(Bb + BROFF(2, 0));                                  \
      b21 = *(const bf16x8*)(Bb + BROFF(2, 1));                                  \
      b30 = *(const bf16x8*)(Bb + BROFF(3, 0));                                  \
      b31 = *(const bf16x8*)(Bb + BROFF(3, 1));                                  \
    }                                                                            \
    bf16x8 a00 = *(const bf16x8*)(Ab + AROFF(Q, 0, 0));                          \
    bf16x8 a01 = *(const bf16x8*)(Ab + AROFF(Q, 0, 1));                          \
    bf16x8 a10 = *(const bf16x8*)(Ab + AROFF(Q, 1, 0));                          \
    bf16x8 a11 = *(const bf16x8*)(Ab + AROFF(Q, 1, 1));                          \
    if (Q == 0) { if ((T) + 1 < NT) stageA((T) + 1, (BUF) ^ 1, 0); }             \
    if (Q == 1) { if ((T) + 1 < NT) stageA((T) + 1, (BUF) ^ 1, 1);               \
                  if ((T) + 2 < NT) stageB((T) + 2, (BUF), 0); }                 \
    if (Q == 2) { if ((T) + 2 < NT) stageB((T) + 2, (BUF), 1); }                 \
    __builtin_amdgcn_s_barrier();                                                \
    __builtin_amdgcn_s_setprio(1);                                               \
    MF16(acc[2 * Q + 0][0], a00, b00); MF16(acc[2 * Q + 0][0], a01, b01);        \
    MF16(acc[2 * Q + 0][1], a00, b10); MF16(acc[2 * Q + 0][1], a01, b11);        \
    MF16(acc[2 * Q + 0][2], a00, b20); MF16(acc[2 * Q + 0][2], a01, b21);        \
    MF16(acc[2 * Q + 0][3], a00, b30); MF16(acc[2 * Q + 0][3], a01, b31);        \
    MF16(acc[2 * Q + 1][0], a10, b00); MF16(acc[2 * Q + 1][0], a11, b01);        \
    MF16(acc[2 * Q + 1][1], a10, b10); MF16(acc[2 * Q + 1][1], a11, b11);        \
    MF16(acc[2 * Q + 1][2], a10, b20); MF16(acc[2 * Q + 1][2], a11, b21);        \
    MF16(acc[2 * Q + 1][3], a10, b30); MF16(acc[2 * Q + 1][3], a11, b31);        \
    __builtin_amdgcn_s_setprio(0);                                               \
    if (Q == 3) { asm volatile("s_waitcnt vmcnt(4)" ::: "memory"); }             \
    __builtin_amdgcn_s_barrier();                                                \
  }

#pragma unroll 1
  for (int t2 = 0; t2 < NT; t2 += 2) {
    PHASE(0, t2, 0) PHASE(1, t2, 0) PHASE(2, t2, 0) PHASE(3, t2, 0)
    PHASE(0, t2 + 1, 1) PHASE(1, t2 + 1, 1) PHASE(2, t2 + 1, 1) PHASE(3, t2 + 1, 1)
  }
#undef PHASE
#undef AROFF
#undef BROFF

  int colb = nt * 256 + wc * 64 + l15;
  if (SUM == 0) {
    int rowb = mt * 256 + wr * 128 + lh * 4;
#pragma unroll
    for (int i = 0; i < 8; i++) {
#pragma unroll
      for (int j = 0; j < 4; j++) {
        int col = colb + j * 16;
        float bv = bias[col];
#pragma unroll
        for (int q = 0; q < 4; q++) {
          int row = rowb + i * 16 + q;
          float v = acc[i][j][q] + bv;
          v = v > 0.f ? v : 0.f;
          Cb[(size_t)row * 2048 + col] = f2bf(v);
        }
      }
    }
  } else {
    // masked relu(acc+bias) column-sum, split at image boundary (<= 1 per block)
    int blockRow0 = mt * 256;
    int bimg = (r0c + blockRow0) / 625;
    int boundary = (bimg + 1) * 625 - (r0c + blockRow0);   // in [1,625]
    float p0[4] = {0.f, 0.f, 0.f, 0.f};
    float p1[4] = {0.f, 0.f, 0.f, 0.f};
#pragma unroll
    for (int i = 0; i < 8; i++) {
#pragma unroll
      for (int j = 0; j < 4; j++) {
        float bv = bias[colb + j * 16];
#pragma unroll
        for (int q = 0; q < 4; q++) {
          int row_local = wr * 128 + lh * 4 + i * 16 + q;
          float v = acc[i][j][q] + bv;
          v = v > 0.f ? v : 0.f;
          if (blockRow0 + row_local >= nvalid) v = 0.f;
          bool sg1 = row_local >= boundary;
          p0[j] += sg1 ? 0.f : v;
          p1[j] += sg1 ? v : 0.f;
        }
      }
    }
    // deterministic LDS tree: 8 contributors per (seg, col)
    float* rs = (float*)lds;   // last tile used buf1 region; rs uses first 16KB
    int contrib = wr * 4 + lh;             // 0..7
#pragma unroll
    for (int j = 0; j < 4; j++) {
      int colL = wc * 64 + j * 16 + l15;   // 0..255
      rs[(contrib * 2 + 0) * 256 + colL] = p0[j];
      rs[(contrib * 2 + 1) * 256 + colL] = p1[j];
    }
    __syncthreads();
    int seg = tid >> 8, colx = tid & 255;  // 512 threads -> 2x256
    float s = 0.f;
#pragma unroll
    for (int c8 = 0; c8 < 8; c8++) s += rs[(c8 * 2 + seg) * 256 + colx];
    rp4[((size_t)(mt * 2 + seg)) * 2048 + nt * 256 + colx] = s;
  }
}

// ---------------- h1 = relu(A_i + B_j + Q_b), rows = global pair index ----------------
__global__ void h1_build(const u16* __restrict__ Af, const u16* __restrict__ Bf,
                         const float* __restrict__ Q, u16* __restrict__ h1,
                         int r0, int nvalid) {
  int lrow = blockIdx.x;
  int t = threadIdx.x;
  u16* dst = h1 + (size_t)lrow * 2048;
  if (lrow >= nvalid) {
#pragma unroll
    for (int it = 0; it < 2; it++) {
      int o = it * 1024 + t * 4;
      ushort4 z; z.x = 0; z.y = 0; z.z = 0; z.w = 0;
      *(ushort4*)(dst + o) = z;
    }
    return;
  }
  int grow = r0 + lrow;
  int b = grow / 625; int rem = grow % 625;
  int i = rem / 25, j = rem % 25;
  const u16* Ap = Af + (size_t)(b * 25 + i) * 2048;
  const u16* Bp = Bf + (size_t)(b * 25 + j) * 2048;
  const float* Qp = Q + (size_t)b * 2048;
#pragma unroll
  for (int it = 0; it < 2; it++) {
    int o = it * 1024 + t * 4;
    ushort4 a4 = *(const ushort4*)(Ap + o);
    ushort4 b4 = *(const ushort4*)(Bp + o);
    float4 qv = *(const float4*)(Qp + o);
    ushort4 outv;
    float v;
    v = bf2f(a4.x) + bf2f(b4.x) + qv.x; outv.x = f2bf(v > 0.f ? v : 0.f);
    v = bf2f(a4.y) + bf2f(b4.y) + qv.y; outv.y = f2bf(v > 0.f ? v : 0.f);
    v = bf2f(a4.z) + bf2f(b4.z) + qv.z; outv.z = f2bf(v > 0.f ? v : 0.f);
    v = bf2f(a4.w) + bf2f(b4.w) + qv.w; outv.w = f2bf(v > 0.f ? v : 0.f);
    *(ushort4*)(dst + o) = outv;
  }
}

// ---------------- layer-4 partial finisher: xg[b] += matching rp4 segments ----------------
__global__ void zero_xg(float* __restrict__ xg) {
  int i = blockIdx.x * blockDim.x + threadIdx.x;
  if (i < 64 * 2048) xg[i] = 0.f;
}

__global__ void l4_fin(const float* __restrict__ rp4, float* __restrict__ xg,
                       int r0, int bfirst, int mtiles) {
  int col = blockIdx.x * 256 + threadIdx.x;   // 0..2047
  int b = bfirst + blockIdx.y;
  if (b > 63) return;
  float s = 0.f;
  for (int mt = 0; mt < mtiles; mt++) {
    int img0 = (r0 + mt * 256) / 625;
    if (img0 == b)     s += rp4[((size_t)(mt * 2 + 0)) * 2048 + col];
    if (img0 + 1 == b) s += rp4[((size_t)(mt * 2 + 1)) * 2048 + col];
  }
  xg[(size_t)b * 2048 + col] += s;
}

// ---------------- f-MLP layer 4: warp per (b,o), bf16 input ----------------
__global__ void f_layer4(const u16* __restrict__ x, const float* __restrict__ Wf,
                         const float* __restrict__ bf_, float* __restrict__ y) {
  int gwid = (blockIdx.x * blockDim.x + threadIdx.x) >> 6;
  int lane = threadIdx.x & 63;
  if (gwid >= 64 * 10) return;
  int b = gwid / 10, o = gwid % 10;
  const u16* xp = x + (size_t)b * 128;
  const float* wp = Wf + (size_t)o * 100;
  float s = 0.f;
  for (int k = lane; k < 100; k += 64) s += bf2f(xp[k]) * wp[k];
  for (int off = 32; off > 0; off >>= 1) s += __shfl_down(s, off);
  if (lane == 0) y[b * 16 + o] = s + bf_[o];
}

__global__ void lsm_kernel(const float* __restrict__ xf4, float* __restrict__ out) {
  int b = blockIdx.x * blockDim.x + threadIdx.x;
  if (b >= 64) return;
  const float* x = xf4 + b * 16;
  float m = x[0];
  for (int i = 1; i < 10; i++) m = fmaxf(m, x[i]);
  float s = 0.f;
  for (int i = 0; i < 10; i++) s += expf(x[i] - m);
  float ls = logf(s);
  for (int i = 0; i < 10; i++) out[b * 10 + i] = x[i] - m - ls;
}

// ---------------- host ----------------
extern "C" void kernel_launch(void* const* d_in, const int* in_sizes, int n_in,
                              void* d_out, int out_size, void* d_ws, size_t ws_size,
                              hipStream_t stream) {
  const float* img = (const float*)d_in[0];
  const float* qst = (const float*)d_in[1];
  const float* w1 = (const float*)d_in[2];  const float* b1 = (const float*)d_in[3];
  const float* w2 = (const float*)d_in[4];  const float* b2 = (const float*)d_in[5];
  const float* w3 = (const float*)d_in[6];  const float* b3 = (const float*)d_in[7];
  const float* w4 = (const float*)d_in[8];  const float* b4 = (const float*)d_in[9];
  const float* g1 = (const float*)d_in[10]; const float* be1 = (const float*)d_in[11];
  const float* g2 = (const float*)d_in[12]; const float* be2 = (const float*)d_in[13];
  const float* g3 = (const float*)d_in[14]; const float* be3 = (const float*)d_in[15];
  const float* g4 = (const float*)d_in[16]; const float* be4 = (const float*)d_in[17];
  const float* gw1 = (const float*)d_in[18]; const float* gb1 = (const float*)d_in[19];
  const float* gw2 = (const float*)d_in[20]; const float* gb2 = (const float*)d_in[21];
  const float* gw3 = (const float*)d_in[22]; const float* gb3 = (const float*)d_in[23];
  const float* gw4 = (const float*)d_in[24]; const float* gb4 = (const float*)d_in[25];
  const float* fw1 = (const float*)d_in[26]; const float* fb1 = (const float*)d_in[27];
  const float* fw2 = (const float*)d_in[28]; const float* fb2 = (const float*)d_in[29];
  const float* fw3 = (const float*)d_in[30]; const float* fb3 = (const float*)d_in[31];
  const float* fw4 = (const float*)d_in[32]; const float* fb4 = (const float*)d_in[33];
  float* out = (float*)d_out;

  char* P = (char*)d_ws;
  auto alloc = [&](size_t bytes) -> char* {
    char* r = P; P += (bytes + 255) & ~(size_t)255; return r;
  };
  // persistent
  u16* Wp2 = (u16*)alloc(2048ull * 2048 * 2);
  u16* Wp3 = (u16*)alloc(2048ull * 2048 * 2);
  u16* Wp4 = (u16*)alloc(2048ull * 2048 * 2);
  u16* Afu = (u16*)alloc(1664ull * 2048 * 2);
  u16* Bfu = (u16*)alloc(1664ull * 2048 * 2);
  float* Q = (float*)alloc(64ull * 2048 * 4);
  float* bp = (float*)alloc(3ull * 2048 * 4);
  float* xg = (float*)alloc(64ull * 2048 * 4);
  u16* obj = (u16*)alloc(1664ull * 256 * 2);
  u16* W1a = (u16*)alloc(2048ull * 256 * 2);
  u16* W1b = (u16*)alloc(2048ull * 256 * 2);
  float* rp4 = (float*)alloc(160ull * 2 * 2048 * 4);
  // f-MLP packs / buffers
  u16* Fp1 = (u16*)alloc(1024ull * 2048 * 2);
  u16* Fp2 = (u16*)alloc(512ull * 1024 * 2);
  u16* Fp3 = (u16*)alloc(128ull * 512 * 2);
  float* fbc1 = (float*)alloc(1024 * 4);
  float* fbc2 = (float*)alloc(512 * 4);
  float* fbc3 = (float*)alloc(128 * 4);
  u16* xgb  = (u16*)alloc(128ull * 2048 * 2);
  u16* xf1b = (u16*)alloc(128ull * 1024 * 2);
  u16* xf2b = (u16*)alloc(128ull * 512 * 2);
  u16* xf3b = (u16*)alloc(128ull * 128 * 2);
  float* xf4 = (float*)alloc(64ull * 16 * 4);
  // conv-phase
  float* C1 = (float*)alloc(92416ull * 32 * 4);
  u16*   X2 = (u16*)alloc(23168ull * 288 * 2);
  float* C2 = (float*)alloc(23168ull * 128 * 4);
  u16*   X3 = (u16*)alloc(6400ull * 576 * 2);
  float* C3 = (float*)alloc(6400ull * 128 * 4);
  u16*   X4 = (u16*)alloc(1664ull * 1152 * 2);
  float* C4 = (float*)alloc(1664ull * 256 * 4);
  u16*  Wc2 = (u16*)alloc(128ull * 288 * 2);
  u16*  Wc3 = (u16*)alloc(128ull * 576 * 2);
  u16*  Wc4 = (u16*)alloc(256ull * 1152 * 2);
  float* bc2 = (float*)alloc(128 * 4);
  float* bc3 = (float*)alloc(128 * 4);
  float* bc4 = (float*)alloc(256 * 4);
  float* bnp = (float*)alloc(BN_S * 512 * 4);
  float* ss  = (float*)alloc(512 * 4);

  // h-phase buffers: pick largest chunk size that fits (grid stays %256==0)
  size_t used = (size_t)(P - (char*)d_ws);
  size_t remain = (ws_size > used) ? (ws_size - used) : 0;
  int CHMAX;
  if (remain >= 2ull * 40960 * 2048 * 2 + 4096)      CHMAX = 40960;
  else if (remain >= 2ull * 16384 * 2048 * 2 + 4096) CHMAX = 16384;
  else                                               CHMAX = 8192;
  u16* h0  = (u16*)alloc((size_t)CHMAX * 2048 * 2);
  u16* h1b = (u16*)alloc((size_t)CHMAX * 2048 * 2);

  // ---- conv weight/bias packs ----
  pack_convw<<<(128 * 288 + 255) / 256, 256, 0, stream>>>(w2, Wc2, 64, 32, 128);
  pack_convw<<<(128 * 576 + 255) / 256, 256, 0, stream>>>(w3, Wc3, 128, 64, 128);
  pack_convw<<<(256 * 1152 + 255) / 256, 256, 0, stream>>>(w4, Wc4, 256, 128, 256);
  pad_bias<<<1, 256, 0, stream>>>(b2, bc2, 64, 128);
  pad_bias<<<1, 256, 0, stream>>>(b3, bc3, 128, 128);
  pad_bias<<<1, 256, 0, stream>>>(b4, bc4, 256, 256);

  // ---- conv stack ----
  conv1_lds<<<64 * 38, 256, 0, stream>>>(img, w1, b1, C1);
  bn_partial<<<dim3(32, BN_S), 256, 0, stream>>>(C1, 32, 92416, bnp);
  bn_final<<<1, 256, 0, stream>>>(bnp, g1, be1, ss, 32, 92416);
  bnrelu_im2col<<<(23168 * 9 * 8 + 255) / 256, 256, 0, stream>>>(C1, 32, 38, 38, ss, X2, 19, 19, 32, 23168);
  gemm_bt<2><<<181, 256, 0, stream>>>(X2, 288, Wc2, 288, C2, nullptr, 128, bc2, 9, 1);

  bn_partial<<<dim3(64, BN_S), 256, 0, stream>>>(C2, 128, 23104, bnp);
  bn_final<<<1, 256, 0, stream>>>(bnp, g2, be2, ss, 64, 23104);
  bnrelu_im2col<<<(6400 * 9 * 16 + 255) / 256, 256, 0, stream>>>(C2, 128, 19, 19, ss, X3, 10, 10, 64, 6400);
  gemm_bt<2><<<50, 256, 0, stream>>>(X3, 576, Wc3, 576, C3, nullptr, 128, bc3, 18, 1);

  bn_partial<<<dim3(128, BN_S), 256, 0, stream>>>(C3, 128, 6400, bnp);
  bn_final<<<1, 256, 0, stream>>>(bnp, g3, be3, ss, 128, 6400);
  bnrelu_im2col<<<(1664 * 9 * 32 + 255) / 256, 256, 0, stream>>>(C3, 128, 10, 10, ss, X4, 5, 5, 128, 1664);
  gemm_bt<2><<<26, 256, 0, stream>>>(X4, 1152, Wc4, 1152, C4, nullptr, 256, bc4, 36, 2);

  bn_partial<<<dim3(256, BN_S), 256, 0, stream>>>(C4, 256, 1600, bnp);
  bn_final<<<1, 256, 0, stream>>>(bnp, g4, be4, ss, 256, 1600);
  obj_from_c4<<<(1664 * 256 + 255) / 256, 256, 0, stream>>>(C4, ss, obj);

  // ---- MLP packs ----
  pack_w1<<<2048, 256, 0, stream>>>(gw1, W1a, W1b);
  pack_wpad<<<(2048 * 2048 + 255) / 256, 256, 0, stream>>>(gw2, Wp2, 2000, 2000, 2048, 2048);
  pack_wpad<<<(2048 * 2048 + 255) / 256, 256, 0, stream>>>(gw3, Wp3, 2000, 2000, 2048, 2048);
  pack_wpad<<<(2048 * 2048 + 255) / 256, 256, 0, stream>>>(gw4, Wp4, 2000, 2000, 2048, 2048);
  pack_bias3<<<8, 256, 0, stream>>>(gb2, gb3, gb4, bp);
  q_build<<<512, 256, 0, stream>>>(qst, gw1, gb1, Q);
  pack_wpad<<<(1024 * 2048 + 255) / 256, 256, 0, stream>>>(fw1, Fp1, 1000, 2000, 1024, 2048);
  pack_wpad<<<(512 * 1024 + 255) / 256, 256, 0, stream>>>(fw2, Fp2, 500, 1000, 512, 1024);
  pack_wpad<<<(128 * 512 + 255) / 256, 256, 0, stream>>>(fw3, Fp3, 100, 500, 128, 512);
  pad_bias<<<4, 256, 0, stream>>>(fb1, fbc1, 1000, 1024);
  pad_bias<<<2, 256, 0, stream>>>(fb2, fbc2, 500, 512);
  pad_bias<<<1, 256, 0, stream>>>(fb3, fbc3, 100, 128);

  // ---- layer-1 decomposition GEMMs (bf16 raw out) ----
  gemm_bt<3><<<13 * 16, 256, 0, stream>>>(obj, 256, W1a, 256, nullptr, Afu, 2048, nullptr, 8, 16);
  gemm_bt<3><<<13 * 16, 256, 0, stream>>>(obj, 256, W1b, 256, nullptr, Bfu, 2048, nullptr, 8, 16);

  // ---- g-MLP in adaptive chunks; layer-4 reduce fused into GEMM epilogue ----
  zero_xg<<<512, 256, 0, stream>>>(xg);
  const int TOTPAD = 40960;   // padded row total (multiple of 256)
  const int TOTROWS = 40000;
  int r0 = 0;
  while (r0 < TOTPAD) {
    int CH = (TOTPAD - r0 >= CHMAX) ? CHMAX : (TOTPAD - r0);
    int nvalid = TOTROWS - r0; if (nvalid > CH) nvalid = CH; if (nvalid < 0) nvalid = 0;
    int mtiles = CH / 256;
    h1_build<<<(unsigned)CH, 256, 0, stream>>>(Afu, Bfu, Q, h0, r0, nvalid);
    gemm256<32, 0><<<mtiles * 8, 512, 0, stream>>>(h0, Wp2, h1b, bp, nullptr, 0, 0);
    gemm256<32, 0><<<mtiles * 8, 512, 0, stream>>>(h1b, Wp3, h0, bp + 2048, nullptr, 0, 0);
    gemm256<32, 1><<<mtiles * 8, 512, 0, stream>>>(h0, Wp4, nullptr, bp + 4096, rp4, r0, nvalid);
    int bfirst = r0 / 625;
    int blast = (r0 + CH - 1) / 625; if (blast > 63) blast = 63;
    int nseg = blast - bfirst + 1;
    l4_fin<<<dim3(8, nseg), 256, 0, stream>>>(rp4, xg, r0, bfirst, mtiles);
    r0 += CH;
  }

  // ---- f MLP: layers 1-3 as MFMA GEMMs, layer 4 tiny ----
  pack_xgb<<<(128 * 2048 + 255) / 256, 256, 0, stream>>>(xg, xgb);
  gemm_bt<5><<<8, 256, 0, stream>>>(xgb, 2048, Fp1, 2048, nullptr, xf1b, 1024, fbc1, 64, 8);
  gemm_bt<5><<<4, 256, 0, stream>>>(xf1b, 1024, Fp2, 1024, nullptr, xf2b, 512, fbc2, 32, 4);
  gemm_bt<5><<<1, 256, 0, stream>>>(xf2b, 512, Fp3, 512, nullptr, xf3b, 128, fbc3, 16, 1);
  f_layer4<<<(64 * 10 * 64 + 255) / 256, 256, 0, stream>>>(xf3b, fw4, fb4, xf4);
  lsm_kernel<<<1, 64, 0, stream>>>(xf4, out);
}

// Round 12
// 1188.876 us; speedup vs baseline: 1.4802x; 1.0097x over previous
//
#include <hip/hip_runtime.h>

typedef unsigned short u16;
typedef unsigned int u32;
typedef __attribute__((ext_vector_type(8))) short bf16x8;
typedef __attribute__((ext_vector_type(4))) float f32x4;

#define BN_EPS 1e-5f
#define BN_S 16

__device__ __forceinline__ float bf2f(u16 u) {
  union { unsigned u; float f; } x; x.u = ((unsigned)u) << 16; return x.f;
}
__device__ __forceinline__ u16 f2bf(float f) {
  union { float f; unsigned u; } x; x.f = f;
  unsigned r = x.u + 0x7FFFu + ((x.u >> 16) & 1u);
  return (u16)(r >> 16);
}

// ---------------- conv1: LDS-staged, one block per (n, ho) ----------------
__global__ __launch_bounds__(256) void conv1_lds(const float* __restrict__ img,
                                                 const float* __restrict__ w,
                                                 const float* __restrict__ b,
                                                 float* __restrict__ C1) {
  int blk = blockIdx.x;             // n*38 + ho
  int n = blk / 38, ho = blk % 38;
  __shared__ float in_s[9 * 80];
  __shared__ float w_s[32 * 27];
  __shared__ float b_s[32];
  int t = threadIdx.x;
  for (int i = t; i < 720; i += 256) in_s[i] = 0.f;
  __syncthreads();
  for (int i = t; i < 675; i += 256) {
    int wi = i % 75; int q = i / 75; int kh = q % 3; int ci = q / 3;
    int hi = ho * 2 - 1 + kh;
    if (hi >= 0 && hi < 75)
      in_s[(ci * 3 + kh) * 80 + wi + 1] = img[((size_t)(n * 3 + ci) * 75 + hi) * 75 + wi];
  }
  for (int i = t; i < 864; i += 256) w_s[i] = w[i];
  if (t < 32) b_s[t] = b[t];
  __syncthreads();
  for (int idx = t; idx < 1216; idx += 256) {
    int wo = idx >> 5, co = idx & 31;
    float acc = b_s[co];
    const float* wp = w_s + co * 27;
#pragma unroll
    for (int ci = 0; ci < 3; ci++) {
#pragma unroll
      for (int kh = 0; kh < 3; kh++) {
        const float* ip = in_s + (ci * 3 + kh) * 80 + 2 * wo;
        const float* wq = wp + ci * 9 + kh * 3;
        acc += ip[0] * wq[0] + ip[1] * wq[1] + ip[2] * wq[2];
      }
    }
    C1[((size_t)blk * 38 + wo) * 32 + co] = acc;
  }
}

// ---------------- BN column-stats (deterministic 2-stage) ----------------
__global__ void bn_partial(const float* __restrict__ C, int ldc, int M,
                           float* __restrict__ part) {
  int c = blockIdx.x; int s = blockIdx.y; int t = threadIdx.x;
  int rowsPer = (M + BN_S - 1) / BN_S;
  int r0 = s * rowsPer; int r1 = r0 + rowsPer; if (r1 > M) r1 = M;
  float s1 = 0.f, s2 = 0.f;
  for (int r = r0 + t; r < r1; r += 256) {
    float v = C[(size_t)r * ldc + c]; s1 += v; s2 += v * v;
  }
  __shared__ float l1[256], l2[256];
  l1[t] = s1; l2[t] = s2; __syncthreads();
  for (int off = 128; off > 0; off >>= 1) {
    if (t < off) { l1[t] += l1[t + off]; l2[t] += l2[t + off]; }
    __syncthreads();
  }
  if (t == 0) { part[s * 512 + c] = l1[0]; part[s * 512 + 256 + c] = l2[0]; }
}

__global__ void bn_final(const float* __restrict__ part, const float* __restrict__ gamma,
                         const float* __restrict__ beta, float* __restrict__ ss,
                         int C, int M) {
  int c = threadIdx.x;
  if (c >= C) { if (c < 256) { ss[c] = 0.f; ss[256 + c] = 0.f; } return; }
  float s1 = 0.f, s2 = 0.f;
#pragma unroll
  for (int s = 0; s < BN_S; s++) { s1 += part[s * 512 + c]; s2 += part[s * 512 + 256 + c]; }
  float mu = s1 / M;
  float var = s2 / M - mu * mu;
  float sc = gamma[c] * rsqrtf(var + BN_EPS);
  ss[c] = sc; ss[256 + c] = beta[c] - mu * sc;
}

// ---------------- fused BN+ReLU + im2col -> bf16 X[row][tap*Ci+ci] ----------------
__global__ void bnrelu_im2col(const float* __restrict__ Cprev, int ldprev, int Hp, int Wp,
                              const float* __restrict__ ss, u16* __restrict__ X,
                              int Ho, int Wo, int Ci, int Mp) {
  int civ4 = Ci >> 2;
  int idx = blockIdx.x * blockDim.x + threadIdx.x;
  int total = Mp * 9 * civ4;
  if (idx >= total) return;
  int cv = idx % civ4; int t2 = idx / civ4;
  int tap = t2 % 9; int row = t2 / 9;
  int K = 9 * Ci;
  u16* dst = X + (size_t)row * K + tap * Ci + cv * 4;
  int HW = Ho * Wo;
  int Mvalid = 64 * HW;
  ushort4 o4; o4.x = 0; o4.y = 0; o4.z = 0; o4.w = 0;
  if (row < Mvalid) {
    int wo = row % Wo; int t = row / Wo;
    int ho = t % Ho; int n = t / Ho;
    int kh = tap / 3, kw = tap % 3;
    int hi = ho * 2 - 1 + kh, wi = wo * 2 - 1 + kw;
    if (hi >= 0 && hi < Hp && wi >= 0 && wi < Wp) {
      const float* src = Cprev + ((size_t)((n * Hp + hi) * Wp + wi)) * ldprev + cv * 4;
      float4 v = *(const float4*)src;
      int c0 = cv * 4;
      float a;
      a = v.x * ss[c0 + 0] + ss[256 + c0 + 0]; o4.x = f2bf(a > 0.f ? a : 0.f);
      a = v.y * ss[c0 + 1] + ss[256 + c0 + 1]; o4.y = f2bf(a > 0.f ? a : 0.f);
      a = v.z * ss[c0 + 2] + ss[256 + c0 + 2]; o4.z = f2bf(a > 0.f ? a : 0.f);
      a = v.w * ss[c0 + 3] + ss[256 + c0 + 3]; o4.w = f2bf(a > 0.f ? a : 0.f);
    }
  }
  *(ushort4*)dst = o4;
}

// ---------------- conv weight pack ----------------
__global__ void pack_convw(const float* __restrict__ w, u16* __restrict__ Wp,
                           int Co, int Ci, int Cop) {
  int K = 9 * Ci;
  int idx = blockIdx.x * blockDim.x + threadIdx.x;
  if (idx >= Cop * K) return;
  int k = idx % K; int co = idx / K;
  int tap = k / Ci; int ci = k % Ci;
  float v = (co < Co) ? w[((size_t)co * Ci + ci) * 9 + tap] : 0.f;
  Wp[idx] = f2bf(v);
}

__global__ void pad_bias(const float* __restrict__ b, float* __restrict__ bc, int Co, int Cop) {
  int i = blockIdx.x * blockDim.x + threadIdx.x;
  if (i < Cop) bc[i] = (i < Co) ? b[i] : 0.f;
}

// ---------------- obj pack from C4 with BN+ReLU ----------------
__global__ void obj_from_c4(const float* __restrict__ C4, const float* __restrict__ ss,
                            u16* __restrict__ obj) {
  int idx = blockIdx.x * blockDim.x + threadIdx.x;
  if (idx >= 1664 * 256) return;
  int c = idx & 255; int row = idx >> 8;
  float v = 0.f;
  if (row < 1600) {
    float x = C4[(size_t)row * 256 + c];
    x = x * ss[c] + ss[256 + c];
    v = x > 0.f ? x : 0.f;
  }
  obj[idx] = f2bf(v);
}

// ---------------- MLP weight packs ----------------
__global__ void pack_w1(const float* __restrict__ gw1, u16* __restrict__ W1a, u16* __restrict__ W1b) {
  int idx = blockIdx.x * blockDim.x + threadIdx.x;
  if (idx >= 2048 * 256) return;
  int k = idx & 255, n = idx >> 8;
  float a = 0.f, b = 0.f;
  if (n < 2000) { a = gw1[(size_t)n * 523 + k]; b = gw1[(size_t)n * 523 + 256 + k]; }
  W1a[idx] = f2bf(a); W1b[idx] = f2bf(b);
}

__global__ void pack_wpad(const float* __restrict__ w, u16* __restrict__ Wp,
                          int N, int K, int Np, int Kp) {
  int idx = blockIdx.x * blockDim.x + threadIdx.x;
  if (idx >= Np * Kp) return;
  int k = idx % Kp, n = idx / Kp;
  float v = (n < N && k < K) ? w[(size_t)n * K + k] : 0.f;
  Wp[idx] = f2bf(v);
}

__global__ void pack_bias3(const float* __restrict__ b2, const float* __restrict__ b3,
                           const float* __restrict__ b4, float* __restrict__ bp) {
  int i = blockIdx.x * blockDim.x + threadIdx.x;
  if (i >= 2048) return;
  bp[i]        = (i < 2000) ? b2[i] : 0.f;
  bp[2048 + i] = (i < 2000) ? b3[i] : 0.f;
  bp[4096 + i] = (i < 2000) ? b4[i] : 0.f;
}

// ---------------- Q[b][o] = gb1[o] + qst[b] . gw1[o][512:523] ----------------
__global__ void q_build(const float* __restrict__ qst, const float* __restrict__ gw1,
                        const float* __restrict__ gb1, float* __restrict__ Q) {
  int idx = blockIdx.x * blockDim.x + threadIdx.x;
  if (idx >= 64 * 2048) return;
  int o = idx & 2047, b = idx >> 11;
  float v = 0.f;
  if (o < 2000) {
    v = gb1[o];
    const float* w = gw1 + (size_t)o * 523 + 512;
    const float* q = qst + b * 11;
#pragma unroll
    for (int k = 0; k < 11; k++) v += q[k] * w[k];
  }
  Q[idx] = v;
}

// ---------------- xg -> bf16 [128][2048] with 1/625 scale ----------------
__global__ void pack_xgb(const float* __restrict__ xg, u16* __restrict__ xgb) {
  int idx = blockIdx.x * blockDim.x + threadIdx.x;
  if (idx >= 128 * 2048) return;
  int row = idx >> 11;
  float v = (row < 64) ? xg[idx] * (1.f / 625.f) : 0.f;
  xgb[idx] = f2bf(v);
}

// ---------------- global->LDS async ----------------
typedef const __attribute__((address_space(1))) u32* gas1;
typedef __attribute__((address_space(3))) u32* las3;
__device__ __forceinline__ void gld16(const void* g, void* l) {
  __builtin_amdgcn_global_load_lds((gas1)g, (las3)l, 16, 0, 0);
}

// ---------------- 128^2 bf16 MFMA GEMM (small/medium shapes) ----------------
// EPI 0: fp32 raw; EPI 2: fp32 acc+bias; EPI 3: bf16 raw; EPI 5: bf16 relu(acc+bias)
template <int EPI>
__global__ __launch_bounds__(256) void gemm_bt(
    const u16* __restrict__ A, int lda,
    const u16* __restrict__ W, int ldb,
    float* __restrict__ Cf, u16* __restrict__ Cb, int ldc,
    const float* __restrict__ bias, int KT, int NTN) {
  __shared__ __align__(16) char lds[32768];
  int bid = blockIdx.x;
  int wg;
  if ((gridDim.x & 7) == 0) {
    int cpx = gridDim.x >> 3;
    wg = (bid & 7) * cpx + (bid >> 3);
  } else {
    wg = bid;
  }
  int mt = wg / NTN, nt = wg % NTN;
  int tid = threadIdx.x;
  int wave = tid >> 6, lane = tid & 63;
  int r = lane & 15, g = lane >> 4;
  int wr = wave >> 1, wc = wave & 1;

  const u16* Asrc = A + (size_t)(mt * 128 + wave * 32 + r) * lda + g * 8;
  const u16* Wsrc = W + (size_t)(nt * 128 + wave * 32 + r) * ldb + g * 8;

  f32x4 acc[4][4];
#pragma unroll
  for (int i = 0; i < 4; i++)
#pragma unroll
    for (int j = 0; j < 4; j++) acc[i][j] = (f32x4){0.f, 0.f, 0.f, 0.f};

  {
    char* Al = lds; char* Wl = lds + 8192;
    gld16(Asrc, Al + wave * 2048);
    gld16(Asrc + (size_t)16 * lda, Al + wave * 2048 + 1024);
    gld16(Wsrc, Wl + wave * 2048);
    gld16(Wsrc + (size_t)16 * ldb, Wl + wave * 2048 + 1024);
  }
  __syncthreads();

  int buf = 0;
  for (int kt = 0; kt < KT; kt++) {
    if (kt + 1 < KT) {
      int k0 = (kt + 1) * 32;
      char* Al = lds + (buf ^ 1) * 16384; char* Wl = Al + 8192;
      gld16(Asrc + k0, Al + wave * 2048);
      gld16(Asrc + k0 + (size_t)16 * lda, Al + wave * 2048 + 1024);
      gld16(Wsrc + k0, Wl + wave * 2048);
      gld16(Wsrc + k0 + (size_t)16 * ldb, Wl + wave * 2048 + 1024);
    }
    char* Al = lds + buf * 16384; char* Wl = Al + 8192;
    bf16x8 a[4], w[4];
#pragma unroll
    for (int i = 0; i < 4; i++) a[i] = *(const bf16x8*)(Al + (wr * 4 + i) * 1024 + lane * 16);
#pragma unroll
    for (int j = 0; j < 4; j++) w[j] = *(const bf16x8*)(Wl + (wc * 4 + j) * 1024 + lane * 16);
#pragma unroll
    for (int i = 0; i < 4; i++)
#pragma unroll
      for (int j = 0; j < 4; j++)
        acc[i][j] = __builtin_amdgcn_mfma_f32_16x16x32_bf16(a[i], w[j], acc[i][j], 0, 0, 0);
    __syncthreads();
    buf ^= 1;
  }

  int rowb = mt * 128 + wr * 64 + (lane >> 4) * 4;
  int colb = nt * 128 + wc * 64 + (lane & 15);
#pragma unroll
  for (int i = 0; i < 4; i++) {
#pragma unroll
    for (int j = 0; j < 4; j++) {
      int col = colb + j * 16;
      float bv = (EPI == 2 || EPI == 5) ? bias[col] : 0.f;
#pragma unroll
      for (int q = 0; q < 4; q++) {
        int row = rowb + i * 16 + q;
        float v = acc[i][j][q];
        if (EPI == 2) {
          Cf[(size_t)row * ldc + col] = v + bv;
        } else if (EPI == 3) {
          Cb[(size_t)row * ldc + col] = f2bf(v);
        } else if (EPI == 5) {
          float z = v + bv; z = z > 0.f ? z : 0.f;
          Cb[(size_t)row * ldc + col] = f2bf(z);
        } else {
          Cf[(size_t)row * ldc + col] = v;
        }
      }
    }
  }
}

// ---------------- 256^2 bf16 GEMM — 8-phase, rotated ds_read schedule ----------------
// Reads for phase Q+1 issued AFTER phase Q's MFMA cluster (WAR deps pin the order),
// so each phase's MFMA consumes reads issued a full phase earlier. vmcnt at Q2
// (proves A(t+1)+B(t+1)); Q3 pre-reads next tile's a+b. Boundary drain fixed.
#define MF16(d, av, bv) d = __builtin_amdgcn_mfma_f32_16x16x32_bf16(av, bv, d, 0, 0, 0)

template <int NT, int SUM>
__global__ __launch_bounds__(512, 2) void gemm256(
    const u16* __restrict__ A, const u16* __restrict__ W,
    u16* __restrict__ Cb, const float* __restrict__ bias,
    float* __restrict__ rp4, int r0c, int nvalid) {
  __shared__ __align__(16) char lds[131072];
  int bid = blockIdx.x;
  int cpx = gridDim.x >> 3;
  int wg = (bid & 7) * cpx + (bid >> 3);
  int mt = wg >> 3, nt = wg & 7;
  int tid = threadIdx.x;
  int wave = tid >> 6, lane = tid & 63;
  int wr = wave >> 2, wc = wave & 3;
  int wcl = wc & 1, wch = wc >> 1;
  int l15 = lane & 15, l7 = lane & 7, lh = lane >> 4;

  int srcChunkOff = (((lane & 7) ^ (lane >> 3)) << 3);
  int srcRowInWave = (lane >> 3);
  auto stageA = [&](int tt, int slot, int h) {
#pragma unroll
    for (int s = 0; s < 2; s++) {
      const u16* src = A + (size_t)(mt * 256 + h * 128 + s * 64 + wave * 8 + srcRowInWave) * 2048
                         + tt * 64 + srcChunkOff;
      gld16(src, lds + slot * 65536 + h * 16384 + s * 8192 + wave * 1024);
    }
  };
  auto stageB = [&](int tt, int slot, int h) {
#pragma unroll
    for (int s = 0; s < 2; s++) {
      const u16* src = W + (size_t)(nt * 256 + h * 128 + s * 64 + wave * 8 + srcRowInWave) * 2048
                         + tt * 64 + srcChunkOff;
      gld16(src, lds + slot * 65536 + 32768 + h * 16384 + s * 8192 + wave * 1024);
    }
  };

  f32x4 acc[8][4];
#pragma unroll
  for (int i = 0; i < 8; i++)
#pragma unroll
    for (int j = 0; j < 4; j++) acc[i][j] = (f32x4){0.f, 0.f, 0.f, 0.f};

  stageA(0, 0, 0); stageA(0, 0, 1); stageB(0, 0, 0); stageB(0, 0, 1);
  stageB(1, 1, 0); stageB(1, 1, 1);
  asm volatile("s_waitcnt vmcnt(4)" ::: "memory");   // tile0 A+B landed; B(1) in flight
  __builtin_amdgcn_s_barrier();

#define AROFF(Q, i, ks) \
  ((((2 * (Q) + (i)) * 16 + l15) * 128) + (((((ks) * 4) + lh) ^ l7) << 4))
#define BROFF(j, ks) \
  ((((wcl * 4 + (j)) * 16 + l15) * 128) + (((((ks) * 4) + lh) ^ l7) << 4))

  bf16x8 a00, a01, a10, a11;
  bf16x8 b00, b01, b10, b11, b20, b21, b30, b31;
  {  // initial operand reads: tile 0, phase 0
    const char* Ab0 = lds + wr * 16384;
    const char* Bb0 = lds + 32768 + wch * 16384;
    a00 = *(const bf16x8*)(Ab0 + AROFF(0, 0, 0));
    a01 = *(const bf16x8*)(Ab0 + AROFF(0, 0, 1));
    a10 = *(const bf16x8*)(Ab0 + AROFF(0, 1, 0));
    a11 = *(const bf16x8*)(Ab0 + AROFF(0, 1, 1));
    b00 = *(const bf16x8*)(Bb0 + BROFF(0, 0));
    b01 = *(const bf16x8*)(Bb0 + BROFF(0, 1));
    b10 = *(const bf16x8*)(Bb0 + BROFF(1, 0));
    b11 = *(const bf16x8*)(Bb0 + BROFF(1, 1));
    b20 = *(const bf16x8*)(Bb0 + BROFF(2, 0));
    b21 = *(const bf16x8*)(Bb0 + BROFF(2, 1));
    b30 = *(const bf16x8*)(Bb0 + BROFF(3, 0));
    b31 = *(const bf16x8*)(Bb0 + BROFF(3, 1));
  }

#define PHASE(Q, T, BUF)                                                         \
  {                                                                              \
    if ((Q) == 0) { if ((T) + 1 < NT) stageA((T) + 1, (BUF) ^ 1, 0); }           \
    if ((Q) == 1) { if ((T) + 1 < NT) stageA((T) + 1, (BUF) ^ 1, 1);             \
                    if ((T) + 2 < NT) stageB((T) + 2, (BUF), 0); }               \
    if ((Q) == 2) { if ((T) + 2 < NT) stageB((T) + 2, (BUF), 1); }               \
    __builtin_amdgcn_s_barrier();                                                \
    __builtin_amdgcn_s_setprio(1);                                               \
    MF16(acc[2 * (Q) + 0][0], a00, b00); MF16(acc[2 * (Q) + 0][0], a01, b01);    \
    MF16(acc[2 * (Q) + 0][1], a00, b10); MF16(acc[2 * (Q) + 0][1], a01, b11);    \
    MF16(acc[2 * (Q) + 0][2], a00, b20); MF16(acc[2 * (Q) + 0][2], a01, b21);    \
    MF16(acc[2 * (Q) + 0][3], a00, b30); MF16(acc[2 * (Q) + 0][3], a01, b31);    \
    MF16(acc[2 * (Q) + 1][0], a10, b00); MF16(acc[2 * (Q) + 1][0], a11, b01);    \
    MF16(acc[2 * (Q) + 1][1], a10, b10); MF16(acc[2 * (Q) + 1][1], a11, b11);    \
    MF16(acc[2 * (Q) + 1][2], a10, b20); MF16(acc[2 * (Q) + 1][2], a11, b21);    \
    MF16(acc[2 * (Q) + 1][3], a10, b30); MF16(acc[2 * (Q) + 1][3], a11, b31);    \
    __builtin_amdgcn_s_setprio(0);                                               \
    if ((Q) < 3) {                                                               \
      const char* Ab_ = lds + (BUF) * 65536 + wr * 16384;                        \
      a00 = *(const bf16x8*)(Ab_ + AROFF((Q) + 1, 0, 0));                        \
      a01 = *(const bf16x8*)(Ab_ + AROFF((Q) + 1, 0, 1));                        \
      a10 = *(const bf16x8*)(Ab_ + AROFF((Q) + 1, 1, 0));                        \
      a11 = *(const bf16x8*)(Ab_ + AROFF((Q) + 1, 1, 1));                        \
    } else if ((T) + 1 < NT) {                                                   \
      const char* AbN_ = lds + (((BUF) ^ 1)) * 65536 + wr * 16384;               \
      const char* BbN_ = lds + (((BUF) ^ 1)) * 65536 + 32768 + wch * 16384;      \
      a00 = *(const bf16x8*)(AbN_ + AROFF(0, 0, 0));                             \
      a01 = *(const bf16x8*)(AbN_ + AROFF(0, 0, 1));                             \
      a10 = *(const bf16x8*)(AbN_ + AROFF(0, 1, 0));                             \
      a11 = *(const bf16x8*)(AbN_ + AROFF(0, 1, 1));                             \
      b00 = *(const bf16x8*)(BbN_ + BROFF(0, 0));                                \
      b01 = *(const bf16x8*)(BbN_ + BROFF(0, 1));                                \
      b10 = *(const bf16x8*)(BbN_ + BROFF(1, 0));                                \
      b11 = *(const bf16x8*)(BbN_ + BROFF(1, 1));                                \
      b20 = *(const bf16x8*)(BbN_ + BROFF(2, 0));                                \
      b21 = *(const bf16x8*)(BbN_ + BROFF(2, 1));                                \
      b30 = *(const bf16x8*)(BbN_ + BROFF(3, 0));                                \
      b31 = *(const bf16x8*)(BbN_ + BROFF(3, 1));                                \
    }                                                                            \
    if ((Q) == 2) {                                                              \
      if ((T) + 2 < NT) { asm volatile("s_waitcnt vmcnt(4)" ::: "memory"); }     \
      else              { asm volatile("s_waitcnt vmcnt(0)" ::: "memory"); }     \
    }                                                                            \
    __builtin_amdgcn_s_barrier();                                                \
  }

#pragma unroll 1
  for (int t2 = 0; t2 < NT; t2 += 2) {
    PHASE(0, t2, 0) PHASE(1, t2, 0) PHASE(2, t2, 0) PHASE(3, t2, 0)
    PHASE(0, t2 + 1, 1) PHASE(1, t2 + 1, 1) PHASE(2, t2 + 1, 1) PHASE(3, t2 + 1, 1)
  }
#undef PHASE
#undef AROFF
#undef BROFF

  int colb = nt * 256 + wc * 64 + l15;
  if (SUM == 0) {
    int rowb = mt * 256 + wr * 128 + lh * 4;
#pragma unroll
    for (int i = 0; i < 8; i++) {
#pragma unroll
      for (int j = 0; j < 4; j++) {
        int col = colb + j * 16;
        float bv = bias[col];
#pragma unroll
        for (int q = 0; q < 4; q++) {
          int row = rowb + i * 16 + q;
          float v = acc[i][j][q] + bv;
          v = v > 0.f ? v : 0.f;
          Cb[(size_t)row * 2048 + col] = f2bf(v);
        }
      }
    }
  } else {
    int blockRow0 = mt * 256;
    int bimg = (r0c + blockRow0) / 625;
    int boundary = (bimg + 1) * 625 - (r0c + blockRow0);   // in [1,625]
    float p0[4] = {0.f, 0.f, 0.f, 0.f};
    float p1[4] = {0.f, 0.f, 0.f, 0.f};
#pragma unroll
    for (int i = 0; i < 8; i++) {
#pragma unroll
      for (int j = 0; j < 4; j++) {
        float bv = bias[colb + j * 16];
#pragma unroll
        for (int q = 0; q < 4; q++) {
          int row_local = wr * 128 + lh * 4 + i * 16 + q;
          float v = acc[i][j][q] + bv;
          v = v > 0.f ? v : 0.f;
          if (blockRow0 + row_local >= nvalid) v = 0.f;
          bool sg1 = row_local >= boundary;
          p0[j] += sg1 ? 0.f : v;
          p1[j] += sg1 ? v : 0.f;
        }
      }
    }
    float* rs = (float*)lds;
    int contrib = wr * 4 + lh;
#pragma unroll
    for (int j = 0; j < 4; j++) {
      int colL = wc * 64 + j * 16 + l15;
      rs[(contrib * 2 + 0) * 256 + colL] = p0[j];
      rs[(contrib * 2 + 1) * 256 + colL] = p1[j];
    }
    __syncthreads();
    int seg = tid >> 8, colx = tid & 255;
    float s = 0.f;
#pragma unroll
    for (int c8 = 0; c8 < 8; c8++) s += rs[(c8 * 2 + seg) * 256 + colx];
    rp4[((size_t)(mt * 2 + seg)) * 2048 + nt * 256 + colx] = s;
  }
}

// ---------------- h1 = relu(A_i + B_j + Q_b), rows = global pair index ----------------
__global__ void h1_build(const u16* __restrict__ Af, const u16* __restrict__ Bf,
                         const float* __restrict__ Q, u16* __restrict__ h1,
                         int r0, int nvalid) {
  int lrow = blockIdx.x;
  int t = threadIdx.x;
  u16* dst = h1 + (size_t)lrow * 2048;
  if (lrow >= nvalid) {
#pragma unroll
    for (int it = 0; it < 2; it++) {
      int o = it * 1024 + t * 4;
      ushort4 z; z.x = 0; z.y = 0; z.z = 0; z.w = 0;
      *(ushort4*)(dst + o) = z;
    }
    return;
  }
  int grow = r0 + lrow;
  int b = grow / 625; int rem = grow % 625;
  int i = rem / 25, j = rem % 25;
  const u16* Ap = Af + (size_t)(b * 25 + i) * 2048;
  const u16* Bp = Bf + (size_t)(b * 25 + j) * 2048;
  const float* Qp = Q + (size_t)b * 2048;
#pragma unroll
  for (int it = 0; it < 2; it++) {
    int o = it * 1024 + t * 4;
    ushort4 a4 = *(const ushort4*)(Ap + o);
    ushort4 b4 = *(const ushort4*)(Bp + o);
    float4 qv = *(const float4*)(Qp + o);
    ushort4 outv;
    float v;
    v = bf2f(a4.x) + bf2f(b4.x) + qv.x; outv.x = f2bf(v > 0.f ? v : 0.f);
    v = bf2f(a4.y) + bf2f(b4.y) + qv.y; outv.y = f2bf(v > 0.f ? v : 0.f);
    v = bf2f(a4.z) + bf2f(b4.z) + qv.z; outv.z = f2bf(v > 0.f ? v : 0.f);
    v = bf2f(a4.w) + bf2f(b4.w) + qv.w; outv.w = f2bf(v > 0.f ? v : 0.f);
    *(ushort4*)(dst + o) = outv;
  }
}

// ---------------- layer-4 partial finisher ----------------
__global__ void zero_xg(float* __restrict__ xg) {
  int i = blockIdx.x * blockDim.x + threadIdx.x;
  if (i < 64 * 2048) xg[i] = 0.f;
}

__global__ void l4_fin(const float* __restrict__ rp4, float* __restrict__ xg,
                       int r0, int bfirst, int mtiles) {
  int col = blockIdx.x * 256 + threadIdx.x;   // 0..2047
  int b = bfirst + blockIdx.y;
  if (b > 63) return;
  float s = 0.f;
  for (int mt = 0; mt < mtiles; mt++) {
    int img0 = (r0 + mt * 256) / 625;
    if (img0 == b)     s += rp4[((size_t)(mt * 2 + 0)) * 2048 + col];
    if (img0 + 1 == b) s += rp4[((size_t)(mt * 2 + 1)) * 2048 + col];
  }
  xg[(size_t)b * 2048 + col] += s;
}

// ---------------- f-MLP layer 4: warp per (b,o), bf16 input ----------------
__global__ void f_layer4(const u16* __restrict__ x, const float* __restrict__ Wf,
                         const float* __restrict__ bf_, float* __restrict__ y) {
  int gwid = (blockIdx.x * blockDim.x + threadIdx.x) >> 6;
  int lane = threadIdx.x & 63;
  if (gwid >= 64 * 10) return;
  int b = gwid / 10, o = gwid % 10;
  const u16* xp = x + (size_t)b * 128;
  const float* wp = Wf + (size_t)o * 100;
  float s = 0.f;
  for (int k = lane; k < 100; k += 64) s += bf2f(xp[k]) * wp[k];
  for (int off = 32; off > 0; off >>= 1) s += __shfl_down(s, off);
  if (lane == 0) y[b * 16 + o] = s + bf_[o];
}

__global__ void lsm_kernel(const float* __restrict__ xf4, float* __restrict__ out) {
  int b = blockIdx.x * blockDim.x + threadIdx.x;
  if (b >= 64) return;
  const float* x = xf4 + b * 16;
  float m = x[0];
  for (int i = 1; i < 10; i++) m = fmaxf(m, x[i]);
  float s = 0.f;
  for (int i = 0; i < 10; i++) s += expf(x[i] - m);
  float ls = logf(s);
  for (int i = 0; i < 10; i++) out[b * 10 + i] = x[i] - m - ls;
}

// ---------------- host ----------------
extern "C" void kernel_launch(void* const* d_in, const int* in_sizes, int n_in,
                              void* d_out, int out_size, void* d_ws, size_t ws_size,
                              hipStream_t stream) {
  const float* img = (const float*)d_in[0];
  const float* qst = (const float*)d_in[1];
  const float* w1 = (const float*)d_in[2];  const float* b1 = (const float*)d_in[3];
  const float* w2 = (const float*)d_in[4];  const float* b2 = (const float*)d_in[5];
  const float* w3 = (const float*)d_in[6];  const float* b3 = (const float*)d_in[7];
  const float* w4 = (const float*)d_in[8];  const float* b4 = (const float*)d_in[9];
  const float* g1 = (const float*)d_in[10]; const float* be1 = (const float*)d_in[11];
  const float* g2 = (const float*)d_in[12]; const float* be2 = (const float*)d_in[13];
  const float* g3 = (const float*)d_in[14]; const float* be3 = (const float*)d_in[15];
  const float* g4 = (const float*)d_in[16]; const float* be4 = (const float*)d_in[17];
  const float* gw1 = (const float*)d_in[18]; const float* gb1 = (const float*)d_in[19];
  const float* gw2 = (const float*)d_in[20]; const float* gb2 = (const float*)d_in[21];
  const float* gw3 = (const float*)d_in[22]; const float* gb3 = (const float*)d_in[23];
  const float* gw4 = (const float*)d_in[24]; const float* gb4 = (const float*)d_in[25];
  const float* fw1 = (const float*)d_in[26]; const float* fb1 = (const float*)d_in[27];
  const float* fw2 = (const float*)d_in[28]; const float* fb2 = (const float*)d_in[29];
  const float* fw3 = (const float*)d_in[30]; const float* fb3 = (const float*)d_in[31];
  const float* fw4 = (const float*)d_in[32]; const float* fb4 = (const float*)d_in[33];
  float* out = (float*)d_out;

  char* P = (char*)d_ws;
  auto alloc = [&](size_t bytes) -> char* {
    char* r = P; P += (bytes + 255) & ~(size_t)255; return r;
  };
  // persistent
  u16* Wp2 = (u16*)alloc(2048ull * 2048 * 2);
  u16* Wp3 = (u16*)alloc(2048ull * 2048 * 2);
  u16* Wp4 = (u16*)alloc(2048ull * 2048 * 2);
  u16* Afu = (u16*)alloc(1664ull * 2048 * 2);
  u16* Bfu = (u16*)alloc(1664ull * 2048 * 2);
  float* Q = (float*)alloc(64ull * 2048 * 4);
  float* bp = (float*)alloc(3ull * 2048 * 4);
  float* xg = (float*)alloc(64ull * 2048 * 4);
  u16* obj = (u16*)alloc(1664ull * 256 * 2);
  u16* W1a = (u16*)alloc(2048ull * 256 * 2);
  u16* W1b = (u16*)alloc(2048ull * 256 * 2);
  float* rp4 = (float*)alloc(160ull * 2 * 2048 * 4);
  // f-MLP packs / buffers
  u16* Fp1 = (u16*)alloc(1024ull * 2048 * 2);
  u16* Fp2 = (u16*)alloc(512ull * 1024 * 2);
  u16* Fp3 = (u16*)alloc(128ull * 512 * 2);
  float* fbc1 = (float*)alloc(1024 * 4);
  float* fbc2 = (float*)alloc(512 * 4);
  float* fbc3 = (float*)alloc(128 * 4);
  u16* xgb  = (u16*)alloc(128ull * 2048 * 2);
  u16* xf1b = (u16*)alloc(128ull * 1024 * 2);
  u16* xf2b = (u16*)alloc(128ull * 512 * 2);
  u16* xf3b = (u16*)alloc(128ull * 128 * 2);
  float* xf4 = (float*)alloc(64ull * 16 * 4);
  // conv-phase
  float* C1 = (float*)alloc(92416ull * 32 * 4);
  u16*   X2 = (u16*)alloc(23168ull * 288 * 2);
  float* C2 = (float*)alloc(23168ull * 128 * 4);
  u16*   X3 = (u16*)alloc(6400ull * 576 * 2);
  float* C3 = (float*)alloc(6400ull * 128 * 4);
  u16*   X4 = (u16*)alloc(1664ull * 1152 * 2);
  float* C4 = (float*)alloc(1664ull * 256 * 4);
  u16*  Wc2 = (u16*)alloc(128ull * 288 * 2);
  u16*  Wc3 = (u16*)alloc(128ull * 576 * 2);
  u16*  Wc4 = (u16*)alloc(256ull * 1152 * 2);
  float* bc2 = (float*)alloc(128 * 4);
  float* bc3 = (float*)alloc(128 * 4);
  float* bc4 = (float*)alloc(256 * 4);
  float* bnp = (float*)alloc(BN_S * 512 * 4);
  float* ss  = (float*)alloc(512 * 4);

  // h-phase buffers: pick largest chunk tier (grid stays %256==0)
  size_t used = (size_t)(P - (char*)d_ws);
  size_t remain = (ws_size > used) ? (ws_size - used) : 0;
  int CHMAX;
  if (remain >= 2ull * 40960 * 2048 * 2 + 4096)      CHMAX = 40960;
  else if (remain >= 2ull * 24576 * 2048 * 2 + 4096) CHMAX = 24576;
  else if (remain >= 2ull * 16384 * 2048 * 2 + 4096) CHMAX = 16384;
  else                                               CHMAX = 8192;
  u16* h0  = (u16*)alloc((size_t)CHMAX * 2048 * 2);
  u16* h1b = (u16*)alloc((size_t)CHMAX * 2048 * 2);

  // ---- conv weight/bias packs ----
  pack_convw<<<(128 * 288 + 255) / 256, 256, 0, stream>>>(w2, Wc2, 64, 32, 128);
  pack_convw<<<(128 * 576 + 255) / 256, 256, 0, stream>>>(w3, Wc3, 128, 64, 128);
  pack_convw<<<(256 * 1152 + 255) / 256, 256, 0, stream>>>(w4, Wc4, 256, 128, 256);
  pad_bias<<<1, 256, 0, stream>>>(b2, bc2, 64, 128);
  pad_bias<<<1, 256, 0, stream>>>(b3, bc3, 128, 128);
  pad_bias<<<1, 256, 0, stream>>>(b4, bc4, 256, 256);

  // ---- conv stack ----
  conv1_lds<<<64 * 38, 256, 0, stream>>>(img, w1, b1, C1);
  bn_partial<<<dim3(32, BN_S), 256, 0, stream>>>(C1, 32, 92416, bnp);
  bn_final<<<1, 256, 0, stream>>>(bnp, g1, be1, ss, 32, 92416);
  bnrelu_im2col<<<(23168 * 9 * 8 + 255) / 256, 256, 0, stream>>>(C1, 32, 38, 38, ss, X2, 19, 19, 32, 23168);
  gemm_bt<2><<<181, 256, 0, stream>>>(X2, 288, Wc2, 288, C2, nullptr, 128, bc2, 9, 1);

  bn_partial<<<dim3(64, BN_S), 256, 0, stream>>>(C2, 128, 23104, bnp);
  bn_final<<<1, 256, 0, stream>>>(bnp, g2, be2, ss, 64, 23104);
  bnrelu_im2col<<<(6400 * 9 * 16 + 255) / 256, 256, 0, stream>>>(C2, 128, 19, 19, ss, X3, 10, 10, 64, 6400);
  gemm_bt<2><<<50, 256, 0, stream>>>(X3, 576, Wc3, 576, C3, nullptr, 128, bc3, 18, 1);

  bn_partial<<<dim3(128, BN_S), 256, 0, stream>>>(C3, 128, 6400, bnp);
  bn_final<<<1, 256, 0, stream>>>(bnp, g3, be3, ss, 128, 6400);
  bnrelu_im2col<<<(1664 * 9 * 32 + 255) / 256, 256, 0, stream>>>(C3, 128, 10, 10, ss, X4, 5, 5, 128, 1664);
  gemm_bt<2><<<26, 256, 0, stream>>>(X4, 1152, Wc4, 1152, C4, nullptr, 256, bc4, 36, 2);

  bn_partial<<<dim3(256, BN_S), 256, 0, stream>>>(C4, 256, 1600, bnp);
  bn_final<<<1, 256, 0, stream>>>(bnp, g4, be4, ss, 256, 1600);
  obj_from_c4<<<(1664 * 256 + 255) / 256, 256, 0, stream>>>(C4, ss, obj);

  // ---- MLP packs ----
  pack_w1<<<2048, 256, 0, stream>>>(gw1, W1a, W1b);
  pack_wpad<<<(2048 * 2048 + 255) / 256, 256, 0, stream>>>(gw2, Wp2, 2000, 2000, 2048, 2048);
  pack_wpad<<<(2048 * 2048 + 255) / 256, 256, 0, stream>>>(gw3, Wp3, 2000, 2000, 2048, 2048);
  pack_wpad<<<(2048 * 2048 + 255) / 256, 256, 0, stream>>>(gw4, Wp4, 2000, 2000, 2048, 2048);
  pack_bias3<<<8, 256, 0, stream>>>(gb2, gb3, gb4, bp);
  q_build<<<512, 256, 0, stream>>>(qst, gw1, gb1, Q);
  pack_wpad<<<(1024 * 2048 + 255) / 256, 256, 0, stream>>>(fw1, Fp1, 1000, 2000, 1024, 2048);
  pack_wpad<<<(512 * 1024 + 255) / 256, 256, 0, stream>>>(fw2, Fp2, 500, 1000, 512, 1024);
  pack_wpad<<<(128 * 512 + 255) / 256, 256, 0, stream>>>(fw3, Fp3, 100, 500, 128, 512);
  pad_bias<<<4, 256, 0, stream>>>(fb1, fbc1, 1000, 1024);
  pad_bias<<<2, 256, 0, stream>>>(fb2, fbc2, 500, 512);
  pad_bias<<<1, 256, 0, stream>>>(fb3, fbc3, 100, 128);

  // ---- layer-1 decomposition GEMMs (bf16 raw out) ----
  gemm_bt<3><<<13 * 16, 256, 0, stream>>>(obj, 256, W1a, 256, nullptr, Afu, 2048, nullptr, 8, 16);
  gemm_bt<3><<<13 * 16, 256, 0, stream>>>(obj, 256, W1b, 256, nullptr, Bfu, 2048, nullptr, 8, 16);

  // ---- g-MLP in adaptive chunks; layer-4 reduce fused into GEMM epilogue ----
  zero_xg<<<512, 256, 0, stream>>>(xg);
  const int TOTPAD = 40960;
  const int TOTROWS = 40000;
  int r0 = 0;
  while (r0 < TOTPAD) {
    int CH = (TOTPAD - r0 >= CHMAX) ? CHMAX : (TOTPAD - r0);
    int nvalid = TOTROWS - r0; if (nvalid > CH) nvalid = CH; if (nvalid < 0) nvalid = 0;
    int mtiles = CH / 256;
    h1_build<<<(unsigned)CH, 256, 0, stream>>>(Afu, Bfu, Q, h0, r0, nvalid);
    gemm256<32, 0><<<mtiles * 8, 512, 0, stream>>>(h0, Wp2, h1b, bp, nullptr, 0, 0);
    gemm256<32, 0><<<mtiles * 8, 512, 0, stream>>>(h1b, Wp3, h0, bp + 2048, nullptr, 0, 0);
    gemm256<32, 1><<<mtiles * 8, 512, 0, stream>>>(h0, Wp4, nullptr, bp + 4096, rp4, r0, nvalid);
    int bfirst = r0 / 625;
    int blast = (r0 + CH - 1) / 625; if (blast > 63) blast = 63;
    int nseg = blast - bfirst + 1;
    l4_fin<<<dim3(8, nseg), 256, 0, stream>>>(rp4, xg, r0, bfirst, mtiles);
    r0 += CH;
  }

  // ---- f MLP: layers 1-3 as MFMA GEMMs, layer 4 tiny ----
  pack_xgb<<<(128 * 2048 + 255) / 256, 256, 0, stream>>>(xg, xgb);
  gemm_bt<5><<<8, 256, 0, stream>>>(xgb, 2048, Fp1, 2048, nullptr, xf1b, 1024, fbc1, 64, 8);
  gemm_bt<5><<<4, 256, 0, stream>>>(xf1b, 1024, Fp2, 1024, nullptr, xf2b, 512, fbc2, 32, 4);
  gemm_bt<5><<<1, 256, 0, stream>>>(xf2b, 512, Fp3, 512, nullptr, xf3b, 128, fbc3, 16, 1);
  f_layer4<<<(64 * 10 * 64 + 255) / 256, 256, 0, stream>>>(xf3b, fw4, fb4, xf4);
  lsm_kernel<<<1, 64, 0, stream>>>(xf4, out);
}